// Round 1
// baseline (7957.088 us; speedup 1.0000x reference)
//
#include <hip/hip_runtime.h>

#define DI __device__ __forceinline__

typedef _Float16 f16x2 __attribute__((ext_vector_type(2)));

#define NPTS 2048
#define KNBR 32
#define SALL 524288.0f
#define EPSV 1e-5f
#define SLOPEV 0.2f

// ---------------- workspace layout (bytes) ----------------
// requires ws_size >= 16 MiB + 128 MiB = 150,994,944
#define OFF_IDX1 0u
#define OFF_IDX2 (2u*1024u*1024u)
#define OFF_H1T  (4u*1024u*1024u)
#define OFF_STAT (8u*1024u*1024u)
#define OFF_BIG  (16u*1024u*1024u)
// stat float offsets
#define SF0 0
#define SC1 32
#define SH1 160
#define S2o 288
#define SS2o 352
#define SC2 416
#define SH2 480
#define S3o 544
#define SS3o 672
#define SC3 800
#define SH3 928
#define S4o 1056
#define SS4o 1120
#define SC4 1184
#define SH4 1248

union U4 { uint4 u; float f[4]; f16x2 h[4]; };
union U2f { uint2 u; f16x2 h[2]; };

DI f16x2 pack2(float a, float b) { f16x2 r; r.x = (_Float16)a; r.y = (_Float16)b; return r; }
DI float lrelu(float z) { return z > 0.f ? z : SLOPEV * z; }

DI float fdot2f(f16x2 a, f16x2 b, float c) {
#if __has_builtin(__builtin_amdgcn_fdot2)
  return __builtin_amdgcn_fdot2(a, b, c, false);
#else
  return c + (float)a.x * (float)b.x + (float)a.y * (float)b.y;
#endif
}

// Exact top-32 of 2048 values held as nd[s] per lane (value j = s*64+lane).
// 32 iterations of (lane-tree-max -> wave butterfly with lowest-index tie-break -> clear).
DI void extract_top32(float (&nd)[32], int lane, int* __restrict__ outp) {
  int myj = 0;
  #pragma nounroll
  for (int it = 0; it < 32; ++it) {
    float tm[16];
    #pragma unroll
    for (int s = 0; s < 16; ++s) tm[s] = fmaxf(nd[s], nd[s + 16]);
    #pragma unroll
    for (int s = 0; s < 8; ++s) tm[s] = fmaxf(tm[s], tm[s + 8]);
    #pragma unroll
    for (int s = 0; s < 4; ++s) tm[s] = fmaxf(tm[s], tm[s + 4]);
    float m = fmaxf(fmaxf(tm[0], tm[2]), fmaxf(tm[1], tm[3]));
    int slot = 0;
    #pragma unroll
    for (int s = 31; s >= 0; --s) slot = (nd[s] == m) ? s : slot;  // lowest slot wins
    int j = slot * 64 + lane;
    float v = m;
    #pragma unroll
    for (int d = 1; d < 64; d <<= 1) {
      float vo = __shfl_xor(v, d);
      int jo = __shfl_xor(j, d);
      bool take = (vo > v) || ((vo == v) && (jo < j));
      v = take ? vo : v;
      j = take ? jo : j;
    }
    int sel = (lane == (j & 63)) ? (j >> 6) : 64;
    #pragma unroll
    for (int s = 0; s < 32; ++s) nd[s] = (s == sel) ? -3.0e38f : nd[s];
    myj = (it == lane) ? j : myj;
  }
  if (lane < 32) outp[lane] = myj;
}

// ---------------- K1: stage-1 top-k (C=3) ----------------
__global__ __launch_bounds__(256) void k_topk1(const float* __restrict__ x, int* __restrict__ idx1) {
  __shared__ float xl[NPTS * 3];   // [n][c]
  __shared__ float sq[NPTS];
  const int t = threadIdx.x;
  const int blk4 = blockIdx.x * 4;
  const int b = blk4 >> 11;
  const float* __restrict__ xb = x + (size_t)b * 3 * NPTS;
  for (int e = t; e < 3 * NPTS; e += 256) {
    int c = e >> 11, n = e & (NPTS - 1);
    xl[n * 3 + c] = xb[e];
  }
  __syncthreads();
  for (int n = t; n < NPTS; n += 256) {
    float a0 = xl[n * 3], a1 = xl[n * 3 + 1], a2 = xl[n * 3 + 2];
    sq[n] = a0 * a0 + a1 * a1 + a2 * a2;
  }
  __syncthreads();
  const int lane = t & 63, w = t >> 6;
  const int row = blk4 + w;
  const int i = row & (NPTS - 1);
  const float xi0 = xl[i * 3], xi1 = xl[i * 3 + 1], xi2 = xl[i * 3 + 2];
  const float si = sq[i];
  float nd[32];
  #pragma unroll
  for (int s = 0; s < 32; ++s) {
    int j = s * 64 + lane;
    float d = xi0 * xl[j * 3] + xi1 * xl[j * 3 + 1] + xi2 * xl[j * 3 + 2];
    nd[s] = (2.0f * d - si) - sq[j];
  }
  extract_top32(nd, lane, idx1 + (size_t)row * KNBR);
}

// ---------------- K2: feat1 moments (6 means + 21 second moments) ----------------
__global__ __launch_bounds__(256) void k_featstats(const float* __restrict__ x,
                                                   const int* __restrict__ idx1,
                                                   float* __restrict__ stat) {
  __shared__ float red[27];
  const int t = threadIdx.x;
  if (t < 27) red[t] = 0.f;
  __syncthreads();
  const int row = blockIdx.x * 256 + t;
  const int b = row >> 11, i = row & (NPTS - 1);
  const float* __restrict__ xb = x + (size_t)b * 3 * NPTS;
  const float xi0 = xb[i], xi1 = xb[NPTS + i], xi2 = xb[2 * NPTS + i];
  float sd0 = 0, sd1 = 0, sd2 = 0, q00 = 0, q01 = 0, q02 = 0, q11 = 0, q12 = 0, q22 = 0;
  for (int k = 0; k < KNBR; ++k) {
    int j = idx1[(size_t)row * KNBR + k];
    float d0 = xb[j] - xi0, d1 = xb[NPTS + j] - xi1, d2 = xb[2 * NPTS + j] - xi2;
    sd0 += d0; sd1 += d1; sd2 += d2;
    q00 += d0 * d0; q01 += d0 * d1; q02 += d0 * d2;
    q11 += d1 * d1; q12 += d1 * d2; q22 += d2 * d2;
  }
  float v[27];
  v[0] = sd0; v[1] = sd1; v[2] = sd2; v[3] = 32.f * xi0; v[4] = 32.f * xi1; v[5] = 32.f * xi2;
  v[6] = q00; v[7] = q01; v[8] = q02; v[9] = sd0 * xi0; v[10] = sd0 * xi1; v[11] = sd0 * xi2;
  v[12] = q11; v[13] = q12; v[14] = sd1 * xi0; v[15] = sd1 * xi1; v[16] = sd1 * xi2;
  v[17] = q22; v[18] = sd2 * xi0; v[19] = sd2 * xi1; v[20] = sd2 * xi2;
  v[21] = 32.f * xi0 * xi0; v[22] = 32.f * xi0 * xi1; v[23] = 32.f * xi0 * xi2;
  v[24] = 32.f * xi1 * xi1; v[25] = 32.f * xi1 * xi2; v[26] = 32.f * xi2 * xi2;
  #pragma unroll
  for (int qq = 0; qq < 27; ++qq) {
    float s = v[qq];
    #pragma unroll
    for (int d = 1; d < 64; d <<= 1) s += __shfl_xor(s, d);
    if ((t & 63) == 0) atomicAdd(&red[qq], s);
  }
  __syncthreads();
  if (t < 27) atomicAdd(&stat[SF0 + t], red[t]);
}

// ---------------- K3: BN1 params from feature moments (linearity of conv) ----------------
__global__ void k_bnprep1(const float* __restrict__ stat, const float* __restrict__ w1,
                          const float* __restrict__ g1, const float* __restrict__ b1,
                          float* __restrict__ sc1, float* __restrict__ sh1) {
  __shared__ float M[36], mu[6];
  const int t = threadIdx.x;
  const float inv = 1.0f / SALL;
  if (t < 6) mu[t] = stat[SF0 + t] * inv;
  if (t < 36) {
    int a = t / 6, bq = t % 6;
    int aa = a < bq ? a : bq, bb = a < bq ? bq : a;
    int pos = aa * 6 - aa * (aa + 1) / 2 + bb;
    M[t] = stat[SF0 + 6 + pos] * inv;
  }
  __syncthreads();
  if (t < 128) {
    const float* w = w1 + t * 6;
    float m = 0.f;
    for (int c = 0; c < 6; ++c) m += w[c] * mu[c];
    float e2 = 0.f;
    for (int a = 0; a < 6; ++a)
      for (int c = 0; c < 6; ++c) e2 += w[a] * w[c] * M[a * 6 + c];
    float var = e2 - m * m;
    float rstd = rsqrtf(var + EPSV);
    float s = g1[t] * rstd;
    sc1[t] = s;
    sh1[t] = b1[t] - m * s;
  }
}

// ---------------- generic BN prep from sums/sumsq ----------------
__global__ void k_bnprep(const float* __restrict__ s, const float* __restrict__ ss,
                         const float* __restrict__ g, const float* __restrict__ bb,
                         float* __restrict__ sc, float* __restrict__ sh, int nch) {
  const int t = threadIdx.x;
  if (t < nch) {
    const float inv = 1.0f / SALL;
    float m = s[t] * inv;
    float var = ss[t] * inv - m * m;
    float rstd = rsqrtf(var + EPSV);
    float scale = g[t] * rstd;
    sc[t] = scale;
    sh[t] = bb[t] - m * scale;
  }
}

// ---------------- K4: fused gather + conv1 + BN1 + lrelu + conv2 (+stats2) (all fp32) ----------------
__global__ __launch_bounds__(256) void k_conv12(
    const float* __restrict__ x, const int* __restrict__ idx1,
    const float* __restrict__ w1, const float* __restrict__ w2,
    const float* __restrict__ sc1g, const float* __restrict__ sh1g,
    float* __restrict__ y2f, float* __restrict__ gS2, float* __restrict__ gSS2) {
  __shared__ float feat[6][64];
  __shared__ __align__(16) float z1l[128][64];
  __shared__ __align__(16) float w2l[64][64];
  __shared__ float s2l[64], ss2l[64];
  const int t = threadIdx.x;
  const int blk = blockIdx.x;  // 8192, 2 rows each
  const int row0 = blk * 2;
  const int b = row0 >> 11;
  const float* __restrict__ xb = x + (size_t)b * 3 * NPTS;
  if (t < 64) { s2l[t] = 0.f; ss2l[t] = 0.f; }
  if (t < 64) {
    int s = t, r = s >> 5, k = s & 31;
    int n = (row0 & (NPTS - 1)) + r;
    int j = idx1[(size_t)(row0 + r) * KNBR + k];
    float c0 = xb[n], c1 = xb[NPTS + n], c2 = xb[2 * NPTS + n];
    feat[0][s] = xb[j] - c0;
    feat[1][s] = xb[NPTS + j] - c1;
    feat[2][s] = xb[2 * NPTS + j] - c2;
    feat[3][s] = c0; feat[4][s] = c1; feat[5][s] = c2;
  }
  __syncthreads();
  {  // z1 = lrelu(BN1(conv1)), fp32
    const int s = t & 63, cb = (t >> 6) * 32;
    float f0 = feat[0][s], f1 = feat[1][s], f2c = feat[2][s];
    float f3 = feat[3][s], f4 = feat[4][s], f5 = feat[5][s];
    for (int ci = 0; ci < 32; ++ci) {
      int c = cb + ci;
      const float* wr = &w1[c * 6];
      float y = wr[0] * f0 + wr[1] * f1 + wr[2] * f2c + wr[3] * f3 + wr[4] * f4 + wr[5] * f5;
      float z = y * sc1g[c] + sh1g[c];
      z1l[c][s] = z > 0.f ? z : SLOPEV * z;
    }
  }
  float acc[4][4] = {};
  const int o0 = (t & 15) * 4, s0 = (t >> 4) * 4;
  const float4* __restrict__ w2v4 = reinterpret_cast<const float4*>(w2);
  for (int h = 0; h < 2; ++h) {  // chunk w2 (c in [64h,64h+64)) to fit LDS
    __syncthreads();
    for (int e = t; e < 1024; e += 256) {
      int o = e >> 4, eq = e & 15;
      float4 v = w2v4[o * 32 + eq + 16 * h];
      int cl = eq * 4;
      w2l[cl][o] = v.x; w2l[cl + 1][o] = v.y; w2l[cl + 2][o] = v.z; w2l[cl + 3][o] = v.w;
    }
    __syncthreads();
    for (int cl = 0; cl < 64; ++cl) {
      int c = 64 * h + cl;
      U4 wv; wv.u = *reinterpret_cast<const uint4*>(&w2l[cl][o0]);
      U4 zv; zv.u = *reinterpret_cast<const uint4*>(&z1l[c][s0]);
      #pragma unroll
      for (int a = 0; a < 4; ++a)
        #pragma unroll
        for (int q = 0; q < 4; ++q) acc[a][q] += wv.f[a] * zv.f[q];
    }
  }
  const size_t sb = (size_t)blk * 64 + s0;
  float sl[4] = {}, ssl[4] = {};
  #pragma unroll
  for (int q = 0; q < 4; ++q) {
    float4 st;
    st.x = acc[0][q]; st.y = acc[1][q]; st.z = acc[2][q]; st.w = acc[3][q];
    *reinterpret_cast<float4*>(&y2f[(sb + q) * 64 + o0]) = st;
    #pragma unroll
    for (int a = 0; a < 4; ++a) { float v = acc[a][q]; sl[a] += v; ssl[a] += v * v; }
  }
  #pragma unroll
  for (int a = 0; a < 4; ++a) {
    sl[a] += __shfl_xor(sl[a], 16); ssl[a] += __shfl_xor(ssl[a], 16);
    sl[a] += __shfl_xor(sl[a], 32); ssl[a] += __shfl_xor(ssl[a], 32);
  }
  if ((t & 63) < 16) {
    #pragma unroll
    for (int a = 0; a < 4; ++a) { atomicAdd(&s2l[o0 + a], sl[a]); atomicAdd(&ss2l[o0 + a], ssl[a]); }
  }
  __syncthreads();
  if (t < 64) atomicAdd(&gS2[t], s2l[t]);
  else if (t < 128) atomicAdd(&gSS2[t - 64], ss2l[t - 64]);
}

// ---------------- K6/K12: BN + lrelu + max over k ----------------
__global__ __launch_bounds__(256) void k_bnmax(
    const void* __restrict__ yv, const int isHalf,
    const float* __restrict__ scg, const float* __restrict__ shg,
    float* __restrict__ out, float* __restrict__ h1t, const int choff) {
  const int t = threadIdx.x, lane = t & 63, w = t >> 6;
  const int row = blockIdx.x * 4 + w;
  const int b = row >> 11, n = row & (NPTS - 1);
  const float sc = scg[lane], sh = shg[lane];
  const size_t base = (size_t)row * 32 * 64 + lane;
  float m = -3.0e38f;
  if (isHalf) {
    const _Float16* p = (const _Float16*)yv;
    for (int k = 0; k < 32; ++k) m = fmaxf(m, lrelu((float)p[base + (size_t)k * 64] * sc + sh));
  } else {
    const float* p = (const float*)yv;
    for (int k = 0; k < 32; ++k) m = fmaxf(m, lrelu(p[base + (size_t)k * 64] * sc + sh));
  }
  out[(size_t)b * 128 * NPTS + (size_t)(choff + lane) * NPTS + n] = m;
  if (h1t) h1t[(size_t)row * 64 + lane] = m;
}

// ---------------- K7: stage-2 top-k (C=64), tiled distances in LDS ----------------
__global__ __launch_bounds__(256) void k_topk2(const float* __restrict__ h1t, int* __restrict__ idx2) {
  __shared__ __align__(16) float tile[128 * 66];
  __shared__ __align__(16) float rowv[16][64];
  __shared__ float rsq[16];
  __shared__ float csq[128];
  const int t = threadIdx.x, lane = t & 63, w = t >> 6;
  const int rb = blockIdx.x * 16;
  const int b = rb >> 11;
  const float* __restrict__ hb = h1t + (size_t)b * NPTS * 64;
  const int i0 = rb & (NPTS - 1);
  for (int e = t; e < 1024; e += 256) rowv[e >> 6][e & 63] = hb[(size_t)i0 * 64 + e];
  __syncthreads();
  if (t < 16) {
    float s = 0.f;
    const float* rp = rowv[t];
    for (int c = 0; c < 64; ++c) { float v = rp[c]; s += v * v; }
    rsq[t] = s;
  }
  float nd[4][32];
  const int w4 = w * 4;
  #pragma unroll
  for (int tt = 0; tt < 16; ++tt) {  // 16 tiles of 128 candidates
    __syncthreads();
    const float4* __restrict__ src = reinterpret_cast<const float4*>(hb + (size_t)tt * 8192);
    for (int e = t; e < 2048; e += 256) {
      float4 v = src[e];
      int cand = e >> 4, c0 = (e & 15) << 2;
      float* dp = &tile[cand * 66 + c0];
      *reinterpret_cast<float2*>(dp) = make_float2(v.x, v.y);
      *reinterpret_cast<float2*>(dp + 2) = make_float2(v.z, v.w);
    }
    __syncthreads();
    if (t < 128) {
      float s = 0.f;
      const float* cp2 = &tile[t * 66];
      for (int c = 0; c < 64; ++c) { float v = cp2[c]; s += v * v; }
      csq[t] = s;
    }
    __syncthreads();
    float dot[4][2] = {{0.f, 0.f}, {0.f, 0.f}, {0.f, 0.f}, {0.f, 0.f}};
    for (int c2 = 0; c2 < 32; ++c2) {
      float2 rv0 = *reinterpret_cast<const float2*>(&rowv[w4 + 0][c2 * 2]);
      float2 rv1 = *reinterpret_cast<const float2*>(&rowv[w4 + 1][c2 * 2]);
      float2 rv2 = *reinterpret_cast<const float2*>(&rowv[w4 + 2][c2 * 2]);
      float2 rv3 = *reinterpret_cast<const float2*>(&rowv[w4 + 3][c2 * 2]);
      #pragma unroll
      for (int q = 0; q < 2; ++q) {
        float2 cv = *reinterpret_cast<const float2*>(&tile[(q * 64 + lane) * 66 + c2 * 2]);
        dot[0][q] += rv0.x * cv.x + rv0.y * cv.y;
        dot[1][q] += rv1.x * cv.x + rv1.y * cv.y;
        dot[2][q] += rv2.x * cv.x + rv2.y * cv.y;
        dot[3][q] += rv3.x * cv.x + rv3.y * cv.y;
      }
    }
    #pragma unroll
    for (int rr = 0; rr < 4; ++rr)
      #pragma unroll
      for (int q = 0; q < 2; ++q)
        nd[rr][tt * 2 + q] = (2.0f * dot[rr][q] - rsq[w4 + rr]) - csq[q * 64 + lane];
  }
  #pragma unroll
  for (int rr = 0; rr < 4; ++rr)
    extract_top32(nd[rr], lane, idx2 + (size_t)(rb + w4 + rr) * KNBR);
}

// ---------------- K8a: conv3 stats pass (fp16 LDS + v_dot2) ----------------
__global__ __launch_bounds__(256) void k_conv3(
    const float* __restrict__ h1t, const int* __restrict__ idx2,
    const float* __restrict__ w3, float* __restrict__ gS3, float* __restrict__ gSS3) {
  __shared__ __align__(16) f16x2 f2p[64][68];
  __shared__ __align__(16) f16x2 w3p[32][132];
  __shared__ float ctr[2][64];
  __shared__ float s3l[128], ss3l[128];
  const int t = threadIdx.x;
  const int blk = blockIdx.x;  // 8192, 2 rows each
  const int row0 = blk * 2;
  const int b = row0 >> 11;
  const float* __restrict__ hb = h1t + (size_t)b * NPTS * 64;
  if (t < 128) { s3l[t] = 0.f; ss3l[t] = 0.f; }
  if (t < 128) {
    int r = t >> 6, c = t & 63;
    ctr[r][c] = hb[(size_t)((row0 & (NPTS - 1)) + r) * 64 + c];
  }
  __syncthreads();
  {  // gather feat2 = [nbr-ctr ; ctr] into fp16 pairs
    int s = t >> 2, cq = t & 3;
    int r = s >> 5, k = s & 31;
    int j = idx2[(size_t)(row0 + r) * KNBR + k];
    const float* __restrict__ nv = hb + (size_t)j * 64 + cq * 16;
    #pragma unroll
    for (int cc = 0; cc < 16; cc += 2) {
      int c = cq * 16 + cc;
      f2p[c >> 1][s] = pack2(nv[cc] - ctr[r][c], nv[cc + 1] - ctr[r][c + 1]);
      f2p[32 + (c >> 1)][s] = pack2(ctr[r][c], ctr[r][c + 1]);
    }
  }
  float acc[4][8] = {};
  const int o0 = (t & 31) * 4, s0 = (t >> 5) * 8;
  const float4* __restrict__ w3v = reinterpret_cast<const float4*>(w3);
  for (int h = 0; h < 2; ++h) {
    __syncthreads();
    for (int e = t; e < 2048; e += 256) {
      int o = e >> 4, eq = e & 15;
      float4 v = w3v[o * 32 + eq + 16 * h];
      int cpl = eq * 2;
      w3p[cpl][o] = pack2(v.x, v.y);
      w3p[cpl + 1][o] = pack2(v.z, v.w);
    }
    __syncthreads();
    for (int cpl = 0; cpl < 32; ++cpl) {
      int cp = 32 * h + cpl;
      U4 wv; wv.u = *reinterpret_cast<const uint4*>(&w3p[cpl][o0]);
      U4 za; za.u = *reinterpret_cast<const uint4*>(&f2p[cp][s0]);
      U4 zb; zb.u = *reinterpret_cast<const uint4*>(&f2p[cp][s0 + 4]);
      #pragma unroll
      for (int a = 0; a < 4; ++a) {
        #pragma unroll
        for (int q = 0; q < 4; ++q) {
          acc[a][q] = fdot2f(wv.h[a], za.h[q], acc[a][q]);
          acc[a][q + 4] = fdot2f(wv.h[a], zb.h[q], acc[a][q + 4]);
        }
      }
    }
  }
  float sl[4] = {}, ssl[4] = {};
  #pragma unroll
  for (int a = 0; a < 4; ++a)
    #pragma unroll
    for (int q = 0; q < 8; ++q) { float v = acc[a][q]; sl[a] += v; ssl[a] += v * v; }
  #pragma unroll
  for (int a = 0; a < 4; ++a) { sl[a] += __shfl_xor(sl[a], 32); ssl[a] += __shfl_xor(ssl[a], 32); }
  if ((t & 63) < 32) {
    #pragma unroll
    for (int a = 0; a < 4; ++a) { atomicAdd(&s3l[o0 + a], sl[a]); atomicAdd(&ss3l[o0 + a], ssl[a]); }
  }
  __syncthreads();
  if (t < 128) atomicAdd(&gS3[t], s3l[t]);
  else atomicAdd(&gSS3[t - 128], ss3l[t - 128]);
}

// ---------------- K8b: recompute conv3 -> BN3+lrelu -> conv4 (+stats4, store y4 fp16) ----------------
__global__ __launch_bounds__(256) void k_conv4(
    const float* __restrict__ h1t, const int* __restrict__ idx2,
    const float* __restrict__ w3, const float* __restrict__ w4,
    const float* __restrict__ sc3g, const float* __restrict__ sh3g,
    _Float16* __restrict__ y4h, float* __restrict__ gS4, float* __restrict__ gSS4) {
  __shared__ __align__(16) f16x2 f2p[64][68];   // feat2, reused as z3 pairs
  __shared__ __align__(16) f16x2 w3p[32][132];
  __shared__ __align__(16) f16x2 w4p[64][68];
  __shared__ float ctr[2][64];
  __shared__ float s4l[64], ss4l[64];
  const int t = threadIdx.x;
  const int blk = blockIdx.x;  // 8192
  const int row0 = blk * 2;
  const int b = row0 >> 11;
  const float* __restrict__ hb = h1t + (size_t)b * NPTS * 64;
  if (t < 64) { s4l[t] = 0.f; ss4l[t] = 0.f; }
  if (t < 128) {
    int r = t >> 6, c = t & 63;
    ctr[r][c] = hb[(size_t)((row0 & (NPTS - 1)) + r) * 64 + c];
  }
  {
    const float4* __restrict__ w4v = reinterpret_cast<const float4*>(w4);
    for (int e = t; e < 2048; e += 256) {
      int o = e >> 5, eq = e & 31;
      float4 v = w4v[o * 32 + eq];
      w4p[eq * 2][o] = pack2(v.x, v.y);
      w4p[eq * 2 + 1][o] = pack2(v.z, v.w);
    }
  }
  __syncthreads();
  {
    int s = t >> 2, cq = t & 3;
    int r = s >> 5, k = s & 31;
    int j = idx2[(size_t)(row0 + r) * KNBR + k];
    const float* __restrict__ nv = hb + (size_t)j * 64 + cq * 16;
    #pragma unroll
    for (int cc = 0; cc < 16; cc += 2) {
      int c = cq * 16 + cc;
      f2p[c >> 1][s] = pack2(nv[cc] - ctr[r][c], nv[cc + 1] - ctr[r][c + 1]);
      f2p[32 + (c >> 1)][s] = pack2(ctr[r][c], ctr[r][c + 1]);
    }
  }
  float acc[4][8] = {};
  const int o0 = (t & 31) * 4, s0 = (t >> 5) * 8;
  const float4* __restrict__ w3v = reinterpret_cast<const float4*>(w3);
  for (int h = 0; h < 2; ++h) {
    __syncthreads();
    for (int e = t; e < 2048; e += 256) {
      int o = e >> 4, eq = e & 15;
      float4 v = w3v[o * 32 + eq + 16 * h];
      int cpl = eq * 2;
      w3p[cpl][o] = pack2(v.x, v.y);
      w3p[cpl + 1][o] = pack2(v.z, v.w);
    }
    __syncthreads();
    for (int cpl = 0; cpl < 32; ++cpl) {
      int cp = 32 * h + cpl;
      U4 wv; wv.u = *reinterpret_cast<const uint4*>(&w3p[cpl][o0]);
      U4 za; za.u = *reinterpret_cast<const uint4*>(&f2p[cp][s0]);
      U4 zb; zb.u = *reinterpret_cast<const uint4*>(&f2p[cp][s0 + 4]);
      #pragma unroll
      for (int a = 0; a < 4; ++a) {
        #pragma unroll
        for (int q = 0; q < 4; ++q) {
          acc[a][q] = fdot2f(wv.h[a], za.h[q], acc[a][q]);
          acc[a][q + 4] = fdot2f(wv.h[a], zb.h[q], acc[a][q + 4]);
        }
      }
    }
  }
  float zsc[4], zsh[4];
  #pragma unroll
  for (int a = 0; a < 4; ++a) { zsc[a] = sc3g[o0 + a]; zsh[a] = sh3g[o0 + a]; }
  __syncthreads();  // all f2p reads done, safe to overwrite with z3
  {
    int cpz = o0 >> 1;
    #pragma unroll
    for (int q = 0; q < 8; ++q) {
      float z0 = lrelu(acc[0][q] * zsc[0] + zsh[0]);
      float z1 = lrelu(acc[1][q] * zsc[1] + zsh[1]);
      float z2 = lrelu(acc[2][q] * zsc[2] + zsh[2]);
      float z3 = lrelu(acc[3][q] * zsc[3] + zsh[3]);
      f2p[cpz][s0 + q] = pack2(z0, z1);
      f2p[cpz + 1][s0 + q] = pack2(z2, z3);
    }
  }
  __syncthreads();
  float a4[4][4] = {};
  const int p0 = (t & 15) * 4, u0 = (t >> 4) * 4;
  for (int cp = 0; cp < 64; ++cp) {
    U4 wv; wv.u = *reinterpret_cast<const uint4*>(&w4p[cp][p0]);
    U4 zv; zv.u = *reinterpret_cast<const uint4*>(&f2p[cp][u0]);
    #pragma unroll
    for (int a = 0; a < 4; ++a)
      #pragma unroll
      for (int q = 0; q < 4; ++q) a4[a][q] = fdot2f(wv.h[a], zv.h[q], a4[a][q]);
  }
  const size_t sb = (size_t)blk * 64 + u0;
  float sl[4] = {}, ssl[4] = {};
  #pragma unroll
  for (int q = 0; q < 4; ++q) {
    #pragma unroll
    for (int a = 0; a < 4; ++a) { float v = a4[a][q]; sl[a] += v; ssl[a] += v * v; }
    U2f pk;
    pk.h[0] = pack2(a4[0][q], a4[1][q]);
    pk.h[1] = pack2(a4[2][q], a4[3][q]);
    *reinterpret_cast<uint2*>(&y4h[(sb + q) * 64 + p0]) = pk.u;
  }
  #pragma unroll
  for (int a = 0; a < 4; ++a) {
    sl[a] += __shfl_xor(sl[a], 16); ssl[a] += __shfl_xor(ssl[a], 16);
    sl[a] += __shfl_xor(sl[a], 32); ssl[a] += __shfl_xor(ssl[a], 32);
  }
  if ((t & 63) < 16) {
    #pragma unroll
    for (int a = 0; a < 4; ++a) { atomicAdd(&s4l[p0 + a], sl[a]); atomicAdd(&ss4l[p0 + a], ssl[a]); }
  }
  __syncthreads();
  if (t < 64) atomicAdd(&gS4[t], s4l[t]);
  else if (t < 128) atomicAdd(&gSS4[t - 64], ss4l[t - 64]);
}

// ---------------- host launcher ----------------
extern "C" void kernel_launch(void* const* d_in, const int* in_sizes, int n_in,
                              void* d_out, int out_size, void* d_ws, size_t ws_size,
                              hipStream_t stream) {
  const float* x = (const float*)d_in[0];
  const float* w1 = (const float*)d_in[1];
  const float* g1 = (const float*)d_in[2];
  const float* b1 = (const float*)d_in[3];
  const float* w2 = (const float*)d_in[4];
  const float* g2 = (const float*)d_in[5];
  const float* b2 = (const float*)d_in[6];
  const float* w3 = (const float*)d_in[7];
  const float* g3 = (const float*)d_in[8];
  const float* b3 = (const float*)d_in[9];
  const float* w4 = (const float*)d_in[10];
  const float* g4 = (const float*)d_in[11];
  const float* b4 = (const float*)d_in[12];
  float* out = (float*)d_out;
  char* ws = (char*)d_ws;
  int* idx1 = (int*)(ws + OFF_IDX1);
  int* idx2 = (int*)(ws + OFF_IDX2);
  float* h1t = (float*)(ws + OFF_H1T);
  float* stat = (float*)(ws + OFF_STAT);
  float* y2f = (float*)(ws + OFF_BIG);          // fp32 [S][64] = 128 MiB
  _Float16* y4h = (_Float16*)(ws + OFF_BIG);    // fp16 [S][64], reuses y2 region

  hipMemsetAsync(stat, 0, 8192, stream);
  hipLaunchKernelGGL(k_topk1, dim3(4096), dim3(256), 0, stream, x, idx1);
  hipLaunchKernelGGL(k_featstats, dim3(64), dim3(256), 0, stream, x, idx1, stat);
  hipLaunchKernelGGL(k_bnprep1, dim3(1), dim3(128), 0, stream, stat, w1, g1, b1, stat + SC1, stat + SH1);
  hipLaunchKernelGGL(k_conv12, dim3(8192), dim3(256), 0, stream, x, idx1, w1, w2,
                     stat + SC1, stat + SH1, y2f, stat + S2o, stat + SS2o);
  hipLaunchKernelGGL(k_bnprep, dim3(1), dim3(128), 0, stream, stat + S2o, stat + SS2o, g2, b2,
                     stat + SC2, stat + SH2, 64);
  hipLaunchKernelGGL(k_bnmax, dim3(4096), dim3(256), 0, stream, (const void*)y2f, 0,
                     stat + SC2, stat + SH2, out, h1t, 0);
  hipLaunchKernelGGL(k_topk2, dim3(1024), dim3(256), 0, stream, h1t, idx2);
  hipLaunchKernelGGL(k_conv3, dim3(8192), dim3(256), 0, stream, h1t, idx2, w3, stat + S3o, stat + SS3o);
  hipLaunchKernelGGL(k_bnprep, dim3(1), dim3(128), 0, stream, stat + S3o, stat + SS3o, g3, b3,
                     stat + SC3, stat + SH3, 128);
  hipLaunchKernelGGL(k_conv4, dim3(8192), dim3(256), 0, stream, h1t, idx2, w3, w4,
                     stat + SC3, stat + SH3, y4h, stat + S4o, stat + SS4o);
  hipLaunchKernelGGL(k_bnprep, dim3(1), dim3(128), 0, stream, stat + S4o, stat + SS4o, g4, b4,
                     stat + SC4, stat + SH4, 64);
  hipLaunchKernelGGL(k_bnmax, dim3(4096), dim3(256), 0, stream, (const void*)y4h, 1,
                     stat + SC4, stat + SH4, out, (float*)nullptr, 64);
  (void)in_sizes; (void)n_in; (void)out_size; (void)ws_size;
}

// Round 2
// 5543.698 us; speedup vs baseline: 1.4353x; 1.4353x over previous
//
#include <hip/hip_runtime.h>

#define DI __device__ __forceinline__

typedef _Float16 f16x2 __attribute__((ext_vector_type(2)));

#define NPTS 2048
#define KNBR 32
#define SALL 524288.0f
#define EPSV 1e-5f
#define SLOPEV 0.2f

// ---------------- workspace layout (bytes) ----------------
// requires ws_size >= 16 MiB + 128 MiB = 150,994,944
#define OFF_IDX1 0u
#define OFF_IDX2 (2u*1024u*1024u)
#define OFF_H1T  (4u*1024u*1024u)
#define OFF_STAT (8u*1024u*1024u)
#define OFF_BIG  (16u*1024u*1024u)
// stat float offsets
#define SF0 0
#define SC1 32
#define SH1 160
#define S2o 288
#define SS2o 352
#define SC2 416
#define SH2 480
#define S3o 544
#define SS3o 672
#define SC3 800
#define SH3 928
#define S4o 1056
#define SS4o 1120
#define SC4 1184
#define SH4 1248

union U4 { uint4 u; float f[4]; f16x2 h[4]; };
union U2f { uint2 u; f16x2 h[2]; };

DI f16x2 pack2(float a, float b) { f16x2 r; r.x = (_Float16)a; r.y = (_Float16)b; return r; }
DI float lrelu(float z) { return z > 0.f ? z : SLOPEV * z; }

DI float fdot2f(f16x2 a, f16x2 b, float c) {
#if __has_builtin(__builtin_amdgcn_fdot2)
  return __builtin_amdgcn_fdot2(a, b, c, false);
#else
  return c + (float)a.x * (float)b.x + (float)a.y * (float)b.y;
#endif
}

// Exact top-32 of 2048 values held as nd[s] per lane (value j = s*64+lane).
// 32 iterations of (lane-tree-max -> wave butterfly with lowest-index tie-break -> clear).
DI void extract_top32(float (&nd)[32], int lane, int* __restrict__ outp) {
  int myj = 0;
  #pragma nounroll
  for (int it = 0; it < 32; ++it) {
    float tm[16];
    #pragma unroll
    for (int s = 0; s < 16; ++s) tm[s] = fmaxf(nd[s], nd[s + 16]);
    #pragma unroll
    for (int s = 0; s < 8; ++s) tm[s] = fmaxf(tm[s], tm[s + 8]);
    #pragma unroll
    for (int s = 0; s < 4; ++s) tm[s] = fmaxf(tm[s], tm[s + 4]);
    float m = fmaxf(fmaxf(tm[0], tm[2]), fmaxf(tm[1], tm[3]));
    int slot = 0;
    #pragma unroll
    for (int s = 31; s >= 0; --s) slot = (nd[s] == m) ? s : slot;  // lowest slot wins
    int j = slot * 64 + lane;
    float v = m;
    #pragma unroll
    for (int d = 1; d < 64; d <<= 1) {
      float vo = __shfl_xor(v, d);
      int jo = __shfl_xor(j, d);
      bool take = (vo > v) || ((vo == v) && (jo < j));
      v = take ? vo : v;
      j = take ? jo : j;
    }
    int sel = (lane == (j & 63)) ? (j >> 6) : 64;
    #pragma unroll
    for (int s = 0; s < 32; ++s) nd[s] = (s == sel) ? -3.0e38f : nd[s];
    myj = (it == lane) ? j : myj;
  }
  if (lane < 32) outp[lane] = myj;
}

// ---------------- K1: stage-1 top-k (C=3) ----------------
__global__ __launch_bounds__(256) void k_topk1(const float* __restrict__ x, int* __restrict__ idx1) {
  __shared__ float xl[NPTS * 3];   // [n][c]
  __shared__ float sq[NPTS];
  const int t = threadIdx.x;
  const int blk4 = blockIdx.x * 4;
  const int b = blk4 >> 11;
  const float* __restrict__ xb = x + (size_t)b * 3 * NPTS;
  for (int e = t; e < 3 * NPTS; e += 256) {
    int c = e >> 11, n = e & (NPTS - 1);
    xl[n * 3 + c] = xb[e];
  }
  __syncthreads();
  for (int n = t; n < NPTS; n += 256) {
    float a0 = xl[n * 3], a1 = xl[n * 3 + 1], a2 = xl[n * 3 + 2];
    sq[n] = a0 * a0 + a1 * a1 + a2 * a2;
  }
  __syncthreads();
  const int lane = t & 63, w = t >> 6;
  const int row = blk4 + w;
  const int i = row & (NPTS - 1);
  const float xi0 = xl[i * 3], xi1 = xl[i * 3 + 1], xi2 = xl[i * 3 + 2];
  const float si = sq[i];
  float nd[32];
  #pragma unroll
  for (int s = 0; s < 32; ++s) {
    int j = s * 64 + lane;
    float d = xi0 * xl[j * 3] + xi1 * xl[j * 3 + 1] + xi2 * xl[j * 3 + 2];
    nd[s] = (2.0f * d - si) - sq[j];
  }
  extract_top32(nd, lane, idx1 + (size_t)row * KNBR);
}

// ---------------- K2: feat1 moments (6 means + 21 second moments) ----------------
__global__ __launch_bounds__(256) void k_featstats(const float* __restrict__ x,
                                                   const int* __restrict__ idx1,
                                                   float* __restrict__ stat) {
  __shared__ float red[27];
  const int t = threadIdx.x;
  if (t < 27) red[t] = 0.f;
  __syncthreads();
  const int row = blockIdx.x * 256 + t;
  const int b = row >> 11, i = row & (NPTS - 1);
  const float* __restrict__ xb = x + (size_t)b * 3 * NPTS;
  const float xi0 = xb[i], xi1 = xb[NPTS + i], xi2 = xb[2 * NPTS + i];
  float sd0 = 0, sd1 = 0, sd2 = 0, q00 = 0, q01 = 0, q02 = 0, q11 = 0, q12 = 0, q22 = 0;
  for (int k = 0; k < KNBR; ++k) {
    int j = idx1[(size_t)row * KNBR + k];
    float d0 = xb[j] - xi0, d1 = xb[NPTS + j] - xi1, d2 = xb[2 * NPTS + j] - xi2;
    sd0 += d0; sd1 += d1; sd2 += d2;
    q00 += d0 * d0; q01 += d0 * d1; q02 += d0 * d2;
    q11 += d1 * d1; q12 += d1 * d2; q22 += d2 * d2;
  }
  float v[27];
  v[0] = sd0; v[1] = sd1; v[2] = sd2; v[3] = 32.f * xi0; v[4] = 32.f * xi1; v[5] = 32.f * xi2;
  v[6] = q00; v[7] = q01; v[8] = q02; v[9] = sd0 * xi0; v[10] = sd0 * xi1; v[11] = sd0 * xi2;
  v[12] = q11; v[13] = q12; v[14] = sd1 * xi0; v[15] = sd1 * xi1; v[16] = sd1 * xi2;
  v[17] = q22; v[18] = sd2 * xi0; v[19] = sd2 * xi1; v[20] = sd2 * xi2;
  v[21] = 32.f * xi0 * xi0; v[22] = 32.f * xi0 * xi1; v[23] = 32.f * xi0 * xi2;
  v[24] = 32.f * xi1 * xi1; v[25] = 32.f * xi1 * xi2; v[26] = 32.f * xi2 * xi2;
  #pragma unroll
  for (int qq = 0; qq < 27; ++qq) {
    float s = v[qq];
    #pragma unroll
    for (int d = 1; d < 64; d <<= 1) s += __shfl_xor(s, d);
    if ((t & 63) == 0) atomicAdd(&red[qq], s);
  }
  __syncthreads();
  if (t < 27) atomicAdd(&stat[SF0 + t], red[t]);
}

// ---------------- K3: BN1 params from feature moments (linearity of conv) ----------------
__global__ void k_bnprep1(const float* __restrict__ stat, const float* __restrict__ w1,
                          const float* __restrict__ g1, const float* __restrict__ b1,
                          float* __restrict__ sc1, float* __restrict__ sh1) {
  __shared__ float M[36], mu[6];
  const int t = threadIdx.x;
  const float inv = 1.0f / SALL;
  if (t < 6) mu[t] = stat[SF0 + t] * inv;
  if (t < 36) {
    int a = t / 6, bq = t % 6;
    int aa = a < bq ? a : bq, bb = a < bq ? bq : a;
    int pos = aa * 6 - aa * (aa + 1) / 2 + bb;
    M[t] = stat[SF0 + 6 + pos] * inv;
  }
  __syncthreads();
  if (t < 128) {
    const float* w = w1 + t * 6;
    float m = 0.f;
    for (int c = 0; c < 6; ++c) m += w[c] * mu[c];
    float e2 = 0.f;
    for (int a = 0; a < 6; ++a)
      for (int c = 0; c < 6; ++c) e2 += w[a] * w[c] * M[a * 6 + c];
    float var = e2 - m * m;
    float rstd = rsqrtf(var + EPSV);
    float s = g1[t] * rstd;
    sc1[t] = s;
    sh1[t] = b1[t] - m * s;
  }
}

// ---------------- generic BN prep from sums/sumsq ----------------
__global__ void k_bnprep(const float* __restrict__ s, const float* __restrict__ ss,
                         const float* __restrict__ g, const float* __restrict__ bb,
                         float* __restrict__ sc, float* __restrict__ sh, int nch) {
  const int t = threadIdx.x;
  if (t < nch) {
    const float inv = 1.0f / SALL;
    float m = s[t] * inv;
    float var = ss[t] * inv - m * m;
    float rstd = rsqrtf(var + EPSV);
    float scale = g[t] * rstd;
    sc[t] = scale;
    sh[t] = bb[t] - m * scale;
  }
}

// ---------------- K4: fused gather + conv1 + BN1 + lrelu + conv2 (+stats2) (all fp32) ----------------
__global__ __launch_bounds__(256) void k_conv12(
    const float* __restrict__ x, const int* __restrict__ idx1,
    const float* __restrict__ w1, const float* __restrict__ w2,
    const float* __restrict__ sc1g, const float* __restrict__ sh1g,
    float* __restrict__ y2f, float* __restrict__ gS2, float* __restrict__ gSS2) {
  __shared__ float feat[6][64];
  __shared__ __align__(16) float z1l[128][64];
  __shared__ __align__(16) float w2l[64][64];
  __shared__ float s2l[64], ss2l[64];
  const int t = threadIdx.x;
  const int blk = blockIdx.x;  // 8192, 2 rows each
  const int row0 = blk * 2;
  const int b = row0 >> 11;
  const float* __restrict__ xb = x + (size_t)b * 3 * NPTS;
  if (t < 64) { s2l[t] = 0.f; ss2l[t] = 0.f; }
  if (t < 64) {
    int s = t, r = s >> 5, k = s & 31;
    int n = (row0 & (NPTS - 1)) + r;
    int j = idx1[(size_t)(row0 + r) * KNBR + k];
    float c0 = xb[n], c1 = xb[NPTS + n], c2 = xb[2 * NPTS + n];
    feat[0][s] = xb[j] - c0;
    feat[1][s] = xb[NPTS + j] - c1;
    feat[2][s] = xb[2 * NPTS + j] - c2;
    feat[3][s] = c0; feat[4][s] = c1; feat[5][s] = c2;
  }
  __syncthreads();
  {  // z1 = lrelu(BN1(conv1)), fp32
    const int s = t & 63, cb = (t >> 6) * 32;
    float f0 = feat[0][s], f1 = feat[1][s], f2c = feat[2][s];
    float f3 = feat[3][s], f4 = feat[4][s], f5 = feat[5][s];
    for (int ci = 0; ci < 32; ++ci) {
      int c = cb + ci;
      const float* wr = &w1[c * 6];
      float y = wr[0] * f0 + wr[1] * f1 + wr[2] * f2c + wr[3] * f3 + wr[4] * f4 + wr[5] * f5;
      float z = y * sc1g[c] + sh1g[c];
      z1l[c][s] = z > 0.f ? z : SLOPEV * z;
    }
  }
  float acc[4][4] = {};
  const int o0 = (t & 15) * 4, s0 = (t >> 4) * 4;
  const float4* __restrict__ w2v4 = reinterpret_cast<const float4*>(w2);
  for (int h = 0; h < 2; ++h) {  // chunk w2 (c in [64h,64h+64)) to fit LDS
    __syncthreads();
    for (int e = t; e < 1024; e += 256) {
      int o = e >> 4, eq = e & 15;
      float4 v = w2v4[o * 32 + eq + 16 * h];
      int cl = eq * 4;
      w2l[cl][o] = v.x; w2l[cl + 1][o] = v.y; w2l[cl + 2][o] = v.z; w2l[cl + 3][o] = v.w;
    }
    __syncthreads();
    for (int cl = 0; cl < 64; ++cl) {
      int c = 64 * h + cl;
      U4 wv; wv.u = *reinterpret_cast<const uint4*>(&w2l[cl][o0]);
      U4 zv; zv.u = *reinterpret_cast<const uint4*>(&z1l[c][s0]);
      #pragma unroll
      for (int a = 0; a < 4; ++a)
        #pragma unroll
        for (int q = 0; q < 4; ++q) acc[a][q] += wv.f[a] * zv.f[q];
    }
  }
  const size_t sb = (size_t)blk * 64 + s0;
  float sl[4] = {}, ssl[4] = {};
  #pragma unroll
  for (int q = 0; q < 4; ++q) {
    float4 st;
    st.x = acc[0][q]; st.y = acc[1][q]; st.z = acc[2][q]; st.w = acc[3][q];
    *reinterpret_cast<float4*>(&y2f[(sb + q) * 64 + o0]) = st;
    #pragma unroll
    for (int a = 0; a < 4; ++a) { float v = acc[a][q]; sl[a] += v; ssl[a] += v * v; }
  }
  #pragma unroll
  for (int a = 0; a < 4; ++a) {
    sl[a] += __shfl_xor(sl[a], 16); ssl[a] += __shfl_xor(ssl[a], 16);
    sl[a] += __shfl_xor(sl[a], 32); ssl[a] += __shfl_xor(ssl[a], 32);
  }
  if ((t & 63) < 16) {
    #pragma unroll
    for (int a = 0; a < 4; ++a) { atomicAdd(&s2l[o0 + a], sl[a]); atomicAdd(&ss2l[o0 + a], ssl[a]); }
  }
  __syncthreads();
  if (t < 64) atomicAdd(&gS2[t], s2l[t]);
  else if (t < 128) atomicAdd(&gSS2[t - 64], ss2l[t - 64]);
}

// ---------------- K6/K12: BN + lrelu + max over k ----------------
__global__ __launch_bounds__(256) void k_bnmax(
    const void* __restrict__ yv, const int isHalf,
    const float* __restrict__ scg, const float* __restrict__ shg,
    float* __restrict__ out, float* __restrict__ h1t, const int choff) {
  const int t = threadIdx.x, lane = t & 63, w = t >> 6;
  const int row = blockIdx.x * 4 + w;
  const int b = row >> 11, n = row & (NPTS - 1);
  const float sc = scg[lane], sh = shg[lane];
  const size_t base = (size_t)row * 32 * 64 + lane;
  float m = -3.0e38f;
  if (isHalf) {
    const _Float16* p = (const _Float16*)yv;
    for (int k = 0; k < 32; ++k) m = fmaxf(m, lrelu((float)p[base + (size_t)k * 64] * sc + sh));
  } else {
    const float* p = (const float*)yv;
    for (int k = 0; k < 32; ++k) m = fmaxf(m, lrelu(p[base + (size_t)k * 64] * sc + sh));
  }
  out[(size_t)b * 128 * NPTS + (size_t)(choff + lane) * NPTS + n] = m;
  if (h1t) h1t[(size_t)row * 64 + lane] = m;
}

// ---------------- K7: stage-2 top-k (C=64) ----------------
// One row per wave (nd[32] = 32 VGPRs -> no scratch spill). 8 waves/block,
// block loads candidate tiles of 128 into LDS; csq fused into the dot loop.
__global__ __launch_bounds__(512) void k_topk2(const float* __restrict__ h1t, int* __restrict__ idx2) {
  __shared__ __align__(16) float tile[128 * 66];
  __shared__ __align__(16) float rowv[8][64];
  const int t = threadIdx.x, lane = t & 63, w = t >> 6;  // 8 waves
  const int rb = blockIdx.x * 8;
  const int b = rb >> 11;
  const float* __restrict__ hb = h1t + (size_t)b * NPTS * 64;
  const int i0 = rb & (NPTS - 1);
  rowv[w][lane] = hb[(size_t)i0 * 64 + t];  // 8 rows x 64 ch, one pass
  __syncthreads();
  // per-wave row norm, kept in registers (all lanes end up with the sum)
  float rsqw;
  {
    float v = rowv[w][lane];
    float s = v * v;
    #pragma unroll
    for (int d = 1; d < 64; d <<= 1) s += __shfl_xor(s, d);
    rsqw = s;
  }
  float nd[32];
  #pragma unroll
  for (int tt = 0; tt < 16; ++tt) {  // 16 tiles of 128 candidates
    __syncthreads();
    const float4* __restrict__ src = reinterpret_cast<const float4*>(hb + (size_t)tt * 8192);
    for (int e = t; e < 2048; e += 512) {
      float4 v = src[e];
      int cand = e >> 4, c0 = (e & 15) << 2;
      float* dp = &tile[cand * 66 + c0];
      *reinterpret_cast<float2*>(dp) = make_float2(v.x, v.y);
      *reinterpret_cast<float2*>(dp + 2) = make_float2(v.z, v.w);
    }
    __syncthreads();
    // dot + candidate-norm fused: lane owns candidates tt*128+lane and tt*128+64+lane
    float dot0 = 0.f, dot1 = 0.f, cs0 = 0.f, cs1 = 0.f;
    const float* rp = rowv[w];
    const float* cp0 = &tile[lane * 66];
    const float* cp1 = &tile[(64 + lane) * 66];
    #pragma unroll
    for (int c2 = 0; c2 < 32; ++c2) {
      float2 rv = *reinterpret_cast<const float2*>(&rp[c2 * 2]);
      float2 v0 = *reinterpret_cast<const float2*>(&cp0[c2 * 2]);
      float2 v1 = *reinterpret_cast<const float2*>(&cp1[c2 * 2]);
      dot0 += rv.x * v0.x + rv.y * v0.y;
      dot1 += rv.x * v1.x + rv.y * v1.y;
      cs0 += v0.x * v0.x + v0.y * v0.y;
      cs1 += v1.x * v1.x + v1.y * v1.y;
    }
    nd[tt * 2] = (2.0f * dot0 - rsqw) - cs0;
    nd[tt * 2 + 1] = (2.0f * dot1 - rsqw) - cs1;
  }
  extract_top32(nd, lane, idx2 + (size_t)(rb + w) * KNBR);
}

// ---------------- K8a: conv3 stats pass (fp16 LDS + v_dot2) ----------------
__global__ __launch_bounds__(256) void k_conv3(
    const float* __restrict__ h1t, const int* __restrict__ idx2,
    const float* __restrict__ w3, float* __restrict__ gS3, float* __restrict__ gSS3) {
  __shared__ __align__(16) f16x2 f2p[64][68];
  __shared__ __align__(16) f16x2 w3p[32][132];
  __shared__ float ctr[2][64];
  __shared__ float s3l[128], ss3l[128];
  const int t = threadIdx.x;
  const int blk = blockIdx.x;  // 8192, 2 rows each
  const int row0 = blk * 2;
  const int b = row0 >> 11;
  const float* __restrict__ hb = h1t + (size_t)b * NPTS * 64;
  if (t < 128) { s3l[t] = 0.f; ss3l[t] = 0.f; }
  if (t < 128) {
    int r = t >> 6, c = t & 63;
    ctr[r][c] = hb[(size_t)((row0 & (NPTS - 1)) + r) * 64 + c];
  }
  __syncthreads();
  {  // gather feat2 = [nbr-ctr ; ctr] into fp16 pairs
    int s = t >> 2, cq = t & 3;
    int r = s >> 5, k = s & 31;
    int j = idx2[(size_t)(row0 + r) * KNBR + k];
    const float* __restrict__ nv = hb + (size_t)j * 64 + cq * 16;
    #pragma unroll
    for (int cc = 0; cc < 16; cc += 2) {
      int c = cq * 16 + cc;
      f2p[c >> 1][s] = pack2(nv[cc] - ctr[r][c], nv[cc + 1] - ctr[r][c + 1]);
      f2p[32 + (c >> 1)][s] = pack2(ctr[r][c], ctr[r][c + 1]);
    }
  }
  float acc[4][8] = {};
  const int o0 = (t & 31) * 4, s0 = (t >> 5) * 8;
  const float4* __restrict__ w3v = reinterpret_cast<const float4*>(w3);
  for (int h = 0; h < 2; ++h) {
    __syncthreads();
    for (int e = t; e < 2048; e += 256) {
      int o = e >> 4, eq = e & 15;
      float4 v = w3v[o * 32 + eq + 16 * h];
      int cpl = eq * 2;
      w3p[cpl][o] = pack2(v.x, v.y);
      w3p[cpl + 1][o] = pack2(v.z, v.w);
    }
    __syncthreads();
    for (int cpl = 0; cpl < 32; ++cpl) {
      int cp = 32 * h + cpl;
      U4 wv; wv.u = *reinterpret_cast<const uint4*>(&w3p[cpl][o0]);
      U4 za; za.u = *reinterpret_cast<const uint4*>(&f2p[cp][s0]);
      U4 zb; zb.u = *reinterpret_cast<const uint4*>(&f2p[cp][s0 + 4]);
      #pragma unroll
      for (int a = 0; a < 4; ++a) {
        #pragma unroll
        for (int q = 0; q < 4; ++q) {
          acc[a][q] = fdot2f(wv.h[a], za.h[q], acc[a][q]);
          acc[a][q + 4] = fdot2f(wv.h[a], zb.h[q], acc[a][q + 4]);
        }
      }
    }
  }
  float sl[4] = {}, ssl[4] = {};
  #pragma unroll
  for (int a = 0; a < 4; ++a)
    #pragma unroll
    for (int q = 0; q < 8; ++q) { float v = acc[a][q]; sl[a] += v; ssl[a] += v * v; }
  #pragma unroll
  for (int a = 0; a < 4; ++a) { sl[a] += __shfl_xor(sl[a], 32); ssl[a] += __shfl_xor(ssl[a], 32); }
  if ((t & 63) < 32) {
    #pragma unroll
    for (int a = 0; a < 4; ++a) { atomicAdd(&s3l[o0 + a], sl[a]); atomicAdd(&ss3l[o0 + a], ssl[a]); }
  }
  __syncthreads();
  if (t < 128) atomicAdd(&gS3[t], s3l[t]);
  else atomicAdd(&gSS3[t - 128], ss3l[t - 128]);
}

// ---------------- K8b: recompute conv3 -> BN3+lrelu -> conv4 (+stats4, store y4 fp16) ----------------
__global__ __launch_bounds__(256) void k_conv4(
    const float* __restrict__ h1t, const int* __restrict__ idx2,
    const float* __restrict__ w3, const float* __restrict__ w4,
    const float* __restrict__ sc3g, const float* __restrict__ sh3g,
    _Float16* __restrict__ y4h, float* __restrict__ gS4, float* __restrict__ gSS4) {
  __shared__ __align__(16) f16x2 f2p[64][68];   // feat2, reused as z3 pairs
  __shared__ __align__(16) f16x2 w3p[32][132];
  __shared__ __align__(16) f16x2 w4p[64][68];
  __shared__ float ctr[2][64];
  __shared__ float s4l[64], ss4l[64];
  const int t = threadIdx.x;
  const int blk = blockIdx.x;  // 8192
  const int row0 = blk * 2;
  const int b = row0 >> 11;
  const float* __restrict__ hb = h1t + (size_t)b * NPTS * 64;
  if (t < 64) { s4l[t] = 0.f; ss4l[t] = 0.f; }
  if (t < 128) {
    int r = t >> 6, c = t & 63;
    ctr[r][c] = hb[(size_t)((row0 & (NPTS - 1)) + r) * 64 + c];
  }
  {
    const float4* __restrict__ w4v = reinterpret_cast<const float4*>(w4);
    for (int e = t; e < 2048; e += 256) {
      int o = e >> 5, eq = e & 31;
      float4 v = w4v[o * 32 + eq];
      w4p[eq * 2][o] = pack2(v.x, v.y);
      w4p[eq * 2 + 1][o] = pack2(v.z, v.w);
    }
  }
  __syncthreads();
  {
    int s = t >> 2, cq = t & 3;
    int r = s >> 5, k = s & 31;
    int j = idx2[(size_t)(row0 + r) * KNBR + k];
    const float* __restrict__ nv = hb + (size_t)j * 64 + cq * 16;
    #pragma unroll
    for (int cc = 0; cc < 16; cc += 2) {
      int c = cq * 16 + cc;
      f2p[c >> 1][s] = pack2(nv[cc] - ctr[r][c], nv[cc + 1] - ctr[r][c + 1]);
      f2p[32 + (c >> 1)][s] = pack2(ctr[r][c], ctr[r][c + 1]);
    }
  }
  float acc[4][8] = {};
  const int o0 = (t & 31) * 4, s0 = (t >> 5) * 8;
  const float4* __restrict__ w3v = reinterpret_cast<const float4*>(w3);
  for (int h = 0; h < 2; ++h) {
    __syncthreads();
    for (int e = t; e < 2048; e += 256) {
      int o = e >> 4, eq = e & 15;
      float4 v = w3v[o * 32 + eq + 16 * h];
      int cpl = eq * 2;
      w3p[cpl][o] = pack2(v.x, v.y);
      w3p[cpl + 1][o] = pack2(v.z, v.w);
    }
    __syncthreads();
    for (int cpl = 0; cpl < 32; ++cpl) {
      int cp = 32 * h + cpl;
      U4 wv; wv.u = *reinterpret_cast<const uint4*>(&w3p[cpl][o0]);
      U4 za; za.u = *reinterpret_cast<const uint4*>(&f2p[cp][s0]);
      U4 zb; zb.u = *reinterpret_cast<const uint4*>(&f2p[cp][s0 + 4]);
      #pragma unroll
      for (int a = 0; a < 4; ++a) {
        #pragma unroll
        for (int q = 0; q < 4; ++q) {
          acc[a][q] = fdot2f(wv.h[a], za.h[q], acc[a][q]);
          acc[a][q + 4] = fdot2f(wv.h[a], zb.h[q], acc[a][q + 4]);
        }
      }
    }
  }
  float zsc[4], zsh[4];
  #pragma unroll
  for (int a = 0; a < 4; ++a) { zsc[a] = sc3g[o0 + a]; zsh[a] = sh3g[o0 + a]; }
  __syncthreads();  // all f2p reads done, safe to overwrite with z3
  {
    int cpz = o0 >> 1;
    #pragma unroll
    for (int q = 0; q < 8; ++q) {
      float z0 = lrelu(acc[0][q] * zsc[0] + zsh[0]);
      float z1 = lrelu(acc[1][q] * zsc[1] + zsh[1]);
      float z2 = lrelu(acc[2][q] * zsc[2] + zsh[2]);
      float z3 = lrelu(acc[3][q] * zsc[3] + zsh[3]);
      f2p[cpz][s0 + q] = pack2(z0, z1);
      f2p[cpz + 1][s0 + q] = pack2(z2, z3);
    }
  }
  __syncthreads();
  float a4[4][4] = {};
  const int p0 = (t & 15) * 4, u0 = (t >> 4) * 4;
  for (int cp = 0; cp < 64; ++cp) {
    U4 wv; wv.u = *reinterpret_cast<const uint4*>(&w4p[cp][p0]);
    U4 zv; zv.u = *reinterpret_cast<const uint4*>(&f2p[cp][u0]);
    #pragma unroll
    for (int a = 0; a < 4; ++a)
      #pragma unroll
      for (int q = 0; q < 4; ++q) a4[a][q] = fdot2f(wv.h[a], zv.h[q], a4[a][q]);
  }
  const size_t sb = (size_t)blk * 64 + u0;
  float sl[4] = {}, ssl[4] = {};
  #pragma unroll
  for (int q = 0; q < 4; ++q) {
    #pragma unroll
    for (int a = 0; a < 4; ++a) { float v = a4[a][q]; sl[a] += v; ssl[a] += v * v; }
    U2f pk;
    pk.h[0] = pack2(a4[0][q], a4[1][q]);
    pk.h[1] = pack2(a4[2][q], a4[3][q]);
    *reinterpret_cast<uint2*>(&y4h[(sb + q) * 64 + p0]) = pk.u;
  }
  #pragma unroll
  for (int a = 0; a < 4; ++a) {
    sl[a] += __shfl_xor(sl[a], 16); ssl[a] += __shfl_xor(ssl[a], 16);
    sl[a] += __shfl_xor(sl[a], 32); ssl[a] += __shfl_xor(ssl[a], 32);
  }
  if ((t & 63) < 16) {
    #pragma unroll
    for (int a = 0; a < 4; ++a) { atomicAdd(&s4l[p0 + a], sl[a]); atomicAdd(&ss4l[p0 + a], ssl[a]); }
  }
  __syncthreads();
  if (t < 64) atomicAdd(&gS4[t], s4l[t]);
  else if (t < 128) atomicAdd(&gSS4[t - 64], ss4l[t - 64]);
}

// ---------------- host launcher ----------------
extern "C" void kernel_launch(void* const* d_in, const int* in_sizes, int n_in,
                              void* d_out, int out_size, void* d_ws, size_t ws_size,
                              hipStream_t stream) {
  const float* x = (const float*)d_in[0];
  const float* w1 = (const float*)d_in[1];
  const float* g1 = (const float*)d_in[2];
  const float* b1 = (const float*)d_in[3];
  const float* w2 = (const float*)d_in[4];
  const float* g2 = (const float*)d_in[5];
  const float* b2 = (const float*)d_in[6];
  const float* w3 = (const float*)d_in[7];
  const float* g3 = (const float*)d_in[8];
  const float* b3 = (const float*)d_in[9];
  const float* w4 = (const float*)d_in[10];
  const float* g4 = (const float*)d_in[11];
  const float* b4 = (const float*)d_in[12];
  float* out = (float*)d_out;
  char* ws = (char*)d_ws;
  int* idx1 = (int*)(ws + OFF_IDX1);
  int* idx2 = (int*)(ws + OFF_IDX2);
  float* h1t = (float*)(ws + OFF_H1T);
  float* stat = (float*)(ws + OFF_STAT);
  float* y2f = (float*)(ws + OFF_BIG);          // fp32 [S][64] = 128 MiB
  _Float16* y4h = (_Float16*)(ws + OFF_BIG);    // fp16 [S][64], reuses y2 region

  hipMemsetAsync(stat, 0, 8192, stream);
  hipLaunchKernelGGL(k_topk1, dim3(4096), dim3(256), 0, stream, x, idx1);
  hipLaunchKernelGGL(k_featstats, dim3(64), dim3(256), 0, stream, x, idx1, stat);
  hipLaunchKernelGGL(k_bnprep1, dim3(1), dim3(128), 0, stream, stat, w1, g1, b1, stat + SC1, stat + SH1);
  hipLaunchKernelGGL(k_conv12, dim3(8192), dim3(256), 0, stream, x, idx1, w1, w2,
                     stat + SC1, stat + SH1, y2f, stat + S2o, stat + SS2o);
  hipLaunchKernelGGL(k_bnprep, dim3(1), dim3(128), 0, stream, stat + S2o, stat + SS2o, g2, b2,
                     stat + SC2, stat + SH2, 64);
  hipLaunchKernelGGL(k_bnmax, dim3(4096), dim3(256), 0, stream, (const void*)y2f, 0,
                     stat + SC2, stat + SH2, out, h1t, 0);
  hipLaunchKernelGGL(k_topk2, dim3(2048), dim3(512), 0, stream, h1t, idx2);
  hipLaunchKernelGGL(k_conv3, dim3(8192), dim3(256), 0, stream, h1t, idx2, w3, stat + S3o, stat + SS3o);
  hipLaunchKernelGGL(k_bnprep, dim3(1), dim3(128), 0, stream, stat + S3o, stat + SS3o, g3, b3,
                     stat + SC3, stat + SH3, 128);
  hipLaunchKernelGGL(k_conv4, dim3(8192), dim3(256), 0, stream, h1t, idx2, w3, w4,
                     stat + SC3, stat + SH3, y4h, stat + S4o, stat + SS4o);
  hipLaunchKernelGGL(k_bnprep, dim3(1), dim3(128), 0, stream, stat + S4o, stat + SS4o, g4, b4,
                     stat + SC4, stat + SH4, 64);
  hipLaunchKernelGGL(k_bnmax, dim3(4096), dim3(256), 0, stream, (const void*)y4h, 1,
                     stat + SC4, stat + SH4, out, (float*)nullptr, 64);
  (void)in_sizes; (void)n_in; (void)out_size; (void)ws_size;
}

// Round 3
// 1285.797 us; speedup vs baseline: 6.1884x; 4.3115x over previous
//
#include <hip/hip_runtime.h>

#define DI __device__ __forceinline__

typedef _Float16 f16x2 __attribute__((ext_vector_type(2)));

#define NPTS 2048
#define KNBR 32
#define SALL 524288.0f
#define EPSV 1e-5f
#define SLOPEV 0.2f

// ---------------- workspace layout (bytes) ----------------
// requires ws_size >= 16 MiB + 128 MiB = 150,994,944
#define OFF_IDX1 0u
#define OFF_IDX2 (2u*1024u*1024u)
#define OFF_H1T  (4u*1024u*1024u)
#define OFF_STAT (8u*1024u*1024u)
#define OFF_NSQ  (9u*1024u*1024u)
#define OFF_BIG  (16u*1024u*1024u)
// stat float offsets
#define SF0 0
#define SC1 32
#define SH1 160
#define S2o 288
#define SS2o 352
#define SC2 416
#define SH2 480
#define S3o 544
#define SS3o 672
#define SC3 800
#define SH3 928
#define S4o 1056
#define SS4o 1120
#define SC4 1184
#define SH4 1248

union U4 { uint4 u; float f[4]; f16x2 h[4]; };
union U2f { uint2 u; f16x2 h[2]; };

DI f16x2 pack2(float a, float b) { f16x2 r; r.x = (_Float16)a; r.y = (_Float16)b; return r; }
DI float lrelu(float z) { return z > 0.f ? z : SLOPEV * z; }

DI float fdot2f(f16x2 a, f16x2 b, float c) {
#if __has_builtin(__builtin_amdgcn_fdot2)
  return __builtin_amdgcn_fdot2(a, b, c, false);
#else
  return c + (float)a.x * (float)b.x + (float)a.y * (float)b.y;
#endif
}

// Exact top-32 of 2048 values held as nd[s] per lane (value j = s*64+lane).
// 32 iterations of (lane-tree-max -> wave butterfly with lowest-index tie-break -> clear).
DI void extract_top32(float (&nd)[32], int lane, int* __restrict__ outp) {
  int myj = 0;
  #pragma nounroll
  for (int it = 0; it < 32; ++it) {
    float tm[16];
    #pragma unroll
    for (int s = 0; s < 16; ++s) tm[s] = fmaxf(nd[s], nd[s + 16]);
    #pragma unroll
    for (int s = 0; s < 8; ++s) tm[s] = fmaxf(tm[s], tm[s + 8]);
    #pragma unroll
    for (int s = 0; s < 4; ++s) tm[s] = fmaxf(tm[s], tm[s + 4]);
    float m = fmaxf(fmaxf(tm[0], tm[2]), fmaxf(tm[1], tm[3]));
    int slot = 0;
    #pragma unroll
    for (int s = 31; s >= 0; --s) slot = (nd[s] == m) ? s : slot;  // lowest slot wins
    int j = slot * 64 + lane;
    float v = m;
    #pragma unroll
    for (int d = 1; d < 64; d <<= 1) {
      float vo = __shfl_xor(v, d);
      int jo = __shfl_xor(j, d);
      bool take = (vo > v) || ((vo == v) && (jo < j));
      v = take ? vo : v;
      j = take ? jo : j;
    }
    int sel = (lane == (j & 63)) ? (j >> 6) : 64;
    #pragma unroll
    for (int s = 0; s < 32; ++s) nd[s] = (s == sel) ? -3.0e38f : nd[s];
    myj = (it == lane) ? j : myj;
  }
  if (lane < 32) outp[lane] = myj;
}

// ---------------- K1: stage-1 top-k (C=3) ----------------
__global__ __launch_bounds__(256) void k_topk1(const float* __restrict__ x, int* __restrict__ idx1) {
  __shared__ float xl[NPTS * 3];   // [n][c]
  __shared__ float sq[NPTS];
  const int t = threadIdx.x;
  const int blk4 = blockIdx.x * 4;
  const int b = blk4 >> 11;
  const float* __restrict__ xb = x + (size_t)b * 3 * NPTS;
  for (int e = t; e < 3 * NPTS; e += 256) {
    int c = e >> 11, n = e & (NPTS - 1);
    xl[n * 3 + c] = xb[e];
  }
  __syncthreads();
  for (int n = t; n < NPTS; n += 256) {
    float a0 = xl[n * 3], a1 = xl[n * 3 + 1], a2 = xl[n * 3 + 2];
    sq[n] = a0 * a0 + a1 * a1 + a2 * a2;
  }
  __syncthreads();
  const int lane = t & 63, w = t >> 6;
  const int row = blk4 + w;
  const int i = row & (NPTS - 1);
  const float xi0 = xl[i * 3], xi1 = xl[i * 3 + 1], xi2 = xl[i * 3 + 2];
  const float si = sq[i];
  float nd[32];
  #pragma unroll
  for (int s = 0; s < 32; ++s) {
    int j = s * 64 + lane;
    float d = xi0 * xl[j * 3] + xi1 * xl[j * 3 + 1] + xi2 * xl[j * 3 + 2];
    nd[s] = (2.0f * d - si) - sq[j];
  }
  extract_top32(nd, lane, idx1 + (size_t)row * KNBR);
}

// ---------------- K2: feat1 moments (6 means + 21 second moments) ----------------
__global__ __launch_bounds__(256) void k_featstats(const float* __restrict__ x,
                                                   const int* __restrict__ idx1,
                                                   float* __restrict__ stat) {
  __shared__ float red[27];
  const int t = threadIdx.x;
  if (t < 27) red[t] = 0.f;
  __syncthreads();
  const int row = blockIdx.x * 256 + t;
  const int b = row >> 11, i = row & (NPTS - 1);
  const float* __restrict__ xb = x + (size_t)b * 3 * NPTS;
  const float xi0 = xb[i], xi1 = xb[NPTS + i], xi2 = xb[2 * NPTS + i];
  float sd0 = 0, sd1 = 0, sd2 = 0, q00 = 0, q01 = 0, q02 = 0, q11 = 0, q12 = 0, q22 = 0;
  for (int k = 0; k < KNBR; ++k) {
    int j = idx1[(size_t)row * KNBR + k];
    float d0 = xb[j] - xi0, d1 = xb[NPTS + j] - xi1, d2 = xb[2 * NPTS + j] - xi2;
    sd0 += d0; sd1 += d1; sd2 += d2;
    q00 += d0 * d0; q01 += d0 * d1; q02 += d0 * d2;
    q11 += d1 * d1; q12 += d1 * d2; q22 += d2 * d2;
  }
  float v[27];
  v[0] = sd0; v[1] = sd1; v[2] = sd2; v[3] = 32.f * xi0; v[4] = 32.f * xi1; v[5] = 32.f * xi2;
  v[6] = q00; v[7] = q01; v[8] = q02; v[9] = sd0 * xi0; v[10] = sd0 * xi1; v[11] = sd0 * xi2;
  v[12] = q11; v[13] = q12; v[14] = sd1 * xi0; v[15] = sd1 * xi1; v[16] = sd1 * xi2;
  v[17] = q22; v[18] = sd2 * xi0; v[19] = sd2 * xi1; v[20] = sd2 * xi2;
  v[21] = 32.f * xi0 * xi0; v[22] = 32.f * xi0 * xi1; v[23] = 32.f * xi0 * xi2;
  v[24] = 32.f * xi1 * xi1; v[25] = 32.f * xi1 * xi2; v[26] = 32.f * xi2 * xi2;
  #pragma unroll
  for (int qq = 0; qq < 27; ++qq) {
    float s = v[qq];
    #pragma unroll
    for (int d = 1; d < 64; d <<= 1) s += __shfl_xor(s, d);
    if ((t & 63) == 0) atomicAdd(&red[qq], s);
  }
  __syncthreads();
  if (t < 27) atomicAdd(&stat[SF0 + t], red[t]);
}

// ---------------- K3: BN1 params from feature moments (linearity of conv) ----------------
__global__ void k_bnprep1(const float* __restrict__ stat, const float* __restrict__ w1,
                          const float* __restrict__ g1, const float* __restrict__ b1,
                          float* __restrict__ sc1, float* __restrict__ sh1) {
  __shared__ float M[36], mu[6];
  const int t = threadIdx.x;
  const float inv = 1.0f / SALL;
  if (t < 6) mu[t] = stat[SF0 + t] * inv;
  if (t < 36) {
    int a = t / 6, bq = t % 6;
    int aa = a < bq ? a : bq, bb = a < bq ? bq : a;
    int pos = aa * 6 - aa * (aa + 1) / 2 + bb;
    M[t] = stat[SF0 + 6 + pos] * inv;
  }
  __syncthreads();
  if (t < 128) {
    const float* w = w1 + t * 6;
    float m = 0.f;
    for (int c = 0; c < 6; ++c) m += w[c] * mu[c];
    float e2 = 0.f;
    for (int a = 0; a < 6; ++a)
      for (int c = 0; c < 6; ++c) e2 += w[a] * w[c] * M[a * 6 + c];
    float var = e2 - m * m;
    float rstd = rsqrtf(var + EPSV);
    float s = g1[t] * rstd;
    sc1[t] = s;
    sh1[t] = b1[t] - m * s;
  }
}

// ---------------- generic BN prep from sums/sumsq ----------------
__global__ void k_bnprep(const float* __restrict__ s, const float* __restrict__ ss,
                         const float* __restrict__ g, const float* __restrict__ bb,
                         float* __restrict__ sc, float* __restrict__ sh, int nch) {
  const int t = threadIdx.x;
  if (t < nch) {
    const float inv = 1.0f / SALL;
    float m = s[t] * inv;
    float var = ss[t] * inv - m * m;
    float rstd = rsqrtf(var + EPSV);
    float scale = g[t] * rstd;
    sc[t] = scale;
    sh[t] = bb[t] - m * scale;
  }
}

// ---------------- K4: fused gather + conv1 + BN1 + lrelu + conv2 (+stats2) (all fp32) ----------------
__global__ __launch_bounds__(256) void k_conv12(
    const float* __restrict__ x, const int* __restrict__ idx1,
    const float* __restrict__ w1, const float* __restrict__ w2,
    const float* __restrict__ sc1g, const float* __restrict__ sh1g,
    float* __restrict__ y2f, float* __restrict__ gS2, float* __restrict__ gSS2) {
  __shared__ float feat[6][64];
  __shared__ __align__(16) float z1l[128][64];
  __shared__ __align__(16) float w2l[64][64];
  __shared__ float s2l[64], ss2l[64];
  const int t = threadIdx.x;
  const int blk = blockIdx.x;  // 8192, 2 rows each
  const int row0 = blk * 2;
  const int b = row0 >> 11;
  const float* __restrict__ xb = x + (size_t)b * 3 * NPTS;
  if (t < 64) { s2l[t] = 0.f; ss2l[t] = 0.f; }
  if (t < 64) {
    int s = t, r = s >> 5, k = s & 31;
    int n = (row0 & (NPTS - 1)) + r;
    int j = idx1[(size_t)(row0 + r) * KNBR + k];
    float c0 = xb[n], c1 = xb[NPTS + n], c2 = xb[2 * NPTS + n];
    feat[0][s] = xb[j] - c0;
    feat[1][s] = xb[NPTS + j] - c1;
    feat[2][s] = xb[2 * NPTS + j] - c2;
    feat[3][s] = c0; feat[4][s] = c1; feat[5][s] = c2;
  }
  __syncthreads();
  {  // z1 = lrelu(BN1(conv1)), fp32
    const int s = t & 63, cb = (t >> 6) * 32;
    float f0 = feat[0][s], f1 = feat[1][s], f2c = feat[2][s];
    float f3 = feat[3][s], f4 = feat[4][s], f5 = feat[5][s];
    for (int ci = 0; ci < 32; ++ci) {
      int c = cb + ci;
      const float* wr = &w1[c * 6];
      float y = wr[0] * f0 + wr[1] * f1 + wr[2] * f2c + wr[3] * f3 + wr[4] * f4 + wr[5] * f5;
      float z = y * sc1g[c] + sh1g[c];
      z1l[c][s] = z > 0.f ? z : SLOPEV * z;
    }
  }
  float acc[4][4] = {};
  const int o0 = (t & 15) * 4, s0 = (t >> 4) * 4;
  const float4* __restrict__ w2v4 = reinterpret_cast<const float4*>(w2);
  for (int h = 0; h < 2; ++h) {  // chunk w2 (c in [64h,64h+64)) to fit LDS
    __syncthreads();
    for (int e = t; e < 1024; e += 256) {
      int o = e >> 4, eq = e & 15;
      float4 v = w2v4[o * 32 + eq + 16 * h];
      int cl = eq * 4;
      w2l[cl][o] = v.x; w2l[cl + 1][o] = v.y; w2l[cl + 2][o] = v.z; w2l[cl + 3][o] = v.w;
    }
    __syncthreads();
    for (int cl = 0; cl < 64; ++cl) {
      int c = 64 * h + cl;
      U4 wv; wv.u = *reinterpret_cast<const uint4*>(&w2l[cl][o0]);
      U4 zv; zv.u = *reinterpret_cast<const uint4*>(&z1l[c][s0]);
      #pragma unroll
      for (int a = 0; a < 4; ++a)
        #pragma unroll
        for (int q = 0; q < 4; ++q) acc[a][q] += wv.f[a] * zv.f[q];
    }
  }
  const size_t sb = (size_t)blk * 64 + s0;
  float sl[4] = {}, ssl[4] = {};
  #pragma unroll
  for (int q = 0; q < 4; ++q) {
    float4 st;
    st.x = acc[0][q]; st.y = acc[1][q]; st.z = acc[2][q]; st.w = acc[3][q];
    *reinterpret_cast<float4*>(&y2f[(sb + q) * 64 + o0]) = st;
    #pragma unroll
    for (int a = 0; a < 4; ++a) { float v = acc[a][q]; sl[a] += v; ssl[a] += v * v; }
  }
  #pragma unroll
  for (int a = 0; a < 4; ++a) {
    sl[a] += __shfl_xor(sl[a], 16); ssl[a] += __shfl_xor(ssl[a], 16);
    sl[a] += __shfl_xor(sl[a], 32); ssl[a] += __shfl_xor(ssl[a], 32);
  }
  if ((t & 63) < 16) {
    #pragma unroll
    for (int a = 0; a < 4; ++a) { atomicAdd(&s2l[o0 + a], sl[a]); atomicAdd(&ss2l[o0 + a], ssl[a]); }
  }
  __syncthreads();
  if (t < 64) atomicAdd(&gS2[t], s2l[t]);
  else if (t < 128) atomicAdd(&gSS2[t - 64], ss2l[t - 64]);
}

// ---------------- K6/K12: BN + lrelu + max over k ----------------
__global__ __launch_bounds__(256) void k_bnmax(
    const void* __restrict__ yv, const int isHalf,
    const float* __restrict__ scg, const float* __restrict__ shg,
    float* __restrict__ out, float* __restrict__ h1t, const int choff) {
  const int t = threadIdx.x, lane = t & 63, w = t >> 6;
  const int row = blockIdx.x * 4 + w;
  const int b = row >> 11, n = row & (NPTS - 1);
  const float sc = scg[lane], sh = shg[lane];
  const size_t base = (size_t)row * 32 * 64 + lane;
  float m = -3.0e38f;
  if (isHalf) {
    const _Float16* p = (const _Float16*)yv;
    for (int k = 0; k < 32; ++k) m = fmaxf(m, lrelu((float)p[base + (size_t)k * 64] * sc + sh));
  } else {
    const float* p = (const float*)yv;
    for (int k = 0; k < 32; ++k) m = fmaxf(m, lrelu(p[base + (size_t)k * 64] * sc + sh));
  }
  out[(size_t)b * 128 * NPTS + (size_t)(choff + lane) * NPTS + n] = m;
  if (h1t) h1t[(size_t)row * 64 + lane] = m;
}

// ---------------- K7a: row norms of h1t ----------------
__global__ __launch_bounds__(256) void k_norms(const float* __restrict__ h1t,
                                               float* __restrict__ nsq) {
  const int t = threadIdx.x;
  const int row = blockIdx.x * 16 + (t >> 4);
  const int l = t & 15;
  float4 v = *reinterpret_cast<const float4*>(h1t + (size_t)row * 64 + l * 4);
  float s = v.x * v.x + v.y * v.y + v.z * v.z + v.w * v.w;
  s += __shfl_xor(s, 1); s += __shfl_xor(s, 2);
  s += __shfl_xor(s, 4); s += __shfl_xor(s, 8);
  if (l == 0) nsq[row] = s;
}

// ---------------- K7b: ND = 2*H*H^T - n_i - n_j (per batch, fp32 tiled GEMM) ----------------
// grid 2048: bt(8) x ti(16) x tj(16), 128x128 tile, K=64 in 2 chunks of 32.
// B panel uses bank-group padding so tx*8 reads are 2-way (free) not 4-way.
#define BCOL(c) ((c) + (((c) >> 5) << 2))
__global__ __launch_bounds__(256) void k_dist(const float* __restrict__ h1t,
                                              const float* __restrict__ nsq,
                                              float* __restrict__ ndb) {
  __shared__ __align__(16) float Al[32][132];
  __shared__ __align__(16) float Bl[32][140];
  const int t = threadIdx.x;
  const int bt = blockIdx.x >> 8, rem = blockIdx.x & 255;
  const int ti = rem >> 4, tj = rem & 15;
  const float* __restrict__ hb = h1t + (size_t)bt * NPTS * 64;
  const int r0 = ti * 128, c0 = tj * 128;
  const int tx = t & 15, ty = t >> 4;
  float acc[8][8] = {};
  for (int kk = 0; kk < 64; kk += 32) {
    __syncthreads();
    for (int e = t; e < 1024; e += 256) {
      int r = e >> 3, c4 = e & 7;
      float4 va = *reinterpret_cast<const float4*>(hb + (size_t)(r0 + r) * 64 + kk + c4 * 4);
      int cb = c4 * 4;
      Al[cb][r] = va.x; Al[cb + 1][r] = va.y; Al[cb + 2][r] = va.z; Al[cb + 3][r] = va.w;
      float4 vb = *reinterpret_cast<const float4*>(hb + (size_t)(c0 + r) * 64 + kk + c4 * 4);
      int rp = BCOL(r);
      Bl[cb][rp] = vb.x; Bl[cb + 1][rp] = vb.y; Bl[cb + 2][rp] = vb.z; Bl[cb + 3][rp] = vb.w;
    }
    __syncthreads();
    #pragma unroll 8
    for (int k = 0; k < 32; ++k) {
      U4 a0; a0.u = *reinterpret_cast<const uint4*>(&Al[k][ty * 8]);
      U4 a1; a1.u = *reinterpret_cast<const uint4*>(&Al[k][ty * 8 + 4]);
      U4 b0; b0.u = *reinterpret_cast<const uint4*>(&Bl[k][BCOL(tx * 8)]);
      U4 b1; b1.u = *reinterpret_cast<const uint4*>(&Bl[k][BCOL(tx * 8) + 4]);
      #pragma unroll
      for (int rr = 0; rr < 4; ++rr) {
        #pragma unroll
        for (int cc = 0; cc < 4; ++cc) {
          acc[rr][cc] += a0.f[rr] * b0.f[cc];
          acc[rr][cc + 4] += a0.f[rr] * b1.f[cc];
          acc[rr + 4][cc] += a1.f[rr] * b0.f[cc];
          acc[rr + 4][cc + 4] += a1.f[rr] * b1.f[cc];
        }
      }
    }
  }
  float nr[8], nc[8];
  const float* __restrict__ nb2 = nsq + (size_t)bt * NPTS;
  #pragma unroll
  for (int i = 0; i < 8; ++i) {
    nr[i] = nb2[r0 + ty * 8 + i];
    nc[i] = nb2[c0 + tx * 8 + i];
  }
  float* __restrict__ op = ndb + ((size_t)bt * NPTS + r0 + ty * 8) * NPTS + c0 + tx * 8;
  #pragma unroll
  for (int rr = 0; rr < 8; ++rr) {
    float4 o0, o1;
    o0.x = 2.f * acc[rr][0] - nr[rr] - nc[0];
    o0.y = 2.f * acc[rr][1] - nr[rr] - nc[1];
    o0.z = 2.f * acc[rr][2] - nr[rr] - nc[2];
    o0.w = 2.f * acc[rr][3] - nr[rr] - nc[3];
    o1.x = 2.f * acc[rr][4] - nr[rr] - nc[4];
    o1.y = 2.f * acc[rr][5] - nr[rr] - nc[5];
    o1.z = 2.f * acc[rr][6] - nr[rr] - nc[6];
    o1.w = 2.f * acc[rr][7] - nr[rr] - nc[7];
    *reinterpret_cast<float4*>(op + (size_t)rr * NPTS) = o0;
    *reinterpret_cast<float4*>(op + (size_t)rr * NPTS + 4) = o1;
  }
}

// ---------------- K7c: streaming top-32 selection from ND ----------------
__global__ __launch_bounds__(512) void k_sel(const float* __restrict__ ndb,
                                             int* __restrict__ idx2) {
  const int t = threadIdx.x, lane = t & 63, w = t >> 6;
  const int row = blockIdx.x * 8 + w;
  const float* __restrict__ nr = ndb + (size_t)row * NPTS;
  float nd[32];
  #pragma unroll
  for (int s = 0; s < 32; ++s) nd[s] = nr[s * 64 + lane];
  extract_top32(nd, lane, idx2 + (size_t)row * KNBR);
}

// ---------------- K8a: conv3 stats pass (fp16 LDS + v_dot2) ----------------
__global__ __launch_bounds__(256) void k_conv3(
    const float* __restrict__ h1t, const int* __restrict__ idx2,
    const float* __restrict__ w3, float* __restrict__ gS3, float* __restrict__ gSS3) {
  __shared__ __align__(16) f16x2 f2p[64][68];
  __shared__ __align__(16) f16x2 w3p[32][132];
  __shared__ float ctr[2][64];
  __shared__ float s3l[128], ss3l[128];
  const int t = threadIdx.x;
  const int blk = blockIdx.x;  // 8192, 2 rows each
  const int row0 = blk * 2;
  const int b = row0 >> 11;
  const float* __restrict__ hb = h1t + (size_t)b * NPTS * 64;
  if (t < 128) { s3l[t] = 0.f; ss3l[t] = 0.f; }
  if (t < 128) {
    int r = t >> 6, c = t & 63;
    ctr[r][c] = hb[(size_t)((row0 & (NPTS - 1)) + r) * 64 + c];
  }
  __syncthreads();
  {  // gather feat2 = [nbr-ctr ; ctr] into fp16 pairs
    int s = t >> 2, cq = t & 3;
    int r = s >> 5, k = s & 31;
    int j = idx2[(size_t)(row0 + r) * KNBR + k];
    const float* __restrict__ nv = hb + (size_t)j * 64 + cq * 16;
    #pragma unroll
    for (int cc = 0; cc < 16; cc += 2) {
      int c = cq * 16 + cc;
      f2p[c >> 1][s] = pack2(nv[cc] - ctr[r][c], nv[cc + 1] - ctr[r][c + 1]);
      f2p[32 + (c >> 1)][s] = pack2(ctr[r][c], ctr[r][c + 1]);
    }
  }
  float acc[4][8] = {};
  const int o0 = (t & 31) * 4, s0 = (t >> 5) * 8;
  const float4* __restrict__ w3v = reinterpret_cast<const float4*>(w3);
  for (int h = 0; h < 2; ++h) {
    __syncthreads();
    for (int e = t; e < 2048; e += 256) {
      int o = e >> 4, eq = e & 15;
      float4 v = w3v[o * 32 + eq + 16 * h];
      int cpl = eq * 2;
      w3p[cpl][o] = pack2(v.x, v.y);
      w3p[cpl + 1][o] = pack2(v.z, v.w);
    }
    __syncthreads();
    for (int cpl = 0; cpl < 32; ++cpl) {
      int cp = 32 * h + cpl;
      U4 wv; wv.u = *reinterpret_cast<const uint4*>(&w3p[cpl][o0]);
      U4 za; za.u = *reinterpret_cast<const uint4*>(&f2p[cp][s0]);
      U4 zb; zb.u = *reinterpret_cast<const uint4*>(&f2p[cp][s0 + 4]);
      #pragma unroll
      for (int a = 0; a < 4; ++a) {
        #pragma unroll
        for (int q = 0; q < 4; ++q) {
          acc[a][q] = fdot2f(wv.h[a], za.h[q], acc[a][q]);
          acc[a][q + 4] = fdot2f(wv.h[a], zb.h[q], acc[a][q + 4]);
        }
      }
    }
  }
  float sl[4] = {}, ssl[4] = {};
  #pragma unroll
  for (int a = 0; a < 4; ++a)
    #pragma unroll
    for (int q = 0; q < 8; ++q) { float v = acc[a][q]; sl[a] += v; ssl[a] += v * v; }
  #pragma unroll
  for (int a = 0; a < 4; ++a) { sl[a] += __shfl_xor(sl[a], 32); ssl[a] += __shfl_xor(ssl[a], 32); }
  if ((t & 63) < 32) {
    #pragma unroll
    for (int a = 0; a < 4; ++a) { atomicAdd(&s3l[o0 + a], sl[a]); atomicAdd(&ss3l[o0 + a], ssl[a]); }
  }
  __syncthreads();
  if (t < 128) atomicAdd(&gS3[t], s3l[t]);
  else atomicAdd(&gSS3[t - 128], ss3l[t - 128]);
}

// ---------------- K8b: recompute conv3 -> BN3+lrelu -> conv4 (+stats4, store y4 fp16) ----------------
__global__ __launch_bounds__(256) void k_conv4(
    const float* __restrict__ h1t, const int* __restrict__ idx2,
    const float* __restrict__ w3, const float* __restrict__ w4,
    const float* __restrict__ sc3g, const float* __restrict__ sh3g,
    _Float16* __restrict__ y4h, float* __restrict__ gS4, float* __restrict__ gSS4) {
  __shared__ __align__(16) f16x2 f2p[64][68];   // feat2, reused as z3 pairs
  __shared__ __align__(16) f16x2 w3p[32][132];
  __shared__ __align__(16) f16x2 w4p[64][68];
  __shared__ float ctr[2][64];
  __shared__ float s4l[64], ss4l[64];
  const int t = threadIdx.x;
  const int blk = blockIdx.x;  // 8192
  const int row0 = blk * 2;
  const int b = row0 >> 11;
  const float* __restrict__ hb = h1t + (size_t)b * NPTS * 64;
  if (t < 64) { s4l[t] = 0.f; ss4l[t] = 0.f; }
  if (t < 128) {
    int r = t >> 6, c = t & 63;
    ctr[r][c] = hb[(size_t)((row0 & (NPTS - 1)) + r) * 64 + c];
  }
  {
    const float4* __restrict__ w4v = reinterpret_cast<const float4*>(w4);
    for (int e = t; e < 2048; e += 256) {
      int o = e >> 5, eq = e & 31;
      float4 v = w4v[o * 32 + eq];
      w4p[eq * 2][o] = pack2(v.x, v.y);
      w4p[eq * 2 + 1][o] = pack2(v.z, v.w);
    }
  }
  __syncthreads();
  {
    int s = t >> 2, cq = t & 3;
    int r = s >> 5, k = s & 31;
    int j = idx2[(size_t)(row0 + r) * KNBR + k];
    const float* __restrict__ nv = hb + (size_t)j * 64 + cq * 16;
    #pragma unroll
    for (int cc = 0; cc < 16; cc += 2) {
      int c = cq * 16 + cc;
      f2p[c >> 1][s] = pack2(nv[cc] - ctr[r][c], nv[cc + 1] - ctr[r][c + 1]);
      f2p[32 + (c >> 1)][s] = pack2(ctr[r][c], ctr[r][c + 1]);
    }
  }
  float acc[4][8] = {};
  const int o0 = (t & 31) * 4, s0 = (t >> 5) * 8;
  const float4* __restrict__ w3v = reinterpret_cast<const float4*>(w3);
  for (int h = 0; h < 2; ++h) {
    __syncthreads();
    for (int e = t; e < 2048; e += 256) {
      int o = e >> 4, eq = e & 15;
      float4 v = w3v[o * 32 + eq + 16 * h];
      int cpl = eq * 2;
      w3p[cpl][o] = pack2(v.x, v.y);
      w3p[cpl + 1][o] = pack2(v.z, v.w);
    }
    __syncthreads();
    for (int cpl = 0; cpl < 32; ++cpl) {
      int cp = 32 * h + cpl;
      U4 wv; wv.u = *reinterpret_cast<const uint4*>(&w3p[cpl][o0]);
      U4 za; za.u = *reinterpret_cast<const uint4*>(&f2p[cp][s0]);
      U4 zb; zb.u = *reinterpret_cast<const uint4*>(&f2p[cp][s0 + 4]);
      #pragma unroll
      for (int a = 0; a < 4; ++a) {
        #pragma unroll
        for (int q = 0; q < 4; ++q) {
          acc[a][q] = fdot2f(wv.h[a], za.h[q], acc[a][q]);
          acc[a][q + 4] = fdot2f(wv.h[a], zb.h[q], acc[a][q + 4]);
        }
      }
    }
  }
  float zsc[4], zsh[4];
  #pragma unroll
  for (int a = 0; a < 4; ++a) { zsc[a] = sc3g[o0 + a]; zsh[a] = sh3g[o0 + a]; }
  __syncthreads();  // all f2p reads done, safe to overwrite with z3
  {
    int cpz = o0 >> 1;
    #pragma unroll
    for (int q = 0; q < 8; ++q) {
      float z0 = lrelu(acc[0][q] * zsc[0] + zsh[0]);
      float z1 = lrelu(acc[1][q] * zsc[1] + zsh[1]);
      float z2 = lrelu(acc[2][q] * zsc[2] + zsh[2]);
      float z3 = lrelu(acc[3][q] * zsc[3] + zsh[3]);
      f2p[cpz][s0 + q] = pack2(z0, z1);
      f2p[cpz + 1][s0 + q] = pack2(z2, z3);
    }
  }
  __syncthreads();
  float a4[4][4] = {};
  const int p0 = (t & 15) * 4, u0 = (t >> 4) * 4;
  for (int cp = 0; cp < 64; ++cp) {
    U4 wv; wv.u = *reinterpret_cast<const uint4*>(&w4p[cp][p0]);
    U4 zv; zv.u = *reinterpret_cast<const uint4*>(&f2p[cp][u0]);
    #pragma unroll
    for (int a = 0; a < 4; ++a)
      #pragma unroll
      for (int q = 0; q < 4; ++q) a4[a][q] = fdot2f(wv.h[a], zv.h[q], a4[a][q]);
  }
  const size_t sb = (size_t)blk * 64 + u0;
  float sl[4] = {}, ssl[4] = {};
  #pragma unroll
  for (int q = 0; q < 4; ++q) {
    #pragma unroll
    for (int a = 0; a < 4; ++a) { float v = a4[a][q]; sl[a] += v; ssl[a] += v * v; }
    U2f pk;
    pk.h[0] = pack2(a4[0][q], a4[1][q]);
    pk.h[1] = pack2(a4[2][q], a4[3][q]);
    *reinterpret_cast<uint2*>(&y4h[(sb + q) * 64 + p0]) = pk.u;
  }
  #pragma unroll
  for (int a = 0; a < 4; ++a) {
    sl[a] += __shfl_xor(sl[a], 16); ssl[a] += __shfl_xor(ssl[a], 16);
    sl[a] += __shfl_xor(sl[a], 32); ssl[a] += __shfl_xor(ssl[a], 32);
  }
  if ((t & 63) < 16) {
    #pragma unroll
    for (int a = 0; a < 4; ++a) { atomicAdd(&s4l[p0 + a], sl[a]); atomicAdd(&ss4l[p0 + a], ssl[a]); }
  }
  __syncthreads();
  if (t < 64) atomicAdd(&gS4[t], s4l[t]);
  else if (t < 128) atomicAdd(&gSS4[t - 64], ss4l[t - 64]);
}

// ---------------- host launcher ----------------
extern "C" void kernel_launch(void* const* d_in, const int* in_sizes, int n_in,
                              void* d_out, int out_size, void* d_ws, size_t ws_size,
                              hipStream_t stream) {
  const float* x = (const float*)d_in[0];
  const float* w1 = (const float*)d_in[1];
  const float* g1 = (const float*)d_in[2];
  const float* b1 = (const float*)d_in[3];
  const float* w2 = (const float*)d_in[4];
  const float* g2 = (const float*)d_in[5];
  const float* b2 = (const float*)d_in[6];
  const float* w3 = (const float*)d_in[7];
  const float* g3 = (const float*)d_in[8];
  const float* b3 = (const float*)d_in[9];
  const float* w4 = (const float*)d_in[10];
  const float* g4 = (const float*)d_in[11];
  const float* b4 = (const float*)d_in[12];
  float* out = (float*)d_out;
  char* ws = (char*)d_ws;
  int* idx1 = (int*)(ws + OFF_IDX1);
  int* idx2 = (int*)(ws + OFF_IDX2);
  float* h1t = (float*)(ws + OFF_H1T);
  float* stat = (float*)(ws + OFF_STAT);
  float* nsq = (float*)(ws + OFF_NSQ);
  float* y2f = (float*)(ws + OFF_BIG);          // fp32 [S][64] = 128 MiB
  float* ndb = (float*)(ws + OFF_BIG);          // fp32 [16384][2048] = 128 MiB (after y2 dead)
  _Float16* y4h = (_Float16*)(ws + OFF_BIG);    // fp16 [S][64], reuses region after ndb dead

  hipMemsetAsync(stat, 0, 8192, stream);
  hipLaunchKernelGGL(k_topk1, dim3(4096), dim3(256), 0, stream, x, idx1);
  hipLaunchKernelGGL(k_featstats, dim3(64), dim3(256), 0, stream, x, idx1, stat);
  hipLaunchKernelGGL(k_bnprep1, dim3(1), dim3(128), 0, stream, stat, w1, g1, b1, stat + SC1, stat + SH1);
  hipLaunchKernelGGL(k_conv12, dim3(8192), dim3(256), 0, stream, x, idx1, w1, w2,
                     stat + SC1, stat + SH1, y2f, stat + S2o, stat + SS2o);
  hipLaunchKernelGGL(k_bnprep, dim3(1), dim3(128), 0, stream, stat + S2o, stat + SS2o, g2, b2,
                     stat + SC2, stat + SH2, 64);
  hipLaunchKernelGGL(k_bnmax, dim3(4096), dim3(256), 0, stream, (const void*)y2f, 0,
                     stat + SC2, stat + SH2, out, h1t, 0);
  hipLaunchKernelGGL(k_norms, dim3(1024), dim3(256), 0, stream, h1t, nsq);
  hipLaunchKernelGGL(k_dist, dim3(2048), dim3(256), 0, stream, h1t, nsq, ndb);
  hipLaunchKernelGGL(k_sel, dim3(2048), dim3(512), 0, stream, ndb, idx2);
  hipLaunchKernelGGL(k_conv3, dim3(8192), dim3(256), 0, stream, h1t, idx2, w3, stat + S3o, stat + SS3o);
  hipLaunchKernelGGL(k_bnprep, dim3(1), dim3(128), 0, stream, stat + S3o, stat + SS3o, g3, b3,
                     stat + SC3, stat + SH3, 128);
  hipLaunchKernelGGL(k_conv4, dim3(8192), dim3(256), 0, stream, h1t, idx2, w3, w4,
                     stat + SC3, stat + SH3, y4h, stat + S4o, stat + SS4o);
  hipLaunchKernelGGL(k_bnprep, dim3(1), dim3(128), 0, stream, stat + S4o, stat + SS4o, g4, b4,
                     stat + SC4, stat + SH4, 64);
  hipLaunchKernelGGL(k_bnmax, dim3(4096), dim3(256), 0, stream, (const void*)y4h, 1,
                     stat + SC4, stat + SH4, out, (float*)nullptr, 64);
  (void)in_sizes; (void)n_in; (void)out_size; (void)ws_size;
}

// Round 4
// 1049.917 us; speedup vs baseline: 7.5788x; 1.2247x over previous
//
#include <hip/hip_runtime.h>

#define DI __device__ __forceinline__

typedef _Float16 f16x2 __attribute__((ext_vector_type(2)));
typedef _Float16 f16x8 __attribute__((ext_vector_type(8)));
typedef float f32x4 __attribute__((ext_vector_type(4)));

#define NPTS 2048
#define KNBR 32
#define SALL 524288.0f
#define EPSV 1e-5f
#define SLOPEV 0.2f

// ---------------- workspace layout (bytes), total 144 MiB ----------------
#define OFF_IDX1 0u
#define OFF_IDX2 (2u*1024u*1024u)
#define OFF_H1T  (4u*1024u*1024u)
#define OFF_STAT (8u*1024u*1024u)
#define OFF_NSQ  (9u*1024u*1024u)
#define OFF_BIG  (16u*1024u*1024u)
// BIG region (128 MiB) time-multiplexed:
//   phase A: h1max @ BIG, h1min @ BIG+4MiB   (conv12 -> finbn2)
//   phase B: ndb   @ BIG (128 MiB)           (dist -> sel)
//   phase C: h2max @ BIG, h2min @ BIG+4MiB   (conv4 -> finbn4)
// stat float offsets
#define SF0 0
#define SC1 32
#define SH1 160
#define S2o 288
#define SS2o 352
#define SC2 416
#define SH2 480
#define S3o 544
#define SS3o 672
#define SC3 800
#define SH3 928
#define S4o 1056
#define SS4o 1120
#define SC4 1184
#define SH4 1248

union U4 { uint4 u; float f[4]; };
union UH8 { uint4 u; f16x8 h; };

DI float lrelu(float z) { return z > 0.f ? z : SLOPEV * z; }

// Exact top-32 of 2048 values held as nd[s] per lane (value j = s*64+lane).
DI void extract_top32(float (&nd)[32], int lane, int* __restrict__ outp) {
  int myj = 0;
  #pragma nounroll
  for (int it = 0; it < 32; ++it) {
    float tm[16];
    #pragma unroll
    for (int s = 0; s < 16; ++s) tm[s] = fmaxf(nd[s], nd[s + 16]);
    #pragma unroll
    for (int s = 0; s < 8; ++s) tm[s] = fmaxf(tm[s], tm[s + 8]);
    #pragma unroll
    for (int s = 0; s < 4; ++s) tm[s] = fmaxf(tm[s], tm[s + 4]);
    float m = fmaxf(fmaxf(tm[0], tm[2]), fmaxf(tm[1], tm[3]));
    int slot = 0;
    #pragma unroll
    for (int s = 31; s >= 0; --s) slot = (nd[s] == m) ? s : slot;  // lowest slot wins
    int j = slot * 64 + lane;
    float v = m;
    #pragma unroll
    for (int d = 1; d < 64; d <<= 1) {
      float vo = __shfl_xor(v, d);
      int jo = __shfl_xor(j, d);
      bool take = (vo > v) || ((vo == v) && (jo < j));
      v = take ? vo : v;
      j = take ? jo : j;
    }
    int sel = (lane == (j & 63)) ? (j >> 6) : 64;
    #pragma unroll
    for (int s = 0; s < 32; ++s) nd[s] = (s == sel) ? -3.0e38f : nd[s];
    myj = (it == lane) ? j : myj;
  }
  if (lane < 32) outp[lane] = myj;
}

// ---------------- K1: stage-1 top-k (C=3) ----------------
__global__ __launch_bounds__(256) void k_topk1(const float* __restrict__ x, int* __restrict__ idx1) {
  __shared__ float xl[NPTS * 3];
  __shared__ float sq[NPTS];
  const int t = threadIdx.x;
  const int blk4 = blockIdx.x * 4;
  const int b = blk4 >> 11;
  const float* __restrict__ xb = x + (size_t)b * 3 * NPTS;
  for (int e = t; e < 3 * NPTS; e += 256) {
    int c = e >> 11, n = e & (NPTS - 1);
    xl[n * 3 + c] = xb[e];
  }
  __syncthreads();
  for (int n = t; n < NPTS; n += 256) {
    float a0 = xl[n * 3], a1 = xl[n * 3 + 1], a2 = xl[n * 3 + 2];
    sq[n] = a0 * a0 + a1 * a1 + a2 * a2;
  }
  __syncthreads();
  const int lane = t & 63, w = t >> 6;
  const int row = blk4 + w;
  const int i = row & (NPTS - 1);
  const float xi0 = xl[i * 3], xi1 = xl[i * 3 + 1], xi2 = xl[i * 3 + 2];
  const float si = sq[i];
  float nd[32];
  #pragma unroll
  for (int s = 0; s < 32; ++s) {
    int j = s * 64 + lane;
    float d = xi0 * xl[j * 3] + xi1 * xl[j * 3 + 1] + xi2 * xl[j * 3 + 2];
    nd[s] = (2.0f * d - si) - sq[j];
  }
  extract_top32(nd, lane, idx1 + (size_t)row * KNBR);
}

// ---------------- K2: feat1 moments ----------------
__global__ __launch_bounds__(256) void k_featstats(const float* __restrict__ x,
                                                   const int* __restrict__ idx1,
                                                   float* __restrict__ stat) {
  __shared__ float red[27];
  const int t = threadIdx.x;
  if (t < 27) red[t] = 0.f;
  __syncthreads();
  const int row = blockIdx.x * 256 + t;
  const int b = row >> 11, i = row & (NPTS - 1);
  const float* __restrict__ xb = x + (size_t)b * 3 * NPTS;
  const float xi0 = xb[i], xi1 = xb[NPTS + i], xi2 = xb[2 * NPTS + i];
  float sd0 = 0, sd1 = 0, sd2 = 0, q00 = 0, q01 = 0, q02 = 0, q11 = 0, q12 = 0, q22 = 0;
  for (int k = 0; k < KNBR; ++k) {
    int j = idx1[(size_t)row * KNBR + k];
    float d0 = xb[j] - xi0, d1 = xb[NPTS + j] - xi1, d2 = xb[2 * NPTS + j] - xi2;
    sd0 += d0; sd1 += d1; sd2 += d2;
    q00 += d0 * d0; q01 += d0 * d1; q02 += d0 * d2;
    q11 += d1 * d1; q12 += d1 * d2; q22 += d2 * d2;
  }
  float v[27];
  v[0] = sd0; v[1] = sd1; v[2] = sd2; v[3] = 32.f * xi0; v[4] = 32.f * xi1; v[5] = 32.f * xi2;
  v[6] = q00; v[7] = q01; v[8] = q02; v[9] = sd0 * xi0; v[10] = sd0 * xi1; v[11] = sd0 * xi2;
  v[12] = q11; v[13] = q12; v[14] = sd1 * xi0; v[15] = sd1 * xi1; v[16] = sd1 * xi2;
  v[17] = q22; v[18] = sd2 * xi0; v[19] = sd2 * xi1; v[20] = sd2 * xi2;
  v[21] = 32.f * xi0 * xi0; v[22] = 32.f * xi0 * xi1; v[23] = 32.f * xi0 * xi2;
  v[24] = 32.f * xi1 * xi1; v[25] = 32.f * xi1 * xi2; v[26] = 32.f * xi2 * xi2;
  #pragma unroll
  for (int qq = 0; qq < 27; ++qq) {
    float s = v[qq];
    #pragma unroll
    for (int d = 1; d < 64; d <<= 1) s += __shfl_xor(s, d);
    if ((t & 63) == 0) atomicAdd(&red[qq], s);
  }
  __syncthreads();
  if (t < 27) atomicAdd(&stat[SF0 + t], red[t]);
}

// ---------------- K3: BN1 params from feature moments ----------------
__global__ void k_bnprep1(const float* __restrict__ stat, const float* __restrict__ w1,
                          const float* __restrict__ g1, const float* __restrict__ b1,
                          float* __restrict__ sc1, float* __restrict__ sh1) {
  __shared__ float M[36], mu[6];
  const int t = threadIdx.x;
  const float inv = 1.0f / SALL;
  if (t < 6) mu[t] = stat[SF0 + t] * inv;
  if (t < 36) {
    int a = t / 6, bq = t % 6;
    int aa = a < bq ? a : bq, bb = a < bq ? bq : a;
    int pos = aa * 6 - aa * (aa + 1) / 2 + bb;
    M[t] = stat[SF0 + 6 + pos] * inv;
  }
  __syncthreads();
  if (t < 128) {
    const float* w = w1 + t * 6;
    float m = 0.f;
    for (int c = 0; c < 6; ++c) m += w[c] * mu[c];
    float e2 = 0.f;
    for (int a = 0; a < 6; ++a)
      for (int c = 0; c < 6; ++c) e2 += w[a] * w[c] * M[a * 6 + c];
    float var = e2 - m * m;
    float rstd = rsqrtf(var + EPSV);
    float s = g1[t] * rstd;
    sc1[t] = s;
    sh1[t] = b1[t] - m * s;
  }
}

// ---------------- generic BN prep ----------------
__global__ void k_bnprep(const float* __restrict__ s, const float* __restrict__ ss,
                         const float* __restrict__ g, const float* __restrict__ bb,
                         float* __restrict__ sc, float* __restrict__ sh, int nch) {
  const int t = threadIdx.x;
  if (t < nch) {
    const float inv = 1.0f / SALL;
    float m = s[t] * inv;
    float var = ss[t] * inv - m * m;
    float rstd = rsqrtf(var + EPSV);
    float scale = g[t] * rstd;
    sc[t] = scale;
    sh[t] = bb[t] - m * scale;
  }
}

// ---------------- K4: gather + conv1 + BN1 + lrelu + conv2 + stats2 + k-max/min ----------------
__global__ __launch_bounds__(256) void k_conv12(
    const float* __restrict__ x, const int* __restrict__ idx1,
    const float* __restrict__ w1, const float* __restrict__ w2,
    const float* __restrict__ sc1g, const float* __restrict__ sh1g,
    float* __restrict__ h1max, float* __restrict__ h1min,
    float* __restrict__ gS2, float* __restrict__ gSS2) {
  __shared__ float feat[6][64];
  __shared__ __align__(16) float z1l[128][64];
  __shared__ __align__(16) float w2l[64][64];
  __shared__ float redmx[16][64], redmn[16][64];
  __shared__ float s2l[64], ss2l[64];
  const int t = threadIdx.x;
  const int blk = blockIdx.x;  // 8192, 2 rows each
  const int row0 = blk * 2;
  const int b = row0 >> 11;
  const float* __restrict__ xb = x + (size_t)b * 3 * NPTS;
  if (t < 64) { s2l[t] = 0.f; ss2l[t] = 0.f; }
  if (t < 64) {
    int s = t, r = s >> 5, k = s & 31;
    int n = (row0 & (NPTS - 1)) + r;
    int j = idx1[(size_t)(row0 + r) * KNBR + k];
    float c0 = xb[n], c1 = xb[NPTS + n], c2 = xb[2 * NPTS + n];
    feat[0][s] = xb[j] - c0;
    feat[1][s] = xb[NPTS + j] - c1;
    feat[2][s] = xb[2 * NPTS + j] - c2;
    feat[3][s] = c0; feat[4][s] = c1; feat[5][s] = c2;
  }
  __syncthreads();
  {  // z1 = lrelu(BN1(conv1)), fp32
    const int s = t & 63, cb = (t >> 6) * 32;
    float f0 = feat[0][s], f1 = feat[1][s], f2c = feat[2][s];
    float f3 = feat[3][s], f4 = feat[4][s], f5 = feat[5][s];
    for (int ci = 0; ci < 32; ++ci) {
      int c = cb + ci;
      const float* wr = &w1[c * 6];
      float y = wr[0] * f0 + wr[1] * f1 + wr[2] * f2c + wr[3] * f3 + wr[4] * f4 + wr[5] * f5;
      float z = y * sc1g[c] + sh1g[c];
      z1l[c][s] = z > 0.f ? z : SLOPEV * z;
    }
  }
  float acc[4][4] = {};
  const int o0 = (t & 15) * 4, s0 = (t >> 4) * 4;
  const float4* __restrict__ w2v4 = reinterpret_cast<const float4*>(w2);
  for (int h = 0; h < 2; ++h) {
    __syncthreads();
    for (int e = t; e < 1024; e += 256) {
      int o = e >> 4, eq = e & 15;
      float4 v = w2v4[o * 32 + eq + 16 * h];
      int cl = eq * 4;
      w2l[cl][o] = v.x; w2l[cl + 1][o] = v.y; w2l[cl + 2][o] = v.z; w2l[cl + 3][o] = v.w;
    }
    __syncthreads();
    for (int cl = 0; cl < 64; ++cl) {
      int c = 64 * h + cl;
      U4 wv; wv.u = *reinterpret_cast<const uint4*>(&w2l[cl][o0]);
      U4 zv; zv.u = *reinterpret_cast<const uint4*>(&z1l[c][s0]);
      #pragma unroll
      for (int a = 0; a < 4; ++a)
        #pragma unroll
        for (int q = 0; q < 4; ++q) acc[a][q] += wv.f[a] * zv.f[q];
    }
  }
  // per-thread: stats + max/min over its 4 samples (all within one row r = s0>>5)
  float sl[4] = {}, ssl[4] = {};
  #pragma unroll
  for (int a = 0; a < 4; ++a) {
    float mx = -3.0e38f, mn = 3.0e38f;
    #pragma unroll
    for (int q = 0; q < 4; ++q) {
      float v = acc[a][q];
      sl[a] += v; ssl[a] += v * v;
      mx = fmaxf(mx, v); mn = fminf(mn, v);
    }
    redmx[t >> 4][o0 + a] = mx;
    redmn[t >> 4][o0 + a] = mn;
  }
  #pragma unroll
  for (int a = 0; a < 4; ++a) {
    sl[a] += __shfl_xor(sl[a], 16); ssl[a] += __shfl_xor(ssl[a], 16);
    sl[a] += __shfl_xor(sl[a], 32); ssl[a] += __shfl_xor(ssl[a], 32);
  }
  if ((t & 63) < 16) {
    #pragma unroll
    for (int a = 0; a < 4; ++a) { atomicAdd(&s2l[o0 + a], sl[a]); atomicAdd(&ss2l[o0 + a], ssl[a]); }
  }
  __syncthreads();
  if (t < 64) atomicAdd(&gS2[t], s2l[t]);
  else if (t < 128) atomicAdd(&gSS2[t - 64], ss2l[t - 64]);
  if (t < 128) {
    int r = t >> 6, c = t & 63;
    float m = -3.0e38f;
    #pragma unroll
    for (int g = 0; g < 8; ++g) m = fmaxf(m, redmx[8 * r + g][c]);
    h1max[(size_t)(row0 + r) * 64 + c] = m;
  } else {
    int r = (t - 128) >> 6, c = t & 63;
    float m = 3.0e38f;
    #pragma unroll
    for (int g = 0; g < 8; ++g) m = fminf(m, redmn[8 * r + g][c]);
    h1min[(size_t)(row0 + r) * 64 + c] = m;
  }
}

// ---------------- K5: BN + lrelu epilogue from (max,min); writes out (+h1t,+nsq) ----------------
__global__ __launch_bounds__(256) void k_finbn(
    const float* __restrict__ hmax, const float* __restrict__ hmin,
    const float* __restrict__ scg, const float* __restrict__ shg,
    float* __restrict__ out, const int choff,
    float* __restrict__ h1t, float* __restrict__ nsq) {
  __shared__ float ht[128][65];
  const int t = threadIdx.x;
  const int blk = blockIdx.x;          // 128 blocks x 128 rows
  const int row0 = blk * 128;
  const int b = row0 >> 11, n0 = row0 & (NPTS - 1);
  const int c = t & 63;
  const float sc = scg[c], sh = shg[c];
  const int rbase = t >> 6;
  for (int it = 0; it < 32; ++it) {
    int rl = it * 4 + rbase;
    size_t gi = (size_t)(row0 + rl) * 64 + c;
    float y = sc > 0.f ? hmax[gi] : hmin[gi];
    float h = lrelu(sc * y + sh);
    if (h1t) h1t[gi] = h;
    ht[rl][c] = h;
  }
  __syncthreads();
  if (nsq && t < 128) {
    float s = 0.f;
    #pragma unroll
    for (int c2 = 0; c2 < 64; ++c2) { float v = ht[t][c2]; s += v * v; }
    nsq[row0 + t] = s;
  }
  const int co = t >> 2, i0 = (t & 3) * 32;
  float* __restrict__ op = out + ((size_t)b * 128 + choff + co) * NPTS + n0 + i0;
  for (int i = 0; i < 32; i += 4) {
    float4 v;
    v.x = ht[i0 + i][co]; v.y = ht[i0 + i + 1][co];
    v.z = ht[i0 + i + 2][co]; v.w = ht[i0 + i + 3][co];
    *reinterpret_cast<float4*>(op + i) = v;
  }
}

// ---------------- K7b: ND = 2*H*H^T - n_i - n_j ----------------
#define BCOL(c) ((c) + (((c) >> 5) << 2))
__global__ __launch_bounds__(256) void k_dist(const float* __restrict__ h1t,
                                              const float* __restrict__ nsq,
                                              float* __restrict__ ndb) {
  __shared__ __align__(16) float Al[32][132];
  __shared__ __align__(16) float Bl[32][140];
  const int t = threadIdx.x;
  const int bt = blockIdx.x >> 8, rem = blockIdx.x & 255;
  const int ti = rem >> 4, tj = rem & 15;
  const float* __restrict__ hb = h1t + (size_t)bt * NPTS * 64;
  const int r0 = ti * 128, c0 = tj * 128;
  const int tx = t & 15, ty = t >> 4;
  float acc[8][8] = {};
  for (int kk = 0; kk < 64; kk += 32) {
    __syncthreads();
    for (int e = t; e < 1024; e += 256) {
      int r = e >> 3, c4 = e & 7;
      float4 va = *reinterpret_cast<const float4*>(hb + (size_t)(r0 + r) * 64 + kk + c4 * 4);
      int cb = c4 * 4;
      Al[cb][r] = va.x; Al[cb + 1][r] = va.y; Al[cb + 2][r] = va.z; Al[cb + 3][r] = va.w;
      float4 vb = *reinterpret_cast<const float4*>(hb + (size_t)(c0 + r) * 64 + kk + c4 * 4);
      int rp = BCOL(r);
      Bl[cb][rp] = vb.x; Bl[cb + 1][rp] = vb.y; Bl[cb + 2][rp] = vb.z; Bl[cb + 3][rp] = vb.w;
    }
    __syncthreads();
    #pragma unroll 8
    for (int k = 0; k < 32; ++k) {
      U4 a0; a0.u = *reinterpret_cast<const uint4*>(&Al[k][ty * 8]);
      U4 a1; a1.u = *reinterpret_cast<const uint4*>(&Al[k][ty * 8 + 4]);
      U4 b0; b0.u = *reinterpret_cast<const uint4*>(&Bl[k][BCOL(tx * 8)]);
      U4 b1; b1.u = *reinterpret_cast<const uint4*>(&Bl[k][BCOL(tx * 8) + 4]);
      #pragma unroll
      for (int rr = 0; rr < 4; ++rr) {
        #pragma unroll
        for (int cc = 0; cc < 4; ++cc) {
          acc[rr][cc] += a0.f[rr] * b0.f[cc];
          acc[rr][cc + 4] += a0.f[rr] * b1.f[cc];
          acc[rr + 4][cc] += a1.f[rr] * b0.f[cc];
          acc[rr + 4][cc + 4] += a1.f[rr] * b1.f[cc];
        }
      }
    }
  }
  float nr[8], nc[8];
  const float* __restrict__ nb2 = nsq + (size_t)bt * NPTS;
  #pragma unroll
  for (int i = 0; i < 8; ++i) {
    nr[i] = nb2[r0 + ty * 8 + i];
    nc[i] = nb2[c0 + tx * 8 + i];
  }
  float* __restrict__ op = ndb + ((size_t)bt * NPTS + r0 + ty * 8) * NPTS + c0 + tx * 8;
  #pragma unroll
  for (int rr = 0; rr < 8; ++rr) {
    float4 o0, o1;
    o0.x = 2.f * acc[rr][0] - nr[rr] - nc[0];
    o0.y = 2.f * acc[rr][1] - nr[rr] - nc[1];
    o0.z = 2.f * acc[rr][2] - nr[rr] - nc[2];
    o0.w = 2.f * acc[rr][3] - nr[rr] - nc[3];
    o1.x = 2.f * acc[rr][4] - nr[rr] - nc[4];
    o1.y = 2.f * acc[rr][5] - nr[rr] - nc[5];
    o1.z = 2.f * acc[rr][6] - nr[rr] - nc[6];
    o1.w = 2.f * acc[rr][7] - nr[rr] - nc[7];
    *reinterpret_cast<float4*>(op + (size_t)rr * NPTS) = o0;
    *reinterpret_cast<float4*>(op + (size_t)rr * NPTS + 4) = o1;
  }
}

// ---------------- K7c: streaming top-32 selection ----------------
__global__ __launch_bounds__(512) void k_sel(const float* __restrict__ ndb,
                                             int* __restrict__ idx2) {
  const int t = threadIdx.x, lane = t & 63, w = t >> 6;
  const int row = blockIdx.x * 8 + w;
  const float* __restrict__ nr = ndb + (size_t)row * NPTS;
  float nd[32];
  #pragma unroll
  for (int s = 0; s < 32; ++s) nd[s] = nr[s * 64 + lane];
  extract_top32(nd, lane, idx2 + (size_t)row * KNBR);
}

// ======== shared gather helper for conv3/conv4 (MFMA feature tile) ========
// f2z layout: [128 samples][136 f16] (pad 8), channels 0-63 = nbr-ctr, 64-127 = ctr
DI void gather_f2(const float* __restrict__ hb, const int* __restrict__ idx2,
                  int row0, int t, const float ctr[4][64], _Float16* __restrict__ f2z) {
  const int s = t >> 1, hh = t & 1;
  const int r = s >> 5, k = s & 31;
  const int j = idx2[(size_t)(row0 + r) * KNBR + k];
  const float* __restrict__ nv = hb + (size_t)j * 64 + hh * 32;
  const float* cv = &ctr[r][hh * 32];
  _Float16* fp = f2z + s * 136 + 32 * hh;
  _Float16* cp = fp + 64;
  #pragma unroll
  for (int i = 0; i < 32; i += 8) {
    float4 v0 = *reinterpret_cast<const float4*>(nv + i);
    float4 v1 = *reinterpret_cast<const float4*>(nv + i + 4);
    UH8 dd, cc;
    dd.h[0] = (_Float16)(v0.x - cv[i + 0]); dd.h[1] = (_Float16)(v0.y - cv[i + 1]);
    dd.h[2] = (_Float16)(v0.z - cv[i + 2]); dd.h[3] = (_Float16)(v0.w - cv[i + 3]);
    dd.h[4] = (_Float16)(v1.x - cv[i + 4]); dd.h[5] = (_Float16)(v1.y - cv[i + 5]);
    dd.h[6] = (_Float16)(v1.z - cv[i + 6]); dd.h[7] = (_Float16)(v1.w - cv[i + 7]);
    cc.h[0] = (_Float16)cv[i + 0]; cc.h[1] = (_Float16)cv[i + 1];
    cc.h[2] = (_Float16)cv[i + 2]; cc.h[3] = (_Float16)cv[i + 3];
    cc.h[4] = (_Float16)cv[i + 4]; cc.h[5] = (_Float16)cv[i + 5];
    cc.h[6] = (_Float16)cv[i + 6]; cc.h[7] = (_Float16)cv[i + 7];
    *reinterpret_cast<uint4*>(fp + i) = dd.u;
    *reinterpret_cast<uint4*>(cp + i) = cc.u;
  }
}

DI f16x8 packw8(const float* __restrict__ wr) {
  float4 a = *reinterpret_cast<const float4*>(wr);
  float4 bq = *reinterpret_cast<const float4*>(wr + 4);
  f16x8 f;
  f[0] = (_Float16)a.x; f[1] = (_Float16)a.y; f[2] = (_Float16)a.z; f[3] = (_Float16)a.w;
  f[4] = (_Float16)bq.x; f[5] = (_Float16)bq.y; f[6] = (_Float16)bq.z; f[7] = (_Float16)bq.w;
  return f;
}

// ---------------- K8a: conv3 stats pass (MFMA f16) ----------------
// 4096 blocks x 4 rows (128 samples). Wave w owns out-slice [32w,32w+32).
__global__ __launch_bounds__(256) void k_conv3m(
    const float* __restrict__ h1t, const int* __restrict__ idx2,
    const float* __restrict__ w3, float* __restrict__ gS3, float* __restrict__ gSS3) {
  __shared__ __align__(16) _Float16 f2z[128 * 136];
  __shared__ float ctr[4][64];
  const int t = threadIdx.x;
  const int blk = blockIdx.x;
  const int row0 = blk * 4;
  const int b = row0 >> 11;
  const float* __restrict__ hb = h1t + (size_t)b * NPTS * 64;
  ctr[t >> 6][t & 63] = hb[(size_t)((row0 & (NPTS - 1)) + (t >> 6)) * 64 + (t & 63)];
  __syncthreads();
  gather_f2(hb, idx2, row0, t, ctr, f2z);
  const int lane = t & 63, w = t >> 6;
  const int c15 = lane & 15, g = lane >> 4;
  f16x8 Bf[2][4];
  #pragma unroll
  for (int nt = 0; nt < 2; ++nt) {
    const float* wr = w3 + (32 * w + 16 * nt + c15) * 128 + 8 * g;
    #pragma unroll
    for (int ks = 0; ks < 4; ++ks) Bf[nt][ks] = packw8(wr + ks * 32);
  }
  __syncthreads();
  f32x4 acc[8][2] = {};
  #pragma unroll
  for (int mt = 0; mt < 8; ++mt) {
    #pragma unroll
    for (int ks = 0; ks < 4; ++ks) {
      UH8 av;
      av.u = *reinterpret_cast<const uint4*>(&f2z[(16 * mt + c15) * 136 + ks * 32 + g * 8]);
      acc[mt][0] = __builtin_amdgcn_mfma_f32_16x16x32_f16(av.h, Bf[0][ks], acc[mt][0], 0, 0, 0);
      acc[mt][1] = __builtin_amdgcn_mfma_f32_16x16x32_f16(av.h, Bf[1][ks], acc[mt][1], 0, 0, 0);
    }
  }
  #pragma unroll
  for (int nt = 0; nt < 2; ++nt) {
    float s = 0.f, ss = 0.f;
    #pragma unroll
    for (int mt = 0; mt < 8; ++mt)
      #pragma unroll
      for (int r = 0; r < 4; ++r) { float v = acc[mt][nt][r]; s += v; ss += v * v; }
    s += __shfl_xor(s, 16); ss += __shfl_xor(ss, 16);
    s += __shfl_xor(s, 32); ss += __shfl_xor(ss, 32);
    if (lane < 16) {
      atomicAdd(&gS3[32 * w + 16 * nt + c15], s);
      atomicAdd(&gSS3[32 * w + 16 * nt + c15], ss);
    }
  }
}

// ---------------- K8b: conv3(recompute)+BN3+lrelu -> conv4 + stats4 + k-max/min (MFMA) ----------------
__global__ __launch_bounds__(256) void k_conv4m(
    const float* __restrict__ h1t, const int* __restrict__ idx2,
    const float* __restrict__ w3, const float* __restrict__ w4,
    const float* __restrict__ sc3g, const float* __restrict__ sh3g,
    float* __restrict__ h2max, float* __restrict__ h2min,
    float* __restrict__ gS4, float* __restrict__ gSS4) {
  __shared__ __align__(16) _Float16 f2z[128 * 136];   // feat2, then reused as z3
  __shared__ float ctr[4][64];
  const int t = threadIdx.x;
  const int blk = blockIdx.x;
  const int row0 = blk * 4;
  const int b = row0 >> 11;
  const float* __restrict__ hb = h1t + (size_t)b * NPTS * 64;
  ctr[t >> 6][t & 63] = hb[(size_t)((row0 & (NPTS - 1)) + (t >> 6)) * 64 + (t & 63)];
  __syncthreads();
  gather_f2(hb, idx2, row0, t, ctr, f2z);
  const int lane = t & 63, w = t >> 6;
  const int c15 = lane & 15, g = lane >> 4;
  f16x8 Bf[2][4];
  float sc3v[2], sh3v[2];
  #pragma unroll
  for (int nt = 0; nt < 2; ++nt) {
    const int ch = 32 * w + 16 * nt + c15;
    const float* wr = w3 + ch * 128 + 8 * g;
    #pragma unroll
    for (int ks = 0; ks < 4; ++ks) Bf[nt][ks] = packw8(wr + ks * 32);
    sc3v[nt] = sc3g[ch]; sh3v[nt] = sh3g[ch];
  }
  f16x8 B4[4];
  const int o4 = 16 * w + c15;
  {
    const float* wr = w4 + o4 * 128 + 8 * g;
    #pragma unroll
    for (int ks = 0; ks < 4; ++ks) B4[ks] = packw8(wr + ks * 32);
  }
  __syncthreads();
  f32x4 acc[8][2] = {};
  #pragma unroll
  for (int mt = 0; mt < 8; ++mt) {
    #pragma unroll
    for (int ks = 0; ks < 4; ++ks) {
      UH8 av;
      av.u = *reinterpret_cast<const uint4*>(&f2z[(16 * mt + c15) * 136 + ks * 32 + g * 8]);
      acc[mt][0] = __builtin_amdgcn_mfma_f32_16x16x32_f16(av.h, Bf[0][ks], acc[mt][0], 0, 0, 0);
      acc[mt][1] = __builtin_amdgcn_mfma_f32_16x16x32_f16(av.h, Bf[1][ks], acc[mt][1], 0, 0, 0);
    }
  }
  __syncthreads();  // all waves done reading f2z
  // z3 = lrelu(BN3(y3)) written into f2z (same [s][136] geometry, ch = conv3 out)
  #pragma unroll
  for (int mt = 0; mt < 8; ++mt)
    #pragma unroll
    for (int nt = 0; nt < 2; ++nt)
      #pragma unroll
      for (int r = 0; r < 4; ++r) {
        float z = acc[mt][nt][r] * sc3v[nt] + sh3v[nt];
        z = z > 0.f ? z : SLOPEV * z;
        f2z[(16 * mt + 4 * g + r) * 136 + 32 * w + 16 * nt + c15] = (_Float16)z;
      }
  __syncthreads();
  f32x4 a4[8] = {};
  #pragma unroll
  for (int mt = 0; mt < 8; ++mt) {
    #pragma unroll
    for (int ks = 0; ks < 4; ++ks) {
      UH8 av;
      av.u = *reinterpret_cast<const uint4*>(&f2z[(16 * mt + c15) * 136 + ks * 32 + g * 8]);
      a4[mt] = __builtin_amdgcn_mfma_f32_16x16x32_f16(av.h, B4[ks], a4[mt], 0, 0, 0);
    }
  }
  // stats + per-row max/min over k (row = mt>>1)
  float s = 0.f, ss = 0.f;
  float mx[4], mn[4];
  #pragma unroll
  for (int rp = 0; rp < 4; ++rp) { mx[rp] = -3.0e38f; mn[rp] = 3.0e38f; }
  #pragma unroll
  for (int mt = 0; mt < 8; ++mt) {
    const int rp = mt >> 1;
    #pragma unroll
    for (int r = 0; r < 4; ++r) {
      float v = a4[mt][r];
      s += v; ss += v * v;
      mx[rp] = fmaxf(mx[rp], v); mn[rp] = fminf(mn[rp], v);
    }
  }
  s += __shfl_xor(s, 16); ss += __shfl_xor(ss, 16);
  s += __shfl_xor(s, 32); ss += __shfl_xor(ss, 32);
  #pragma unroll
  for (int rp = 0; rp < 4; ++rp) {
    mx[rp] = fmaxf(mx[rp], __shfl_xor(mx[rp], 16));
    mx[rp] = fmaxf(mx[rp], __shfl_xor(mx[rp], 32));
    mn[rp] = fminf(mn[rp], __shfl_xor(mn[rp], 16));
    mn[rp] = fminf(mn[rp], __shfl_xor(mn[rp], 32));
  }
  if (lane < 16) {
    #pragma unroll
    for (int rp = 0; rp < 4; ++rp) {
      h2max[(size_t)(row0 + rp) * 64 + o4] = mx[rp];
      h2min[(size_t)(row0 + rp) * 64 + o4] = mn[rp];
    }
    atomicAdd(&gS4[o4], s);
    atomicAdd(&gSS4[o4], ss);
  }
}

// ---------------- host launcher ----------------
extern "C" void kernel_launch(void* const* d_in, const int* in_sizes, int n_in,
                              void* d_out, int out_size, void* d_ws, size_t ws_size,
                              hipStream_t stream) {
  const float* x = (const float*)d_in[0];
  const float* w1 = (const float*)d_in[1];
  const float* g1 = (const float*)d_in[2];
  const float* b1 = (const float*)d_in[3];
  const float* w2 = (const float*)d_in[4];
  const float* g2 = (const float*)d_in[5];
  const float* b2 = (const float*)d_in[6];
  const float* w3 = (const float*)d_in[7];
  const float* g3 = (const float*)d_in[8];
  const float* b3 = (const float*)d_in[9];
  const float* w4 = (const float*)d_in[10];
  const float* g4 = (const float*)d_in[11];
  const float* b4 = (const float*)d_in[12];
  float* out = (float*)d_out;
  char* ws = (char*)d_ws;
  int* idx1 = (int*)(ws + OFF_IDX1);
  int* idx2 = (int*)(ws + OFF_IDX2);
  float* h1t = (float*)(ws + OFF_H1T);
  float* stat = (float*)(ws + OFF_STAT);
  float* nsq = (float*)(ws + OFF_NSQ);
  float* big0 = (float*)(ws + OFF_BIG);
  float* big1 = (float*)(ws + OFF_BIG + 4u * 1024u * 1024u);
  float* ndb = (float*)(ws + OFF_BIG);

  hipMemsetAsync(stat, 0, 8192, stream);
  hipLaunchKernelGGL(k_topk1, dim3(4096), dim3(256), 0, stream, x, idx1);
  hipLaunchKernelGGL(k_featstats, dim3(64), dim3(256), 0, stream, x, idx1, stat);
  hipLaunchKernelGGL(k_bnprep1, dim3(1), dim3(128), 0, stream, stat, w1, g1, b1, stat + SC1, stat + SH1);
  hipLaunchKernelGGL(k_conv12, dim3(8192), dim3(256), 0, stream, x, idx1, w1, w2,
                     stat + SC1, stat + SH1, big0, big1, stat + S2o, stat + SS2o);
  hipLaunchKernelGGL(k_bnprep, dim3(1), dim3(128), 0, stream, stat + S2o, stat + SS2o, g2, b2,
                     stat + SC2, stat + SH2, 64);
  hipLaunchKernelGGL(k_finbn, dim3(128), dim3(256), 0, stream, big0, big1,
                     stat + SC2, stat + SH2, out, 0, h1t, nsq);
  hipLaunchKernelGGL(k_dist, dim3(2048), dim3(256), 0, stream, h1t, nsq, ndb);
  hipLaunchKernelGGL(k_sel, dim3(2048), dim3(512), 0, stream, ndb, idx2);
  hipLaunchKernelGGL(k_conv3m, dim3(4096), dim3(256), 0, stream, h1t, idx2, w3, stat + S3o, stat + SS3o);
  hipLaunchKernelGGL(k_bnprep, dim3(1), dim3(128), 0, stream, stat + S3o, stat + SS3o, g3, b3,
                     stat + SC3, stat + SH3, 128);
  hipLaunchKernelGGL(k_conv4m, dim3(4096), dim3(256), 0, stream, h1t, idx2, w3, w4,
                     stat + SC3, stat + SH3, big0, big1, stat + S4o, stat + SS4o);
  hipLaunchKernelGGL(k_bnprep, dim3(1), dim3(128), 0, stream, stat + S4o, stat + SS4o, g4, b4,
                     stat + SC4, stat + SH4, 64);
  hipLaunchKernelGGL(k_finbn, dim3(128), dim3(256), 0, stream, big0, big1,
                     stat + SC4, stat + SH4, out, 64, (float*)nullptr, (float*)nullptr);
  (void)in_sizes; (void)n_in; (void)out_size; (void)ws_size;
}

// Round 6
// 935.543 us; speedup vs baseline: 8.5053x; 1.1223x over previous
//
#include <hip/hip_runtime.h>

#define DI __device__ __forceinline__

typedef _Float16 f16x2 __attribute__((ext_vector_type(2)));
typedef _Float16 f16x8 __attribute__((ext_vector_type(8)));
typedef float f32x4 __attribute__((ext_vector_type(4)));

#define NPTS 2048
#define KNBR 32
#define SALL 524288.0f
#define EPSV 1e-5f
#define SLOPEV 0.2f

// ---------------- workspace layout (bytes), total 144 MiB ----------------
#define OFF_IDX1 0u
#define OFF_IDX2 (2u*1024u*1024u)
#define OFF_H1T  (4u*1024u*1024u)
#define OFF_STAT (8u*1024u*1024u)
#define OFF_NSQ  (9u*1024u*1024u)
#define OFF_BIG  (16u*1024u*1024u)
// BIG region (128 MiB) time-multiplexed:
//   phase A: h1max @ BIG, h1min @ BIG+4MiB   (conv12 -> finbn2)
//   phase B: ndb   @ BIG (128 MiB)           (dist -> sel)
//   phase C: h2max @ BIG, h2min @ BIG+4MiB   (conv4 -> finbn4)
// stat float offsets
#define SF0 0
#define SC1 32
#define SH1 160
#define S2o 288
#define SS2o 352
#define SC2 416
#define SH2 480
#define S3o 544
#define SS3o 672
#define SC3 800
#define SH3 928
#define S4o 1056
#define SS4o 1120
#define SC4 1184
#define SH4 1248

union U4 { uint4 u; float f[4]; };
union UH8 { uint4 u; f16x8 h; };

DI float lrelu(float z) { return z > 0.f ? z : SLOPEV * z; }

// Exact top-32 of 2048 values held as nd[s] per lane (value j = s*64+lane).
DI void extract_top32(float (&nd)[32], int lane, int* __restrict__ outp) {
  int myj = 0;
  #pragma nounroll
  for (int it = 0; it < 32; ++it) {
    float tm[16];
    #pragma unroll
    for (int s = 0; s < 16; ++s) tm[s] = fmaxf(nd[s], nd[s + 16]);
    #pragma unroll
    for (int s = 0; s < 8; ++s) tm[s] = fmaxf(tm[s], tm[s + 8]);
    #pragma unroll
    for (int s = 0; s < 4; ++s) tm[s] = fmaxf(tm[s], tm[s + 4]);
    float m = fmaxf(fmaxf(tm[0], tm[2]), fmaxf(tm[1], tm[3]));
    int slot = 0;
    #pragma unroll
    for (int s = 31; s >= 0; --s) slot = (nd[s] == m) ? s : slot;  // lowest slot wins
    int j = slot * 64 + lane;
    float v = m;
    #pragma unroll
    for (int d = 1; d < 64; d <<= 1) {
      float vo = __shfl_xor(v, d);
      int jo = __shfl_xor(j, d);
      bool take = (vo > v) || ((vo == v) && (jo < j));
      v = take ? vo : v;
      j = take ? jo : j;
    }
    int sel = (lane == (j & 63)) ? (j >> 6) : 64;
    #pragma unroll
    for (int s = 0; s < 32; ++s) nd[s] = (s == sel) ? -3.0e38f : nd[s];
    myj = (it == lane) ? j : myj;
  }
  if (lane < 32) outp[lane] = myj;
}

// ---------------- K1: stage-1 top-k (C=3) ----------------
__global__ __launch_bounds__(256) void k_topk1(const float* __restrict__ x, int* __restrict__ idx1) {
  __shared__ float xl[NPTS * 3];
  __shared__ float sq[NPTS];
  const int t = threadIdx.x;
  const int blk4 = blockIdx.x * 4;
  const int b = blk4 >> 11;
  const float* __restrict__ xb = x + (size_t)b * 3 * NPTS;
  for (int e = t; e < 3 * NPTS; e += 256) {
    int c = e >> 11, n = e & (NPTS - 1);
    xl[n * 3 + c] = xb[e];
  }
  __syncthreads();
  for (int n = t; n < NPTS; n += 256) {
    float a0 = xl[n * 3], a1 = xl[n * 3 + 1], a2 = xl[n * 3 + 2];
    sq[n] = a0 * a0 + a1 * a1 + a2 * a2;
  }
  __syncthreads();
  const int lane = t & 63, w = t >> 6;
  const int row = blk4 + w;
  const int i = row & (NPTS - 1);
  const float xi0 = xl[i * 3], xi1 = xl[i * 3 + 1], xi2 = xl[i * 3 + 2];
  const float si = sq[i];
  float nd[32];
  #pragma unroll
  for (int s = 0; s < 32; ++s) {
    int j = s * 64 + lane;
    float d = xi0 * xl[j * 3] + xi1 * xl[j * 3 + 1] + xi2 * xl[j * 3 + 2];
    nd[s] = (2.0f * d - si) - sq[j];
  }
  extract_top32(nd, lane, idx1 + (size_t)row * KNBR);
}

// ---------------- K2: feat1 moments ----------------
__global__ __launch_bounds__(256) void k_featstats(const float* __restrict__ x,
                                                   const int* __restrict__ idx1,
                                                   float* __restrict__ stat) {
  __shared__ float red[27];
  const int t = threadIdx.x;
  if (t < 27) red[t] = 0.f;
  __syncthreads();
  const int row = blockIdx.x * 256 + t;
  const int b = row >> 11, i = row & (NPTS - 1);
  const float* __restrict__ xb = x + (size_t)b * 3 * NPTS;
  const float xi0 = xb[i], xi1 = xb[NPTS + i], xi2 = xb[2 * NPTS + i];
  float sd0 = 0, sd1 = 0, sd2 = 0, q00 = 0, q01 = 0, q02 = 0, q11 = 0, q12 = 0, q22 = 0;
  for (int k = 0; k < KNBR; ++k) {
    int j = idx1[(size_t)row * KNBR + k];
    float d0 = xb[j] - xi0, d1 = xb[NPTS + j] - xi1, d2 = xb[2 * NPTS + j] - xi2;
    sd0 += d0; sd1 += d1; sd2 += d2;
    q00 += d0 * d0; q01 += d0 * d1; q02 += d0 * d2;
    q11 += d1 * d1; q12 += d1 * d2; q22 += d2 * d2;
  }
  float v[27];
  v[0] = sd0; v[1] = sd1; v[2] = sd2; v[3] = 32.f * xi0; v[4] = 32.f * xi1; v[5] = 32.f * xi2;
  v[6] = q00; v[7] = q01; v[8] = q02; v[9] = sd0 * xi0; v[10] = sd0 * xi1; v[11] = sd0 * xi2;
  v[12] = q11; v[13] = q12; v[14] = sd1 * xi0; v[15] = sd1 * xi1; v[16] = sd1 * xi2;
  v[17] = q22; v[18] = sd2 * xi0; v[19] = sd2 * xi1; v[20] = sd2 * xi2;
  v[21] = 32.f * xi0 * xi0; v[22] = 32.f * xi0 * xi1; v[23] = 32.f * xi0 * xi2;
  v[24] = 32.f * xi1 * xi1; v[25] = 32.f * xi1 * xi2; v[26] = 32.f * xi2 * xi2;
  #pragma unroll
  for (int qq = 0; qq < 27; ++qq) {
    float s = v[qq];
    #pragma unroll
    for (int d = 1; d < 64; d <<= 1) s += __shfl_xor(s, d);
    if ((t & 63) == 0) atomicAdd(&red[qq], s);
  }
  __syncthreads();
  if (t < 27) atomicAdd(&stat[SF0 + t], red[t]);
}

// ---------------- K3: BN1 params from feature moments ----------------
__global__ void k_bnprep1(const float* __restrict__ stat, const float* __restrict__ w1,
                          const float* __restrict__ g1, const float* __restrict__ b1,
                          float* __restrict__ sc1, float* __restrict__ sh1) {
  __shared__ float M[36], mu[6];
  const int t = threadIdx.x;
  const float inv = 1.0f / SALL;
  if (t < 6) mu[t] = stat[SF0 + t] * inv;
  if (t < 36) {
    int a = t / 6, bq = t % 6;
    int aa = a < bq ? a : bq, bb = a < bq ? bq : a;
    int pos = aa * 6 - aa * (aa + 1) / 2 + bb;
    M[t] = stat[SF0 + 6 + pos] * inv;
  }
  __syncthreads();
  if (t < 128) {
    const float* w = w1 + t * 6;
    float m = 0.f;
    for (int c = 0; c < 6; ++c) m += w[c] * mu[c];
    float e2 = 0.f;
    for (int a = 0; a < 6; ++a)
      for (int c = 0; c < 6; ++c) e2 += w[a] * w[c] * M[a * 6 + c];
    float var = e2 - m * m;
    float rstd = rsqrtf(var + EPSV);
    float s = g1[t] * rstd;
    sc1[t] = s;
    sh1[t] = b1[t] - m * s;
  }
}

// ---------------- generic BN prep ----------------
__global__ void k_bnprep(const float* __restrict__ s, const float* __restrict__ ss,
                         const float* __restrict__ g, const float* __restrict__ bb,
                         float* __restrict__ sc, float* __restrict__ sh, int nch) {
  const int t = threadIdx.x;
  if (t < nch) {
    const float inv = 1.0f / SALL;
    float m = s[t] * inv;
    float var = ss[t] * inv - m * m;
    float rstd = rsqrtf(var + EPSV);
    float scale = g[t] * rstd;
    sc[t] = scale;
    sh[t] = bb[t] - m * scale;
  }
}

// ---------------- K4: gather + conv1(fp32) + BN1 + lrelu + conv2(split-f16 MFMA) ----------------
// 4096 blocks x 4 rows (128 samples). Wave w owns out-slice [16w,16w+16).
// Split precision: z1 = z1h + z1lo, w2 = Bh + Bl (f16 each);
// y2 = Ah*Bh + Al*Bh + Ah*Bl accumulated fp32 (drops Al*Bl ~1e-7) => ~fp32 accuracy.
__global__ __launch_bounds__(256) void k_conv12m(
    const float* __restrict__ x, const int* __restrict__ idx1,
    const float* __restrict__ w1, const float* __restrict__ w2,
    const float* __restrict__ sc1g, const float* __restrict__ sh1g,
    float* __restrict__ h1max, float* __restrict__ h1min,
    float* __restrict__ gS2, float* __restrict__ gSS2) {
  __shared__ __align__(16) _Float16 z1h[128 * 136];
  __shared__ __align__(16) _Float16 z1lo[128 * 136];
  __shared__ float featl[6][128];
  __shared__ float w1l[768];
  const int t = threadIdx.x;
  const int blk = blockIdx.x;
  const int row0 = blk * 4;
  const int b = row0 >> 11;
  const float* __restrict__ xb = x + (size_t)b * 3 * NPTS;
  for (int e = t; e < 768; e += 256) w1l[e] = w1[e];
  if (t < 128) {
    int r = t >> 5;
    int n = (row0 & (NPTS - 1)) + r;
    int j = idx1[(size_t)(row0 + r) * KNBR + (t & 31)];
    float c0 = xb[n], c1 = xb[NPTS + n], c2 = xb[2 * NPTS + n];
    featl[0][t] = xb[j] - c0;
    featl[1][t] = xb[NPTS + j] - c1;
    featl[2][t] = xb[2 * NPTS + j] - c2;
    featl[3][t] = c0; featl[4][t] = c1; featl[5][t] = c2;
  }
  __syncthreads();
  {  // conv1 + BN1 + lrelu -> split into f16 hi/lo; thread owns (sample t>>1, 64 ch half)
    const int s = t >> 1, hh = t & 1;
    float f0 = featl[0][s], f1 = featl[1][s], f2 = featl[2][s];
    float f3 = featl[3][s], f4 = featl[4][s], f5 = featl[5][s];
    #pragma unroll
    for (int chunk = 0; chunk < 8; ++chunk) {
      UH8 hi8, lo8;
      #pragma unroll
      for (int i = 0; i < 8; ++i) {
        int c = hh * 64 + chunk * 8 + i;
        const float* wr = &w1l[c * 6];
        float y = wr[0] * f0 + wr[1] * f1 + wr[2] * f2 + wr[3] * f3 + wr[4] * f4 + wr[5] * f5;
        float z = y * sc1g[c] + sh1g[c];
        z = z > 0.f ? z : SLOPEV * z;
        _Float16 h = (_Float16)z;
        hi8.h[i] = h;
        lo8.h[i] = (_Float16)(z - (float)h);
      }
      *reinterpret_cast<uint4*>(&z1h[s * 136 + hh * 64 + chunk * 8]) = hi8.u;
      *reinterpret_cast<uint4*>(&z1lo[s * 136 + hh * 64 + chunk * 8]) = lo8.u;
    }
  }
  const int lane = t & 63, w = t >> 6;
  const int c15 = lane & 15, g = lane >> 4;
  const int o4 = 16 * w + c15;
  f16x8 Bh[4], Bl[4];
  #pragma unroll
  for (int ks = 0; ks < 4; ++ks) {
    const float* wr = w2 + o4 * 128 + ks * 32 + g * 8;
    #pragma unroll
    for (int i = 0; i < 8; ++i) {
      float v = wr[i];
      _Float16 h = (_Float16)v;
      Bh[ks][i] = h;
      Bl[ks][i] = (_Float16)(v - (float)h);
    }
  }
  __syncthreads();
  f32x4 acc[8] = {};
  #pragma unroll
  for (int mt = 0; mt < 8; ++mt) {
    #pragma unroll
    for (int ks = 0; ks < 4; ++ks) {
      UH8 ah, al;
      ah.u = *reinterpret_cast<const uint4*>(&z1h[(16 * mt + c15) * 136 + ks * 32 + g * 8]);
      al.u = *reinterpret_cast<const uint4*>(&z1lo[(16 * mt + c15) * 136 + ks * 32 + g * 8]);
      acc[mt] = __builtin_amdgcn_mfma_f32_16x16x32_f16(ah.h, Bh[ks], acc[mt], 0, 0, 0);
      acc[mt] = __builtin_amdgcn_mfma_f32_16x16x32_f16(al.h, Bh[ks], acc[mt], 0, 0, 0);
      acc[mt] = __builtin_amdgcn_mfma_f32_16x16x32_f16(ah.h, Bl[ks], acc[mt], 0, 0, 0);
    }
  }
  // stats + per-row max/min over k (row = mt>>1); D layout: sample = 16mt+4g+r, ch = o4
  float s = 0.f, ss = 0.f;
  float mx[4], mn[4];
  #pragma unroll
  for (int rp = 0; rp < 4; ++rp) { mx[rp] = -3.0e38f; mn[rp] = 3.0e38f; }
  #pragma unroll
  for (int mt = 0; mt < 8; ++mt) {
    const int rp = mt >> 1;
    #pragma unroll
    for (int r = 0; r < 4; ++r) {
      float v = acc[mt][r];
      s += v; ss += v * v;
      mx[rp] = fmaxf(mx[rp], v); mn[rp] = fminf(mn[rp], v);
    }
  }
  s += __shfl_xor(s, 16); ss += __shfl_xor(ss, 16);
  s += __shfl_xor(s, 32); ss += __shfl_xor(ss, 32);
  #pragma unroll
  for (int rp = 0; rp < 4; ++rp) {
    mx[rp] = fmaxf(mx[rp], __shfl_xor(mx[rp], 16));
    mx[rp] = fmaxf(mx[rp], __shfl_xor(mx[rp], 32));
    mn[rp] = fminf(mn[rp], __shfl_xor(mn[rp], 16));
    mn[rp] = fminf(mn[rp], __shfl_xor(mn[rp], 32));
  }
  if (lane < 16) {
    #pragma unroll
    for (int rp = 0; rp < 4; ++rp) {
      h1max[(size_t)(row0 + rp) * 64 + o4] = mx[rp];
      h1min[(size_t)(row0 + rp) * 64 + o4] = mn[rp];
    }
    atomicAdd(&gS2[o4], s);
    atomicAdd(&gSS2[o4], ss);
  }
}

// ---------------- K5: BN + lrelu epilogue from (max,min); writes out (+h1t,+nsq) ----------------
__global__ __launch_bounds__(256) void k_finbn(
    const float* __restrict__ hmax, const float* __restrict__ hmin,
    const float* __restrict__ scg, const float* __restrict__ shg,
    float* __restrict__ out, const int choff,
    float* __restrict__ h1t, float* __restrict__ nsq) {
  __shared__ float ht[128][65];
  const int t = threadIdx.x;
  const int blk = blockIdx.x;          // 128 blocks x 128 rows
  const int row0 = blk * 128;
  const int b = row0 >> 11, n0 = row0 & (NPTS - 1);
  const int c = t & 63;
  const float sc = scg[c], sh = shg[c];
  const int rbase = t >> 6;
  for (int it = 0; it < 32; ++it) {
    int rl = it * 4 + rbase;
    size_t gi = (size_t)(row0 + rl) * 64 + c;
    float y = sc > 0.f ? hmax[gi] : hmin[gi];
    float h = lrelu(sc * y + sh);
    if (h1t) h1t[gi] = h;
    ht[rl][c] = h;
  }
  __syncthreads();
  if (nsq && t < 128) {
    float s = 0.f;
    #pragma unroll
    for (int c2 = 0; c2 < 64; ++c2) { float v = ht[t][c2]; s += v * v; }
    nsq[row0 + t] = s;
  }
  const int co = t >> 2, i0 = (t & 3) * 32;
  float* __restrict__ op = out + ((size_t)b * 128 + choff + co) * NPTS + n0 + i0;
  for (int i = 0; i < 32; i += 4) {
    float4 v;
    v.x = ht[i0 + i][co]; v.y = ht[i0 + i + 1][co];
    v.z = ht[i0 + i + 2][co]; v.w = ht[i0 + i + 3][co];
    *reinterpret_cast<float4*>(op + i) = v;
  }
}

// ---------------- K7b: ND = 2*H*H^T - n_i - n_j ----------------
#define BCOL(c) ((c) + (((c) >> 5) << 2))
__global__ __launch_bounds__(256) void k_dist(const float* __restrict__ h1t,
                                              const float* __restrict__ nsq,
                                              float* __restrict__ ndb) {
  __shared__ __align__(16) float Al[32][132];
  __shared__ __align__(16) float Bl[32][140];
  const int t = threadIdx.x;
  const int bt = blockIdx.x >> 8, rem = blockIdx.x & 255;
  const int ti = rem >> 4, tj = rem & 15;
  const float* __restrict__ hb = h1t + (size_t)bt * NPTS * 64;
  const int r0 = ti * 128, c0 = tj * 128;
  const int tx = t & 15, ty = t >> 4;
  float acc[8][8] = {};
  for (int kk = 0; kk < 64; kk += 32) {
    __syncthreads();
    for (int e = t; e < 1024; e += 256) {
      int r = e >> 3, c4 = e & 7;
      float4 va = *reinterpret_cast<const float4*>(hb + (size_t)(r0 + r) * 64 + kk + c4 * 4);
      int cb = c4 * 4;
      Al[cb][r] = va.x; Al[cb + 1][r] = va.y; Al[cb + 2][r] = va.z; Al[cb + 3][r] = va.w;
      float4 vb = *reinterpret_cast<const float4*>(hb + (size_t)(c0 + r) * 64 + kk + c4 * 4);
      int rp = BCOL(r);
      Bl[cb][rp] = vb.x; Bl[cb + 1][rp] = vb.y; Bl[cb + 2][rp] = vb.z; Bl[cb + 3][rp] = vb.w;
    }
    __syncthreads();
    #pragma unroll 8
    for (int k = 0; k < 32; ++k) {
      U4 a0; a0.u = *reinterpret_cast<const uint4*>(&Al[k][ty * 8]);
      U4 a1; a1.u = *reinterpret_cast<const uint4*>(&Al[k][ty * 8 + 4]);
      U4 b0; b0.u = *reinterpret_cast<const uint4*>(&Bl[k][BCOL(tx * 8)]);
      U4 b1; b1.u = *reinterpret_cast<const uint4*>(&Bl[k][BCOL(tx * 8) + 4]);
      #pragma unroll
      for (int rr = 0; rr < 4; ++rr) {
        #pragma unroll
        for (int cc = 0; cc < 4; ++cc) {
          acc[rr][cc] += a0.f[rr] * b0.f[cc];
          acc[rr][cc + 4] += a0.f[rr] * b1.f[cc];
          acc[rr + 4][cc] += a1.f[rr] * b0.f[cc];
          acc[rr + 4][cc + 4] += a1.f[rr] * b1.f[cc];
        }
      }
    }
  }
  float nr[8], nc[8];
  const float* __restrict__ nb2 = nsq + (size_t)bt * NPTS;
  #pragma unroll
  for (int i = 0; i < 8; ++i) {
    nr[i] = nb2[r0 + ty * 8 + i];
    nc[i] = nb2[c0 + tx * 8 + i];
  }
  float* __restrict__ op = ndb + ((size_t)bt * NPTS + r0 + ty * 8) * NPTS + c0 + tx * 8;
  #pragma unroll
  for (int rr = 0; rr < 8; ++rr) {
    float4 o0, o1;
    o0.x = 2.f * acc[rr][0] - nr[rr] - nc[0];
    o0.y = 2.f * acc[rr][1] - nr[rr] - nc[1];
    o0.z = 2.f * acc[rr][2] - nr[rr] - nc[2];
    o0.w = 2.f * acc[rr][3] - nr[rr] - nc[3];
    o1.x = 2.f * acc[rr][4] - nr[rr] - nc[4];
    o1.y = 2.f * acc[rr][5] - nr[rr] - nc[5];
    o1.z = 2.f * acc[rr][6] - nr[rr] - nc[6];
    o1.w = 2.f * acc[rr][7] - nr[rr] - nc[7];
    *reinterpret_cast<float4*>(op + (size_t)rr * NPTS) = o0;
    *reinterpret_cast<float4*>(op + (size_t)rr * NPTS + 4) = o1;
  }
}

// ---------------- K7c: streaming top-32 selection ----------------
__global__ __launch_bounds__(512) void k_sel(const float* __restrict__ ndb,
                                             int* __restrict__ idx2) {
  const int t = threadIdx.x, lane = t & 63, w = t >> 6;
  const int row = blockIdx.x * 8 + w;
  const float* __restrict__ nr = ndb + (size_t)row * NPTS;
  float nd[32];
  #pragma unroll
  for (int s = 0; s < 32; ++s) nd[s] = nr[s * 64 + lane];
  extract_top32(nd, lane, idx2 + (size_t)row * KNBR);
}

// ======== shared gather helper for conv3/conv4 (MFMA feature tile) ========
// f2z layout: [128 samples][136 f16] (pad 8), channels 0-63 = nbr-ctr, 64-127 = ctr
DI void gather_f2(const float* __restrict__ hb, const int* __restrict__ idx2,
                  int row0, int t, const float ctr[4][64], _Float16* __restrict__ f2z) {
  const int s = t >> 1, hh = t & 1;
  const int r = s >> 5, k = s & 31;
  const int j = idx2[(size_t)(row0 + r) * KNBR + k];
  const float* __restrict__ nv = hb + (size_t)j * 64 + hh * 32;
  const float* cv = &ctr[r][hh * 32];
  _Float16* fp = f2z + s * 136 + 32 * hh;
  _Float16* cp = fp + 64;
  #pragma unroll
  for (int i = 0; i < 32; i += 8) {
    float4 v0 = *reinterpret_cast<const float4*>(nv + i);
    float4 v1 = *reinterpret_cast<const float4*>(nv + i + 4);
    UH8 dd, cc;
    dd.h[0] = (_Float16)(v0.x - cv[i + 0]); dd.h[1] = (_Float16)(v0.y - cv[i + 1]);
    dd.h[2] = (_Float16)(v0.z - cv[i + 2]); dd.h[3] = (_Float16)(v0.w - cv[i + 3]);
    dd.h[4] = (_Float16)(v1.x - cv[i + 4]); dd.h[5] = (_Float16)(v1.y - cv[i + 5]);
    dd.h[6] = (_Float16)(v1.z - cv[i + 6]); dd.h[7] = (_Float16)(v1.w - cv[i + 7]);
    cc.h[0] = (_Float16)cv[i + 0]; cc.h[1] = (_Float16)cv[i + 1];
    cc.h[2] = (_Float16)cv[i + 2]; cc.h[3] = (_Float16)cv[i + 3];
    cc.h[4] = (_Float16)cv[i + 4]; cc.h[5] = (_Float16)cv[i + 5];
    cc.h[6] = (_Float16)cv[i + 6]; cc.h[7] = (_Float16)cv[i + 7];
    *reinterpret_cast<uint4*>(fp + i) = dd.u;
    *reinterpret_cast<uint4*>(cp + i) = cc.u;
  }
}

DI f16x8 packw8(const float* __restrict__ wr) {
  float4 a = *reinterpret_cast<const float4*>(wr);
  float4 bq = *reinterpret_cast<const float4*>(wr + 4);
  f16x8 f;
  f[0] = (_Float16)a.x; f[1] = (_Float16)a.y; f[2] = (_Float16)a.z; f[3] = (_Float16)a.w;
  f[4] = (_Float16)bq.x; f[5] = (_Float16)bq.y; f[6] = (_Float16)bq.z; f[7] = (_Float16)bq.w;
  return f;
}

// ---------------- K8a: conv3 stats pass (MFMA f16) ----------------
__global__ __launch_bounds__(256) void k_conv3m(
    const float* __restrict__ h1t, const int* __restrict__ idx2,
    const float* __restrict__ w3, float* __restrict__ gS3, float* __restrict__ gSS3) {
  __shared__ __align__(16) _Float16 f2z[128 * 136];
  __shared__ float ctr[4][64];
  const int t = threadIdx.x;
  const int blk = blockIdx.x;
  const int row0 = blk * 4;
  const int b = row0 >> 11;
  const float* __restrict__ hb = h1t + (size_t)b * NPTS * 64;
  ctr[t >> 6][t & 63] = hb[(size_t)((row0 & (NPTS - 1)) + (t >> 6)) * 64 + (t & 63)];
  __syncthreads();
  gather_f2(hb, idx2, row0, t, ctr, f2z);
  const int lane = t & 63, w = t >> 6;
  const int c15 = lane & 15, g = lane >> 4;
  f16x8 Bf[2][4];
  #pragma unroll
  for (int nt = 0; nt < 2; ++nt) {
    const float* wr = w3 + (32 * w + 16 * nt + c15) * 128 + 8 * g;
    #pragma unroll
    for (int ks = 0; ks < 4; ++ks) Bf[nt][ks] = packw8(wr + ks * 32);
  }
  __syncthreads();
  f32x4 acc[8][2] = {};
  #pragma unroll
  for (int mt = 0; mt < 8; ++mt) {
    #pragma unroll
    for (int ks = 0; ks < 4; ++ks) {
      UH8 av;
      av.u = *reinterpret_cast<const uint4*>(&f2z[(16 * mt + c15) * 136 + ks * 32 + g * 8]);
      acc[mt][0] = __builtin_amdgcn_mfma_f32_16x16x32_f16(av.h, Bf[0][ks], acc[mt][0], 0, 0, 0);
      acc[mt][1] = __builtin_amdgcn_mfma_f32_16x16x32_f16(av.h, Bf[1][ks], acc[mt][1], 0, 0, 0);
    }
  }
  #pragma unroll
  for (int nt = 0; nt < 2; ++nt) {
    float s = 0.f, ss = 0.f;
    #pragma unroll
    for (int mt = 0; mt < 8; ++mt)
      #pragma unroll
      for (int r = 0; r < 4; ++r) { float v = acc[mt][nt][r]; s += v; ss += v * v; }
    s += __shfl_xor(s, 16); ss += __shfl_xor(ss, 16);
    s += __shfl_xor(s, 32); ss += __shfl_xor(ss, 32);
    if (lane < 16) {
      atomicAdd(&gS3[32 * w + 16 * nt + c15], s);
      atomicAdd(&gSS3[32 * w + 16 * nt + c15], ss);
    }
  }
}

// ---------------- K8b: conv3(recompute)+BN3+lrelu -> conv4 + stats4 + k-max/min (MFMA) ----------------
__global__ __launch_bounds__(256) void k_conv4m(
    const float* __restrict__ h1t, const int* __restrict__ idx2,
    const float* __restrict__ w3, const float* __restrict__ w4,
    const float* __restrict__ sc3g, const float* __restrict__ sh3g,
    float* __restrict__ h2max, float* __restrict__ h2min,
    float* __restrict__ gS4, float* __restrict__ gSS4) {
  __shared__ __align__(16) _Float16 f2z[128 * 136];   // feat2, then reused as z3
  __shared__ float ctr[4][64];
  const int t = threadIdx.x;
  const int blk = blockIdx.x;
  const int row0 = blk * 4;
  const int b = row0 >> 11;
  const float* __restrict__ hb = h1t + (size_t)b * NPTS * 64;
  ctr[t >> 6][t & 63] = hb[(size_t)((row0 & (NPTS - 1)) + (t >> 6)) * 64 + (t & 63)];
  __syncthreads();
  gather_f2(hb, idx2, row0, t, ctr, f2z);
  const int lane = t & 63, w = t >> 6;
  const int c15 = lane & 15, g = lane >> 4;
  f16x8 Bf[2][4];
  float sc3v[2], sh3v[2];
  #pragma unroll
  for (int nt = 0; nt < 2; ++nt) {
    const int ch = 32 * w + 16 * nt + c15;
    const float* wr = w3 + ch * 128 + 8 * g;
    #pragma unroll
    for (int ks = 0; ks < 4; ++ks) Bf[nt][ks] = packw8(wr + ks * 32);
    sc3v[nt] = sc3g[ch]; sh3v[nt] = sh3g[ch];
  }
  f16x8 B4[4];
  const int o4 = 16 * w + c15;
  {
    const float* wr = w4 + o4 * 128 + 8 * g;
    #pragma unroll
    for (int ks = 0; ks < 4; ++ks) B4[ks] = packw8(wr + ks * 32);
  }
  __syncthreads();
  f32x4 acc[8][2] = {};
  #pragma unroll
  for (int mt = 0; mt < 8; ++mt) {
    #pragma unroll
    for (int ks = 0; ks < 4; ++ks) {
      UH8 av;
      av.u = *reinterpret_cast<const uint4*>(&f2z[(16 * mt + c15) * 136 + ks * 32 + g * 8]);
      acc[mt][0] = __builtin_amdgcn_mfma_f32_16x16x32_f16(av.h, Bf[0][ks], acc[mt][0], 0, 0, 0);
      acc[mt][1] = __builtin_amdgcn_mfma_f32_16x16x32_f16(av.h, Bf[1][ks], acc[mt][1], 0, 0, 0);
    }
  }
  __syncthreads();  // all waves done reading f2z
  #pragma unroll
  for (int mt = 0; mt < 8; ++mt)
    #pragma unroll
    for (int nt = 0; nt < 2; ++nt)
      #pragma unroll
      for (int r = 0; r < 4; ++r) {
        float z = acc[mt][nt][r] * sc3v[nt] + sh3v[nt];
        z = z > 0.f ? z : SLOPEV * z;
        f2z[(16 * mt + 4 * g + r) * 136 + 32 * w + 16 * nt + c15] = (_Float16)z;
      }
  __syncthreads();
  f32x4 a4[8] = {};
  #pragma unroll
  for (int mt = 0; mt < 8; ++mt) {
    #pragma unroll
    for (int ks = 0; ks < 4; ++ks) {
      UH8 av;
      av.u = *reinterpret_cast<const uint4*>(&f2z[(16 * mt + c15) * 136 + ks * 32 + g * 8]);
      a4[mt] = __builtin_amdgcn_mfma_f32_16x16x32_f16(av.h, B4[ks], a4[mt], 0, 0, 0);
    }
  }
  float s = 0.f, ss = 0.f;
  float mx[4], mn[4];
  #pragma unroll
  for (int rp = 0; rp < 4; ++rp) { mx[rp] = -3.0e38f; mn[rp] = 3.0e38f; }
  #pragma unroll
  for (int mt = 0; mt < 8; ++mt) {
    const int rp = mt >> 1;
    #pragma unroll
    for (int r = 0; r < 4; ++r) {
      float v = a4[mt][r];
      s += v; ss += v * v;
      mx[rp] = fmaxf(mx[rp], v); mn[rp] = fminf(mn[rp], v);
    }
  }
  s += __shfl_xor(s, 16); ss += __shfl_xor(ss, 16);
  s += __shfl_xor(s, 32); ss += __shfl_xor(ss, 32);
  #pragma unroll
  for (int rp = 0; rp < 4; ++rp) {
    mx[rp] = fmaxf(mx[rp], __shfl_xor(mx[rp], 16));
    mx[rp] = fmaxf(mx[rp], __shfl_xor(mx[rp], 32));
    mn[rp] = fminf(mn[rp], __shfl_xor(mn[rp], 16));
    mn[rp] = fminf(mn[rp], __shfl_xor(mn[rp], 32));
  }
  if (lane < 16) {
    #pragma unroll
    for (int rp = 0; rp < 4; ++rp) {
      h2max[(size_t)(row0 + rp) * 64 + o4] = mx[rp];
      h2min[(size_t)(row0 + rp) * 64 + o4] = mn[rp];
    }
    atomicAdd(&gS4[o4], s);
    atomicAdd(&gSS4[o4], ss);
  }
}

// ---------------- host launcher ----------------
extern "C" void kernel_launch(void* const* d_in, const int* in_sizes, int n_in,
                              void* d_out, int out_size, void* d_ws, size_t ws_size,
                              hipStream_t stream) {
  const float* x = (const float*)d_in[0];
  const float* w1 = (const float*)d_in[1];
  const float* g1 = (const float*)d_in[2];
  const float* b1 = (const float*)d_in[3];
  const float* w2 = (const float*)d_in[4];
  const float* g2 = (const float*)d_in[5];
  const float* b2 = (const float*)d_in[6];
  const float* w3 = (const float*)d_in[7];
  const float* g3 = (const float*)d_in[8];
  const float* b3 = (const float*)d_in[9];
  const float* w4 = (const float*)d_in[10];
  const float* g4 = (const float*)d_in[11];
  const float* b4 = (const float*)d_in[12];
  float* out = (float*)d_out;
  char* ws = (char*)d_ws;
  int* idx1 = (int*)(ws + OFF_IDX1);
  int* idx2 = (int*)(ws + OFF_IDX2);
  float* h1t = (float*)(ws + OFF_H1T);
  float* stat = (float*)(ws + OFF_STAT);
  float* nsq = (float*)(ws + OFF_NSQ);
  float* big0 = (float*)(ws + OFF_BIG);
  float* big1 = (float*)(ws + OFF_BIG + 4u * 1024u * 1024u);
  float* ndb = (float*)(ws + OFF_BIG);

  hipMemsetAsync(stat, 0, 8192, stream);
  hipLaunchKernelGGL(k_topk1, dim3(4096), dim3(256), 0, stream, x, idx1);
  hipLaunchKernelGGL(k_featstats, dim3(64), dim3(256), 0, stream, x, idx1, stat);
  hipLaunchKernelGGL(k_bnprep1, dim3(1), dim3(128), 0, stream, stat, w1, g1, b1, stat + SC1, stat + SH1);
  hipLaunchKernelGGL(k_conv12m, dim3(4096), dim3(256), 0, stream, x, idx1, w1, w2,
                     stat + SC1, stat + SH1, big0, big1, stat + S2o, stat + SS2o);
  hipLaunchKernelGGL(k_bnprep, dim3(1), dim3(128), 0, stream, stat + S2o, stat + SS2o, g2, b2,
                     stat + SC2, stat + SH2, 64);
  hipLaunchKernelGGL(k_finbn, dim3(128), dim3(256), 0, stream, big0, big1,
                     stat + SC2, stat + SH2, out, 0, h1t, nsq);
  hipLaunchKernelGGL(k_dist, dim3(2048), dim3(256), 0, stream, h1t, nsq, ndb);
  hipLaunchKernelGGL(k_sel, dim3(2048), dim3(512), 0, stream, ndb, idx2);
  hipLaunchKernelGGL(k_conv3m, dim3(4096), dim3(256), 0, stream, h1t, idx2, w3, stat + S3o, stat + SS3o);
  hipLaunchKernelGGL(k_bnprep, dim3(1), dim3(128), 0, stream, stat + S3o, stat + SS3o, g3, b3,
                     stat + SC3, stat + SH3, 128);
  hipLaunchKernelGGL(k_conv4m, dim3(4096), dim3(256), 0, stream, h1t, idx2, w3, w4,
                     stat + SC3, stat + SH3, big0, big1, stat + S4o, stat + SS4o);
  hipLaunchKernelGGL(k_bnprep, dim3(1), dim3(128), 0, stream, stat + S4o, stat + SS4o, g4, b4,
                     stat + SC4, stat + SH4, 64);
  hipLaunchKernelGGL(k_finbn, dim3(128), dim3(256), 0, stream, big0, big1,
                     stat + SC4, stat + SH4, out, 64, (float*)nullptr, (float*)nullptr);
  (void)in_sizes; (void)n_in; (void)out_size; (void)ws_size;
}

// Round 8
// 719.411 us; speedup vs baseline: 11.0606x; 1.3004x over previous
//
#include <hip/hip_runtime.h>

#define DI __device__ __forceinline__

typedef _Float16 f16x2 __attribute__((ext_vector_type(2)));
typedef _Float16 f16x8 __attribute__((ext_vector_type(8)));
typedef float f32x4 __attribute__((ext_vector_type(4)));

#define NPTS 2048
#define KNBR 32
#define SALL 524288.0f
#define EPSV 1e-5f
#define SLOPEV 0.2f

// ---------------- workspace layout (bytes), total 144 MiB ----------------
#define OFF_IDX1 0u
#define OFF_IDX2 (2u*1024u*1024u)
#define OFF_H1T  (4u*1024u*1024u)
#define OFF_STAT (8u*1024u*1024u)
#define OFF_PF   (8u*1024u*1024u + 16384u)
#define OFF_NSQ  (9u*1024u*1024u)
#define OFF_PS2  (10u*1024u*1024u)
#define OFF_PSS2 (11u*1024u*1024u)
#define OFF_BIG  (16u*1024u*1024u)
// stat float offsets
#define SC1 32
#define SH1 160
#define SC2 416
#define SH2 480
#define S3o 544
#define SS3o 672
#define SC3 800
#define SH3 928
#define S4o 1056
#define SS4o 1120
#define SC4 1184
#define SH4 1248

union U4 { uint4 u; float f[4]; };
union UH8 { uint4 u; f16x8 h; };

DI float lrelu(float z) { return z > 0.f ? z : SLOPEV * z; }

DI unsigned ordf(float f) {
  unsigned u = __float_as_uint(f);
  return ((int)u < 0) ? ~u : (u | 0x80000000u);
}

// Exact top-32 SET of 2048 values nd[s] per lane (value j = s*64+lane).
// Deterministic given input; boundary ties go to lowest j (jax tie rule).
DI void select_top32(const float (&nd)[32], int lane, int* __restrict__ outp) {
  unsigned uo[32];
  #pragma unroll
  for (int s = 0; s < 32; ++s) uo[s] = ordf(nd[s]);
  unsigned T = 0u;
  #pragma nounroll
  for (int bit = 31; bit >= 0; --bit) {
    unsigned cand = T | (1u << bit);
    int cnt = 0;
    #pragma unroll
    for (int s = 0; s < 32; ++s) cnt += __popcll(__ballot(uo[s] >= cand));
    if (cnt >= 32) T = cand;
  }
  const unsigned long long lml = (1ull << lane) - 1ull;
  int base = 0;
  #pragma nounroll
  for (int s = 0; s < 32; ++s) {  // all strictly-greater values (count <= 31)
    unsigned long long m = __ballot(uo[s] > T);
    if ((m >> lane) & 1ull) outp[base + __popcll(m & lml)] = s * 64 + lane;
    base += __popcll(m);
  }
  #pragma nounroll
  for (int s = 0; s < 32 && base < 32; ++s) {  // fill from ties, lowest j first
    unsigned long long m = __ballot(uo[s] == T);
    int r = __popcll(m & lml);
    if (((m >> lane) & 1ull) && (base + r) < 32) outp[base + r] = s * 64 + lane;
    base += __popcll(m);
  }
}

// ---------------- K1: stage-1 top-k (C=3) ----------------
__global__ __launch_bounds__(256) void k_topk1(const float* __restrict__ x, int* __restrict__ idx1) {
  __shared__ float xl[NPTS * 3];
  __shared__ float sq[NPTS];
  const int t = threadIdx.x;
  const int blk4 = blockIdx.x * 4;
  const int b = blk4 >> 11;
  const float* __restrict__ xb = x + (size_t)b * 3 * NPTS;
  for (int e = t; e < 3 * NPTS; e += 256) {
    int c = e >> 11, n = e & (NPTS - 1);
    xl[n * 3 + c] = xb[e];
  }
  __syncthreads();
  for (int n = t; n < NPTS; n += 256) {
    float a0 = xl[n * 3], a1 = xl[n * 3 + 1], a2 = xl[n * 3 + 2];
    sq[n] = a0 * a0 + a1 * a1 + a2 * a2;
  }
  __syncthreads();
  const int lane = t & 63, w = t >> 6;
  const int row = blk4 + w;
  const int i = row & (NPTS - 1);
  const float xi0 = xl[i * 3], xi1 = xl[i * 3 + 1], xi2 = xl[i * 3 + 2];
  const float si = sq[i];
  float nd[32];
  #pragma unroll
  for (int s = 0; s < 32; ++s) {
    int j = s * 64 + lane;
    float d = xi0 * xl[j * 3] + xi1 * xl[j * 3 + 1] + xi2 * xl[j * 3 + 2];
    nd[s] = (2.0f * d - si) - sq[j];
  }
  select_top32(nd, lane, idx1 + (size_t)row * KNBR);
}

// ---------------- K2: feat1 moments -> per-block partials (deterministic) ----------------
__global__ __launch_bounds__(256) void k_featstats(const float* __restrict__ x,
                                                   const int* __restrict__ idx1,
                                                   float* __restrict__ partF) {
  __shared__ float wred[4][27];
  const int t = threadIdx.x;
  const int row = blockIdx.x * 256 + t;
  const int b = row >> 11, i = row & (NPTS - 1);
  const float* __restrict__ xb = x + (size_t)b * 3 * NPTS;
  const float xi0 = xb[i], xi1 = xb[NPTS + i], xi2 = xb[2 * NPTS + i];
  float sd0 = 0, sd1 = 0, sd2 = 0, q00 = 0, q01 = 0, q02 = 0, q11 = 0, q12 = 0, q22 = 0;
  for (int k = 0; k < KNBR; ++k) {
    int j = idx1[(size_t)row * KNBR + k];
    float d0 = xb[j] - xi0, d1 = xb[NPTS + j] - xi1, d2 = xb[2 * NPTS + j] - xi2;
    sd0 += d0; sd1 += d1; sd2 += d2;
    q00 += d0 * d0; q01 += d0 * d1; q02 += d0 * d2;
    q11 += d1 * d1; q12 += d1 * d2; q22 += d2 * d2;
  }
  float v[27];
  v[0] = sd0; v[1] = sd1; v[2] = sd2; v[3] = 32.f * xi0; v[4] = 32.f * xi1; v[5] = 32.f * xi2;
  v[6] = q00; v[7] = q01; v[8] = q02; v[9] = sd0 * xi0; v[10] = sd0 * xi1; v[11] = sd0 * xi2;
  v[12] = q11; v[13] = q12; v[14] = sd1 * xi0; v[15] = sd1 * xi1; v[16] = sd1 * xi2;
  v[17] = q22; v[18] = sd2 * xi0; v[19] = sd2 * xi1; v[20] = sd2 * xi2;
  v[21] = 32.f * xi0 * xi0; v[22] = 32.f * xi0 * xi1; v[23] = 32.f * xi0 * xi2;
  v[24] = 32.f * xi1 * xi1; v[25] = 32.f * xi1 * xi2; v[26] = 32.f * xi2 * xi2;
  #pragma unroll
  for (int qq = 0; qq < 27; ++qq) {
    float s = v[qq];
    #pragma unroll
    for (int d = 1; d < 64; d <<= 1) s += __shfl_xor(s, d);
    if ((t & 63) == 0) wred[t >> 6][qq] = s;
  }
  __syncthreads();
  if (t < 27)
    partF[blockIdx.x * 27 + t] = (wred[0][t] + wred[1][t]) + (wred[2][t] + wred[3][t]);
}

// ---------------- K3: BN1 params (deterministic reduce of 64 partials) ----------------
__global__ void k_bnprep1(const float* __restrict__ partF, const float* __restrict__ w1,
                          const float* __restrict__ g1, const float* __restrict__ b1,
                          float* __restrict__ sc1, float* __restrict__ sh1) {
  __shared__ float F[27], M[36], mu[6];
  const int t = threadIdx.x;
  const float inv = 1.0f / SALL;
  if (t < 27) {
    float s = 0.f;
    for (int b = 0; b < 64; ++b) s += partF[b * 27 + t];
    F[t] = s;
  }
  __syncthreads();
  if (t < 6) mu[t] = F[t] * inv;
  if (t < 36) {
    int a = t / 6, bq = t % 6;
    int aa = a < bq ? a : bq, bb = a < bq ? bq : a;
    int pos = aa * 6 - aa * (aa + 1) / 2 + bb;
    M[t] = F[6 + pos] * inv;
  }
  __syncthreads();
  if (t < 128) {
    const float* w = w1 + t * 6;
    float m = 0.f;
    for (int c = 0; c < 6; ++c) m += w[c] * mu[c];
    float e2 = 0.f;
    for (int a = 0; a < 6; ++a)
      for (int c = 0; c < 6; ++c) e2 += w[a] * w[c] * M[a * 6 + c];
    float var = e2 - m * m;
    float rstd = rsqrtf(var + EPSV);
    float s = g1[t] * rstd;
    sc1[t] = s;
    sh1[t] = b1[t] - m * s;
  }
}

// ---------------- BN2 prep: deterministic reduce of 4096 block partials ----------------
__global__ __launch_bounds__(256) void k_bnprep2(
    const float* __restrict__ pS, const float* __restrict__ pSS,
    const float* __restrict__ g, const float* __restrict__ bb,
    float* __restrict__ sc, float* __restrict__ sh) {
  __shared__ float wsA[4], wsB[4];
  const int c = blockIdx.x;  // channel
  const int t = threadIdx.x;
  float s = 0.f, ss = 0.f;
  #pragma nounroll
  for (int i = 0; i < 16; ++i) {
    int blk = t * 16 + i;
    s += pS[(size_t)blk * 64 + c];
    ss += pSS[(size_t)blk * 64 + c];
  }
  #pragma unroll
  for (int d = 1; d < 64; d <<= 1) { s += __shfl_xor(s, d); ss += __shfl_xor(ss, d); }
  if ((t & 63) == 0) { wsA[t >> 6] = s; wsB[t >> 6] = ss; }
  __syncthreads();
  if (t == 0) {
    float S = (wsA[0] + wsA[1]) + (wsA[2] + wsA[3]);
    float SS = (wsB[0] + wsB[1]) + (wsB[2] + wsB[3]);
    const float inv = 1.0f / SALL;
    float m = S * inv;
    float var = SS * inv - m * m;
    float rstd = rsqrtf(var + EPSV);
    float scale = g[c] * rstd;
    sc[c] = scale;
    sh[c] = bb[c] - m * scale;
  }
}

// ---------------- generic BN prep (atomic-based, BN3/BN4 only) ----------------
__global__ void k_bnprep(const float* __restrict__ s, const float* __restrict__ ss,
                         const float* __restrict__ g, const float* __restrict__ bb,
                         float* __restrict__ sc, float* __restrict__ sh, int nch) {
  const int t = threadIdx.x;
  if (t < nch) {
    const float inv = 1.0f / SALL;
    float m = s[t] * inv;
    float var = ss[t] * inv - m * m;
    float rstd = rsqrtf(var + EPSV);
    float scale = g[t] * rstd;
    sc[t] = scale;
    sh[t] = bb[t] - m * scale;
  }
}

// ---------------- K4: gather + conv1(fp32) + BN1 + lrelu + conv2(split-f16 MFMA) ----------------
__global__ __launch_bounds__(256) void k_conv12m(
    const float* __restrict__ x, const int* __restrict__ idx1,
    const float* __restrict__ w1, const float* __restrict__ w2,
    const float* __restrict__ sc1g, const float* __restrict__ sh1g,
    float* __restrict__ h1max, float* __restrict__ h1min,
    float* __restrict__ pS2, float* __restrict__ pSS2) {
  __shared__ __align__(16) _Float16 z1h[128 * 136];
  __shared__ __align__(16) _Float16 z1lo[128 * 136];
  __shared__ float featl[6][128];
  __shared__ float w1l[768];
  const int t = threadIdx.x;
  const int blk = blockIdx.x;
  const int row0 = blk * 4;
  const int b = row0 >> 11;
  const float* __restrict__ xb = x + (size_t)b * 3 * NPTS;
  for (int e = t; e < 768; e += 256) w1l[e] = w1[e];
  if (t < 128) {
    int r = t >> 5;
    int n = (row0 & (NPTS - 1)) + r;
    int j = idx1[(size_t)(row0 + r) * KNBR + (t & 31)];
    float c0 = xb[n], c1 = xb[NPTS + n], c2 = xb[2 * NPTS + n];
    featl[0][t] = xb[j] - c0;
    featl[1][t] = xb[NPTS + j] - c1;
    featl[2][t] = xb[2 * NPTS + j] - c2;
    featl[3][t] = c0; featl[4][t] = c1; featl[5][t] = c2;
  }
  __syncthreads();
  {
    const int s = t >> 1, hh = t & 1;
    float f0 = featl[0][s], f1 = featl[1][s], f2 = featl[2][s];
    float f3 = featl[3][s], f4 = featl[4][s], f5 = featl[5][s];
    #pragma unroll
    for (int chunk = 0; chunk < 8; ++chunk) {
      UH8 hi8, lo8;
      #pragma unroll
      for (int i = 0; i < 8; ++i) {
        int c = hh * 64 + chunk * 8 + i;
        const float* wr = &w1l[c * 6];
        float y = wr[0] * f0 + wr[1] * f1 + wr[2] * f2 + wr[3] * f3 + wr[4] * f4 + wr[5] * f5;
        float z = y * sc1g[c] + sh1g[c];
        z = z > 0.f ? z : SLOPEV * z;
        _Float16 h = (_Float16)z;
        hi8.h[i] = h;
        lo8.h[i] = (_Float16)(z - (float)h);
      }
      *reinterpret_cast<uint4*>(&z1h[s * 136 + hh * 64 + chunk * 8]) = hi8.u;
      *reinterpret_cast<uint4*>(&z1lo[s * 136 + hh * 64 + chunk * 8]) = lo8.u;
    }
  }
  const int lane = t & 63, w = t >> 6;
  const int c15 = lane & 15, g = lane >> 4;
  const int o4 = 16 * w + c15;
  f16x8 Bh[4], Bl[4];
  #pragma unroll
  for (int ks = 0; ks < 4; ++ks) {
    const float* wr = w2 + o4 * 128 + ks * 32 + g * 8;
    #pragma unroll
    for (int i = 0; i < 8; ++i) {
      float v = wr[i];
      _Float16 h = (_Float16)v;
      Bh[ks][i] = h;
      Bl[ks][i] = (_Float16)(v - (float)h);
    }
  }
  __syncthreads();
  f32x4 acc[8] = {};
  #pragma unroll
  for (int mt = 0; mt < 8; ++mt) {
    #pragma unroll
    for (int ks = 0; ks < 4; ++ks) {
      UH8 ah, al;
      ah.u = *reinterpret_cast<const uint4*>(&z1h[(16 * mt + c15) * 136 + ks * 32 + g * 8]);
      al.u = *reinterpret_cast<const uint4*>(&z1lo[(16 * mt + c15) * 136 + ks * 32 + g * 8]);
      acc[mt] = __builtin_amdgcn_mfma_f32_16x16x32_f16(ah.h, Bh[ks], acc[mt], 0, 0, 0);
      acc[mt] = __builtin_amdgcn_mfma_f32_16x16x32_f16(al.h, Bh[ks], acc[mt], 0, 0, 0);
      acc[mt] = __builtin_amdgcn_mfma_f32_16x16x32_f16(ah.h, Bl[ks], acc[mt], 0, 0, 0);
    }
  }
  float s = 0.f, ss = 0.f;
  float mx[4], mn[4];
  #pragma unroll
  for (int rp = 0; rp < 4; ++rp) { mx[rp] = -3.0e38f; mn[rp] = 3.0e38f; }
  #pragma unroll
  for (int mt = 0; mt < 8; ++mt) {
    const int rp = mt >> 1;
    #pragma unroll
    for (int r = 0; r < 4; ++r) {
      float v = acc[mt][r];
      s += v; ss += v * v;
      mx[rp] = fmaxf(mx[rp], v); mn[rp] = fminf(mn[rp], v);
    }
  }
  s += __shfl_xor(s, 16); ss += __shfl_xor(ss, 16);
  s += __shfl_xor(s, 32); ss += __shfl_xor(ss, 32);
  #pragma unroll
  for (int rp = 0; rp < 4; ++rp) {
    mx[rp] = fmaxf(mx[rp], __shfl_xor(mx[rp], 16));
    mx[rp] = fmaxf(mx[rp], __shfl_xor(mx[rp], 32));
    mn[rp] = fminf(mn[rp], __shfl_xor(mn[rp], 16));
    mn[rp] = fminf(mn[rp], __shfl_xor(mn[rp], 32));
  }
  if (lane < 16) {
    #pragma unroll
    for (int rp = 0; rp < 4; ++rp) {
      h1max[(size_t)(row0 + rp) * 64 + o4] = mx[rp];
      h1min[(size_t)(row0 + rp) * 64 + o4] = mn[rp];
    }
    pS2[(size_t)blk * 64 + o4] = s;    // deterministic block partials
    pSS2[(size_t)blk * 64 + o4] = ss;
  }
}

// ---------------- K5: BN + lrelu epilogue from (max,min); writes out (+h1t,+nsq) ----------------
__global__ __launch_bounds__(256) void k_finbn(
    const float* __restrict__ hmax, const float* __restrict__ hmin,
    const float* __restrict__ scg, const float* __restrict__ shg,
    float* __restrict__ out, const int choff,
    float* __restrict__ h1t, float* __restrict__ nsq) {
  __shared__ float ht[128][65];
  const int t = threadIdx.x;
  const int blk = blockIdx.x;          // 128 blocks x 128 rows
  const int row0 = blk * 128;
  const int b = row0 >> 11, n0 = row0 & (NPTS - 1);
  const int c = t & 63;
  const float sc = scg[c], sh = shg[c];
  const int rbase = t >> 6;
  for (int it = 0; it < 32; ++it) {
    int rl = it * 4 + rbase;
    size_t gi = (size_t)(row0 + rl) * 64 + c;
    float y = sc > 0.f ? hmax[gi] : hmin[gi];
    float h = lrelu(sc * y + sh);
    if (h1t) h1t[gi] = h;
    ht[rl][c] = h;
  }
  __syncthreads();
  if (nsq && t < 128) {
    float s = 0.f;
    #pragma unroll
    for (int c2 = 0; c2 < 64; ++c2) { float v = ht[t][c2]; s += v * v; }
    nsq[row0 + t] = s;
  }
  const int co = t >> 2, i0 = (t & 3) * 32;
  float* __restrict__ op = out + ((size_t)b * 128 + choff + co) * NPTS + n0 + i0;
  for (int i = 0; i < 32; i += 4) {
    float4 v;
    v.x = ht[i0 + i][co]; v.y = ht[i0 + i + 1][co];
    v.z = ht[i0 + i + 2][co]; v.w = ht[i0 + i + 3][co];
    *reinterpret_cast<float4*>(op + i) = v;
  }
}

// ---------------- K7b: ND = 2*H*H^T - n_i - n_j ----------------
#define BCOL(c) ((c) + (((c) >> 5) << 2))
__global__ __launch_bounds__(256) void k_dist(const float* __restrict__ h1t,
                                              const float* __restrict__ nsq,
                                              float* __restrict__ ndb) {
  __shared__ __align__(16) float Al[32][132];
  __shared__ __align__(16) float Bl[32][140];
  const int t = threadIdx.x;
  const int bt = blockIdx.x >> 8, rem = blockIdx.x & 255;
  const int ti = rem >> 4, tj = rem & 15;
  const float* __restrict__ hb = h1t + (size_t)bt * NPTS * 64;
  const int r0 = ti * 128, c0 = tj * 128;
  const int tx = t & 15, ty = t >> 4;
  float acc[8][8] = {};
  for (int kk = 0; kk < 64; kk += 32) {
    __syncthreads();
    for (int e = t; e < 1024; e += 256) {
      int r = e >> 3, c4 = e & 7;
      float4 va = *reinterpret_cast<const float4*>(hb + (size_t)(r0 + r) * 64 + kk + c4 * 4);
      int cb = c4 * 4;
      Al[cb][r] = va.x; Al[cb + 1][r] = va.y; Al[cb + 2][r] = va.z; Al[cb + 3][r] = va.w;
      float4 vb = *reinterpret_cast<const float4*>(hb + (size_t)(c0 + r) * 64 + kk + c4 * 4);
      int rp = BCOL(r);
      Bl[cb][rp] = vb.x; Bl[cb + 1][rp] = vb.y; Bl[cb + 2][rp] = vb.z; Bl[cb + 3][rp] = vb.w;
    }
    __syncthreads();
    #pragma unroll 8
    for (int k = 0; k < 32; ++k) {
      U4 a0; a0.u = *reinterpret_cast<const uint4*>(&Al[k][ty * 8]);
      U4 a1; a1.u = *reinterpret_cast<const uint4*>(&Al[k][ty * 8 + 4]);
      U4 b0; b0.u = *reinterpret_cast<const uint4*>(&Bl[k][BCOL(tx * 8)]);
      U4 b1; b1.u = *reinterpret_cast<const uint4*>(&Bl[k][BCOL(tx * 8) + 4]);
      #pragma unroll
      for (int rr = 0; rr < 4; ++rr) {
        #pragma unroll
        for (int cc = 0; cc < 4; ++cc) {
          acc[rr][cc] += a0.f[rr] * b0.f[cc];
          acc[rr][cc + 4] += a0.f[rr] * b1.f[cc];
          acc[rr + 4][cc] += a1.f[rr] * b0.f[cc];
          acc[rr + 4][cc + 4] += a1.f[rr] * b1.f[cc];
        }
      }
    }
  }
  float nr[8], nc[8];
  const float* __restrict__ nb2 = nsq + (size_t)bt * NPTS;
  #pragma unroll
  for (int i = 0; i < 8; ++i) {
    nr[i] = nb2[r0 + ty * 8 + i];
    nc[i] = nb2[c0 + tx * 8 + i];
  }
  float* __restrict__ op = ndb + ((size_t)bt * NPTS + r0 + ty * 8) * NPTS + c0 + tx * 8;
  #pragma unroll
  for (int rr = 0; rr < 8; ++rr) {
    float4 o0, o1;
    o0.x = 2.f * acc[rr][0] - nr[rr] - nc[0];
    o0.y = 2.f * acc[rr][1] - nr[rr] - nc[1];
    o0.z = 2.f * acc[rr][2] - nr[rr] - nc[2];
    o0.w = 2.f * acc[rr][3] - nr[rr] - nc[3];
    o1.x = 2.f * acc[rr][4] - nr[rr] - nc[4];
    o1.y = 2.f * acc[rr][5] - nr[rr] - nc[5];
    o1.z = 2.f * acc[rr][6] - nr[rr] - nc[6];
    o1.w = 2.f * acc[rr][7] - nr[rr] - nc[7];
    *reinterpret_cast<float4*>(op + (size_t)rr * NPTS) = o0;
    *reinterpret_cast<float4*>(op + (size_t)rr * NPTS + 4) = o1;
  }
}

// ---------------- K7c: streaming top-32 selection ----------------
__global__ __launch_bounds__(512) void k_sel(const float* __restrict__ ndb,
                                             int* __restrict__ idx2) {
  const int t = threadIdx.x, lane = t & 63, w = t >> 6;
  const int row = blockIdx.x * 8 + w;
  const float* __restrict__ nr = ndb + (size_t)row * NPTS;
  float nd[32];
  #pragma unroll
  for (int s = 0; s < 32; ++s) nd[s] = nr[s * 64 + lane];
  select_top32(nd, lane, idx2 + (size_t)row * KNBR);
}

// ======== shared gather helper for conv3/conv4 (MFMA feature tile) ========
DI void gather_f2(const float* __restrict__ hb, const int* __restrict__ idx2,
                  int row0, int t, const float ctr[4][64], _Float16* __restrict__ f2z) {
  const int s = t >> 1, hh = t & 1;
  const int r = s >> 5, k = s & 31;
  const int j = idx2[(size_t)(row0 + r) * KNBR + k];
  const float* __restrict__ nv = hb + (size_t)j * 64 + hh * 32;
  const float* cv = &ctr[r][hh * 32];
  _Float16* fp = f2z + s * 136 + 32 * hh;
  _Float16* cp = fp + 64;
  #pragma unroll
  for (int i = 0; i < 32; i += 8) {
    float4 v0 = *reinterpret_cast<const float4*>(nv + i);
    float4 v1 = *reinterpret_cast<const float4*>(nv + i + 4);
    UH8 dd, cc;
    dd.h[0] = (_Float16)(v0.x - cv[i + 0]); dd.h[1] = (_Float16)(v0.y - cv[i + 1]);
    dd.h[2] = (_Float16)(v0.z - cv[i + 2]); dd.h[3] = (_Float16)(v0.w - cv[i + 3]);
    dd.h[4] = (_Float16)(v1.x - cv[i + 4]); dd.h[5] = (_Float16)(v1.y - cv[i + 5]);
    dd.h[6] = (_Float16)(v1.z - cv[i + 6]); dd.h[7] = (_Float16)(v1.w - cv[i + 7]);
    cc.h[0] = (_Float16)cv[i + 0]; cc.h[1] = (_Float16)cv[i + 1];
    cc.h[2] = (_Float16)cv[i + 2]; cc.h[3] = (_Float16)cv[i + 3];
    cc.h[4] = (_Float16)cv[i + 4]; cc.h[5] = (_Float16)cv[i + 5];
    cc.h[6] = (_Float16)cv[i + 6]; cc.h[7] = (_Float16)cv[i + 7];
    *reinterpret_cast<uint4*>(fp + i) = dd.u;
    *reinterpret_cast<uint4*>(cp + i) = cc.u;
  }
}

DI f16x8 packw8(const float* __restrict__ wr) {
  float4 a = *reinterpret_cast<const float4*>(wr);
  float4 bq = *reinterpret_cast<const float4*>(wr + 4);
  f16x8 f;
  f[0] = (_Float16)a.x; f[1] = (_Float16)a.y; f[2] = (_Float16)a.z; f[3] = (_Float16)a.w;
  f[4] = (_Float16)bq.x; f[5] = (_Float16)bq.y; f[6] = (_Float16)bq.z; f[7] = (_Float16)bq.w;
  return f;
}

// ---------------- K8a: conv3 stats pass (MFMA f16) ----------------
__global__ __launch_bounds__(256) void k_conv3m(
    const float* __restrict__ h1t, const int* __restrict__ idx2,
    const float* __restrict__ w3, float* __restrict__ gS3, float* __restrict__ gSS3) {
  __shared__ __align__(16) _Float16 f2z[128 * 136];
  __shared__ float ctr[4][64];
  const int t = threadIdx.x;
  const int blk = blockIdx.x;
  const int row0 = blk * 4;
  const int b = row0 >> 11;
  const float* __restrict__ hb = h1t + (size_t)b * NPTS * 64;
  ctr[t >> 6][t & 63] = hb[(size_t)((row0 & (NPTS - 1)) + (t >> 6)) * 64 + (t & 63)];
  __syncthreads();
  gather_f2(hb, idx2, row0, t, ctr, f2z);
  const int lane = t & 63, w = t >> 6;
  const int c15 = lane & 15, g = lane >> 4;
  f16x8 Bf[2][4];
  #pragma unroll
  for (int nt = 0; nt < 2; ++nt) {
    const float* wr = w3 + (32 * w + 16 * nt + c15) * 128 + 8 * g;
    #pragma unroll
    for (int ks = 0; ks < 4; ++ks) Bf[nt][ks] = packw8(wr + ks * 32);
  }
  __syncthreads();
  f32x4 acc[8][2] = {};
  #pragma unroll
  for (int mt = 0; mt < 8; ++mt) {
    #pragma unroll
    for (int ks = 0; ks < 4; ++ks) {
      UH8 av;
      av.u = *reinterpret_cast<const uint4*>(&f2z[(16 * mt + c15) * 136 + ks * 32 + g * 8]);
      acc[mt][0] = __builtin_amdgcn_mfma_f32_16x16x32_f16(av.h, Bf[0][ks], acc[mt][0], 0, 0, 0);
      acc[mt][1] = __builtin_amdgcn_mfma_f32_16x16x32_f16(av.h, Bf[1][ks], acc[mt][1], 0, 0, 0);
    }
  }
  #pragma unroll
  for (int nt = 0; nt < 2; ++nt) {
    float s = 0.f, ss = 0.f;
    #pragma unroll
    for (int mt = 0; mt < 8; ++mt)
      #pragma unroll
      for (int r = 0; r < 4; ++r) { float v = acc[mt][nt][r]; s += v; ss += v * v; }
    s += __shfl_xor(s, 16); ss += __shfl_xor(ss, 16);
    s += __shfl_xor(s, 32); ss += __shfl_xor(ss, 32);
    if (lane < 16) {
      atomicAdd(&gS3[32 * w + 16 * nt + c15], s);
      atomicAdd(&gSS3[32 * w + 16 * nt + c15], ss);
    }
  }
}

// ---------------- K8b: conv3(recompute)+BN3+lrelu -> conv4 + stats4 + k-max/min (MFMA) ----------------
__global__ __launch_bounds__(256) void k_conv4m(
    const float* __restrict__ h1t, const int* __restrict__ idx2,
    const float* __restrict__ w3, const float* __restrict__ w4,
    const float* __restrict__ sc3g, const float* __restrict__ sh3g,
    float* __restrict__ h2max, float* __restrict__ h2min,
    float* __restrict__ gS4, float* __restrict__ gSS4) {
  __shared__ __align__(16) _Float16 f2z[128 * 136];   // feat2, then reused as z3
  __shared__ float ctr[4][64];
  const int t = threadIdx.x;
  const int blk = blockIdx.x;
  const int row0 = blk * 4;
  const int b = row0 >> 11;
  const float* __restrict__ hb = h1t + (size_t)b * NPTS * 64;
  ctr[t >> 6][t & 63] = hb[(size_t)((row0 & (NPTS - 1)) + (t >> 6)) * 64 + (t & 63)];
  __syncthreads();
  gather_f2(hb, idx2, row0, t, ctr, f2z);
  const int lane = t & 63, w = t >> 6;
  const int c15 = lane & 15, g = lane >> 4;
  f16x8 Bf[2][4];
  float sc3v[2], sh3v[2];
  #pragma unroll
  for (int nt = 0; nt < 2; ++nt) {
    const int ch = 32 * w + 16 * nt + c15;
    const float* wr = w3 + ch * 128 + 8 * g;
    #pragma unroll
    for (int ks = 0; ks < 4; ++ks) Bf[nt][ks] = packw8(wr + ks * 32);
    sc3v[nt] = sc3g[ch]; sh3v[nt] = sh3g[ch];
  }
  f16x8 B4[4];
  const int o4 = 16 * w + c15;
  {
    const float* wr = w4 + o4 * 128 + 8 * g;
    #pragma unroll
    for (int ks = 0; ks < 4; ++ks) B4[ks] = packw8(wr + ks * 32);
  }
  __syncthreads();
  f32x4 acc[8][2] = {};
  #pragma unroll
  for (int mt = 0; mt < 8; ++mt) {
    #pragma unroll
    for (int ks = 0; ks < 4; ++ks) {
      UH8 av;
      av.u = *reinterpret_cast<const uint4*>(&f2z[(16 * mt + c15) * 136 + ks * 32 + g * 8]);
      acc[mt][0] = __builtin_amdgcn_mfma_f32_16x16x32_f16(av.h, Bf[0][ks], acc[mt][0], 0, 0, 0);
      acc[mt][1] = __builtin_amdgcn_mfma_f32_16x16x32_f16(av.h, Bf[1][ks], acc[mt][1], 0, 0, 0);
    }
  }
  __syncthreads();  // all waves done reading f2z
  #pragma unroll
  for (int mt = 0; mt < 8; ++mt)
    #pragma unroll
    for (int nt = 0; nt < 2; ++nt)
      #pragma unroll
      for (int r = 0; r < 4; ++r) {
        float z = acc[mt][nt][r] * sc3v[nt] + sh3v[nt];
        z = z > 0.f ? z : SLOPEV * z;
        f2z[(16 * mt + 4 * g + r) * 136 + 32 * w + 16 * nt + c15] = (_Float16)z;
      }
  __syncthreads();
  f32x4 a4[8] = {};
  #pragma unroll
  for (int mt = 0; mt < 8; ++mt) {
    #pragma unroll
    for (int ks = 0; ks < 4; ++ks) {
      UH8 av;
      av.u = *reinterpret_cast<const uint4*>(&f2z[(16 * mt + c15) * 136 + ks * 32 + g * 8]);
      a4[mt] = __builtin_amdgcn_mfma_f32_16x16x32_f16(av.h, B4[ks], a4[mt], 0, 0, 0);
    }
  }
  float s = 0.f, ss = 0.f;
  float mx[4], mn[4];
  #pragma unroll
  for (int rp = 0; rp < 4; ++rp) { mx[rp] = -3.0e38f; mn[rp] = 3.0e38f; }
  #pragma unroll
  for (int mt = 0; mt < 8; ++mt) {
    const int rp = mt >> 1;
    #pragma unroll
    for (int r = 0; r < 4; ++r) {
      float v = a4[mt][r];
      s += v; ss += v * v;
      mx[rp] = fmaxf(mx[rp], v); mn[rp] = fminf(mn[rp], v);
    }
  }
  s += __shfl_xor(s, 16); ss += __shfl_xor(ss, 16);
  s += __shfl_xor(s, 32); ss += __shfl_xor(ss, 32);
  #pragma unroll
  for (int rp = 0; rp < 4; ++rp) {
    mx[rp] = fmaxf(mx[rp], __shfl_xor(mx[rp], 16));
    mx[rp] = fmaxf(mx[rp], __shfl_xor(mx[rp], 32));
    mn[rp] = fminf(mn[rp], __shfl_xor(mn[rp], 16));
    mn[rp] = fminf(mn[rp], __shfl_xor(mn[rp], 32));
  }
  if (lane < 16) {
    #pragma unroll
    for (int rp = 0; rp < 4; ++rp) {
      h2max[(size_t)(row0 + rp) * 64 + o4] = mx[rp];
      h2min[(size_t)(row0 + rp) * 64 + o4] = mn[rp];
    }
    atomicAdd(&gS4[o4], s);
    atomicAdd(&gSS4[o4], ss);
  }
}

// ---------------- host launcher ----------------
extern "C" void kernel_launch(void* const* d_in, const int* in_sizes, int n_in,
                              void* d_out, int out_size, void* d_ws, size_t ws_size,
                              hipStream_t stream) {
  const float* x = (const float*)d_in[0];
  const float* w1 = (const float*)d_in[1];
  const float* g1 = (const float*)d_in[2];
  const float* b1 = (const float*)d_in[3];
  const float* w2 = (const float*)d_in[4];
  const float* g2 = (const float*)d_in[5];
  const float* b2 = (const float*)d_in[6];
  const float* w3 = (const float*)d_in[7];
  const float* g3 = (const float*)d_in[8];
  const float* b3 = (const float*)d_in[9];
  const float* w4 = (const float*)d_in[10];
  const float* g4 = (const float*)d_in[11];
  const float* b4 = (const float*)d_in[12];
  float* out = (float*)d_out;
  char* ws = (char*)d_ws;
  int* idx1 = (int*)(ws + OFF_IDX1);
  int* idx2 = (int*)(ws + OFF_IDX2);
  float* h1t = (float*)(ws + OFF_H1T);
  float* stat = (float*)(ws + OFF_STAT);
  float* partF = (float*)(ws + OFF_PF);
  float* nsq = (float*)(ws + OFF_NSQ);
  float* pS2 = (float*)(ws + OFF_PS2);
  float* pSS2 = (float*)(ws + OFF_PSS2);
  float* big0 = (float*)(ws + OFF_BIG);
  float* big1 = (float*)(ws + OFF_BIG + 4u * 1024u * 1024u);
  float* ndb = (float*)(ws + OFF_BIG);

  hipMemsetAsync(stat, 0, 8192, stream);  // zero BN3/BN4 atomic accumulators
  hipLaunchKernelGGL(k_topk1, dim3(4096), dim3(256), 0, stream, x, idx1);
  hipLaunchKernelGGL(k_featstats, dim3(64), dim3(256), 0, stream, x, idx1, partF);
  hipLaunchKernelGGL(k_bnprep1, dim3(1), dim3(128), 0, stream, partF, w1, g1, b1, stat + SC1, stat + SH1);
  hipLaunchKernelGGL(k_conv12m, dim3(4096), dim3(256), 0, stream, x, idx1, w1, w2,
                     stat + SC1, stat + SH1, big0, big1, pS2, pSS2);
  hipLaunchKernelGGL(k_bnprep2, dim3(64), dim3(256), 0, stream, pS2, pSS2, g2, b2,
                     stat + SC2, stat + SH2);
  hipLaunchKernelGGL(k_finbn, dim3(128), dim3(256), 0, stream, big0, big1,
                     stat + SC2, stat + SH2, out, 0, h1t, nsq);
  hipLaunchKernelGGL(k_dist, dim3(2048), dim3(256), 0, stream, h1t, nsq, ndb);
  hipLaunchKernelGGL(k_sel, dim3(2048), dim3(512), 0, stream, ndb, idx2);
  hipLaunchKernelGGL(k_conv3m, dim3(4096), dim3(256), 0, stream, h1t, idx2, w3, stat + S3o, stat + SS3o);
  hipLaunchKernelGGL(k_bnprep, dim3(1), dim3(128), 0, stream, stat + S3o, stat + SS3o, g3, b3,
                     stat + SC3, stat + SH3, 128);
  hipLaunchKernelGGL(k_conv4m, dim3(4096), dim3(256), 0, stream, h1t, idx2, w3, w4,
                     stat + SC3, stat + SH3, big0, big1, stat + S4o, stat + SS4o);
  hipLaunchKernelGGL(k_bnprep, dim3(1), dim3(128), 0, stream, stat + S4o, stat + SS4o, g4, b4,
                     stat + SC4, stat + SH4, 64);
  hipLaunchKernelGGL(k_finbn, dim3(128), dim3(256), 0, stream, big0, big1,
                     stat + SC4, stat + SH4, out, 64, (float*)nullptr, (float*)nullptr);
  (void)in_sizes; (void)n_in; (void)out_size; (void)ws_size;
}

// Round 9
// 671.064 us; speedup vs baseline: 11.8574x; 1.0720x over previous
//
#include <hip/hip_runtime.h>

#define DI __device__ __forceinline__

typedef _Float16 f16x2 __attribute__((ext_vector_type(2)));
typedef _Float16 f16x8 __attribute__((ext_vector_type(8)));
typedef float f32x4 __attribute__((ext_vector_type(4)));

#define NPTS 2048
#define KNBR 32
#define SALL 524288.0f
#define EPSV 1e-5f
#define SLOPEV 0.2f

// ---------------- workspace layout (bytes), total 144 MiB ----------------
#define OFF_IDX1 0u
#define OFF_IDX2 (2u*1024u*1024u)
#define OFF_H1T  (4u*1024u*1024u)
#define OFF_STAT (8u*1024u*1024u)
#define OFF_PF   (8u*1024u*1024u + 16384u)
#define OFF_NSQ  (9u*1024u*1024u)
#define OFF_PS2  (10u*1024u*1024u)
#define OFF_PSS2 (11u*1024u*1024u)
#define OFF_BIG  (16u*1024u*1024u)
#define OFF_PQ   (16u*1024u*1024u + 8u*1024u*1024u)
// BIG region timeline: [h1max,h1min] -> ndb(128MB) -> [h2max,h2min, PQ@+8MiB]
// stat float offsets
#define SC1 32
#define SH1 160
#define SC2 416
#define SH2 480
#define S3o 544
#define SS3o 672
#define SC3 800
#define SH3 928
#define S4o 1056
#define SS4o 1120
#define SC4 1184
#define SH4 1248

union U4 { uint4 u; float f[4]; };
union UH8 { uint4 u; f16x8 h; };

DI float lrelu(float z) { return z > 0.f ? z : SLOPEV * z; }

DI unsigned ordf(float f) {
  unsigned u = __float_as_uint(f);
  return ((int)u < 0) ? ~u : (u | 0x80000000u);
}

// Exact top-32 SET of 2048 values nd[s] per lane (value j = s*64+lane).
// Deterministic given input; boundary ties go to lowest j (jax tie rule).
DI void select_top32(const float (&nd)[32], int lane, int* __restrict__ outp) {
  unsigned uo[32];
  #pragma unroll
  for (int s = 0; s < 32; ++s) uo[s] = ordf(nd[s]);
  unsigned T = 0u;
  #pragma nounroll
  for (int bit = 31; bit >= 0; --bit) {
    unsigned cand = T | (1u << bit);
    int cnt = 0;
    #pragma unroll
    for (int s = 0; s < 32; ++s) cnt += __popcll(__ballot(uo[s] >= cand));
    if (cnt >= 32) T = cand;
  }
  const unsigned long long lml = (1ull << lane) - 1ull;
  int base = 0;
  #pragma nounroll
  for (int s = 0; s < 32; ++s) {
    unsigned long long m = __ballot(uo[s] > T);
    if ((m >> lane) & 1ull) outp[base + __popcll(m & lml)] = s * 64 + lane;
    base += __popcll(m);
  }
  #pragma nounroll
  for (int s = 0; s < 32 && base < 32; ++s) {
    unsigned long long m = __ballot(uo[s] == T);
    int r = __popcll(m & lml);
    if (((m >> lane) & 1ull) && (base + r) < 32) outp[base + r] = s * 64 + lane;
    base += __popcll(m);
  }
}

// ---------------- K1: stage-1 top-k (C=3) ----------------
__global__ __launch_bounds__(256) void k_topk1(const float* __restrict__ x, int* __restrict__ idx1) {
  __shared__ float xl[NPTS * 3];
  __shared__ float sq[NPTS];
  const int t = threadIdx.x;
  const int blk4 = blockIdx.x * 4;
  const int b = blk4 >> 11;
  const float* __restrict__ xb = x + (size_t)b * 3 * NPTS;
  for (int e = t; e < 3 * NPTS; e += 256) {
    int c = e >> 11, n = e & (NPTS - 1);
    xl[n * 3 + c] = xb[e];
  }
  __syncthreads();
  for (int n = t; n < NPTS; n += 256) {
    float a0 = xl[n * 3], a1 = xl[n * 3 + 1], a2 = xl[n * 3 + 2];
    sq[n] = a0 * a0 + a1 * a1 + a2 * a2;
  }
  __syncthreads();
  const int lane = t & 63, w = t >> 6;
  const int row = blk4 + w;
  const int i = row & (NPTS - 1);
  const float xi0 = xl[i * 3], xi1 = xl[i * 3 + 1], xi2 = xl[i * 3 + 2];
  const float si = sq[i];
  float nd[32];
  #pragma unroll
  for (int s = 0; s < 32; ++s) {
    int j = s * 64 + lane;
    float d = xi0 * xl[j * 3] + xi1 * xl[j * 3 + 1] + xi2 * xl[j * 3 + 2];
    nd[s] = (2.0f * d - si) - sq[j];
  }
  select_top32(nd, lane, idx1 + (size_t)row * KNBR);
}

// ---------------- K2: feat1 moments -> per-block partials (deterministic) ----------------
__global__ __launch_bounds__(256) void k_featstats(const float* __restrict__ x,
                                                   const int* __restrict__ idx1,
                                                   float* __restrict__ partF) {
  __shared__ float wred[4][27];
  const int t = threadIdx.x;
  const int row = blockIdx.x * 256 + t;
  const int b = row >> 11, i = row & (NPTS - 1);
  const float* __restrict__ xb = x + (size_t)b * 3 * NPTS;
  const float xi0 = xb[i], xi1 = xb[NPTS + i], xi2 = xb[2 * NPTS + i];
  float sd0 = 0, sd1 = 0, sd2 = 0, q00 = 0, q01 = 0, q02 = 0, q11 = 0, q12 = 0, q22 = 0;
  for (int k = 0; k < KNBR; ++k) {
    int j = idx1[(size_t)row * KNBR + k];
    float d0 = xb[j] - xi0, d1 = xb[NPTS + j] - xi1, d2 = xb[2 * NPTS + j] - xi2;
    sd0 += d0; sd1 += d1; sd2 += d2;
    q00 += d0 * d0; q01 += d0 * d1; q02 += d0 * d2;
    q11 += d1 * d1; q12 += d1 * d2; q22 += d2 * d2;
  }
  float v[27];
  v[0] = sd0; v[1] = sd1; v[2] = sd2; v[3] = 32.f * xi0; v[4] = 32.f * xi1; v[5] = 32.f * xi2;
  v[6] = q00; v[7] = q01; v[8] = q02; v[9] = sd0 * xi0; v[10] = sd0 * xi1; v[11] = sd0 * xi2;
  v[12] = q11; v[13] = q12; v[14] = sd1 * xi0; v[15] = sd1 * xi1; v[16] = sd1 * xi2;
  v[17] = q22; v[18] = sd2 * xi0; v[19] = sd2 * xi1; v[20] = sd2 * xi2;
  v[21] = 32.f * xi0 * xi0; v[22] = 32.f * xi0 * xi1; v[23] = 32.f * xi0 * xi2;
  v[24] = 32.f * xi1 * xi1; v[25] = 32.f * xi1 * xi2; v[26] = 32.f * xi2 * xi2;
  #pragma unroll
  for (int qq = 0; qq < 27; ++qq) {
    float s = v[qq];
    #pragma unroll
    for (int d = 1; d < 64; d <<= 1) s += __shfl_xor(s, d);
    if ((t & 63) == 0) wred[t >> 6][qq] = s;
  }
  __syncthreads();
  if (t < 27)
    partF[blockIdx.x * 27 + t] = (wred[0][t] + wred[1][t]) + (wred[2][t] + wred[3][t]);
}

// ---------------- K3: BN1 params (deterministic reduce of 64 partials) ----------------
__global__ void k_bnprep1(const float* __restrict__ partF, const float* __restrict__ w1,
                          const float* __restrict__ g1, const float* __restrict__ b1,
                          float* __restrict__ sc1, float* __restrict__ sh1) {
  __shared__ float F[27], M[36], mu[6];
  const int t = threadIdx.x;
  const float inv = 1.0f / SALL;
  if (t < 27) {
    float s = 0.f;
    for (int b = 0; b < 64; ++b) s += partF[b * 27 + t];
    F[t] = s;
  }
  __syncthreads();
  if (t < 6) mu[t] = F[t] * inv;
  if (t < 36) {
    int a = t / 6, bq = t % 6;
    int aa = a < bq ? a : bq, bb = a < bq ? bq : a;
    int pos = aa * 6 - aa * (aa + 1) / 2 + bb;
    M[t] = F[6 + pos] * inv;
  }
  __syncthreads();
  if (t < 128) {
    const float* w = w1 + t * 6;
    float m = 0.f;
    for (int c = 0; c < 6; ++c) m += w[c] * mu[c];
    float e2 = 0.f;
    for (int a = 0; a < 6; ++a)
      for (int c = 0; c < 6; ++c) e2 += w[a] * w[c] * M[a * 6 + c];
    float var = e2 - m * m;
    float rstd = rsqrtf(var + EPSV);
    float s = g1[t] * rstd;
    sc1[t] = s;
    sh1[t] = b1[t] - m * s;
  }
}

// ---------------- BN2 prep: deterministic reduce of 4096 block partials ----------------
__global__ __launch_bounds__(256) void k_bnprep2(
    const float* __restrict__ pS, const float* __restrict__ pSS,
    const float* __restrict__ g, const float* __restrict__ bb,
    float* __restrict__ sc, float* __restrict__ sh) {
  __shared__ float wsA[4], wsB[4];
  const int c = blockIdx.x;
  const int t = threadIdx.x;
  float s = 0.f, ss = 0.f;
  #pragma nounroll
  for (int i = 0; i < 16; ++i) {
    int blk = t * 16 + i;
    s += pS[(size_t)blk * 64 + c];
    ss += pSS[(size_t)blk * 64 + c];
  }
  #pragma unroll
  for (int d = 1; d < 64; d <<= 1) { s += __shfl_xor(s, d); ss += __shfl_xor(ss, d); }
  if ((t & 63) == 0) { wsA[t >> 6] = s; wsB[t >> 6] = ss; }
  __syncthreads();
  if (t == 0) {
    float S = (wsA[0] + wsA[1]) + (wsA[2] + wsA[3]);
    float SS = (wsB[0] + wsB[1]) + (wsB[2] + wsB[3]);
    const float inv = 1.0f / SALL;
    float m = S * inv;
    float var = SS * inv - m * m;
    float rstd = rsqrtf(var + EPSV);
    float scale = g[c] * rstd;
    sc[c] = scale;
    sh[c] = bb[c] - m * scale;
  }
}

// ---------------- generic BN prep (atomic sums; BN3/BN4 only) ----------------
__global__ void k_bnprep(const float* __restrict__ s, const float* __restrict__ ss,
                         const float* __restrict__ g, const float* __restrict__ bb,
                         float* __restrict__ sc, float* __restrict__ sh, int nch) {
  const int t = threadIdx.x;
  if (t < nch) {
    const float inv = 1.0f / SALL;
    float m = s[t] * inv;
    float var = ss[t] * inv - m * m;
    float rstd = rsqrtf(var + EPSV);
    float scale = g[t] * rstd;
    sc[t] = scale;
    sh[t] = bb[t] - m * scale;
  }
}

// ---------------- K4: gather + conv1(fp32) + BN1 + lrelu + conv2(split-f16 MFMA) ----------------
__global__ __launch_bounds__(256) void k_conv12m(
    const float* __restrict__ x, const int* __restrict__ idx1,
    const float* __restrict__ w1, const float* __restrict__ w2,
    const float* __restrict__ sc1g, const float* __restrict__ sh1g,
    float* __restrict__ h1max, float* __restrict__ h1min,
    float* __restrict__ pS2, float* __restrict__ pSS2) {
  __shared__ __align__(16) _Float16 z1h[128 * 136];
  __shared__ __align__(16) _Float16 z1lo[128 * 136];
  __shared__ float featl[6][128];
  __shared__ float w1l[768];
  const int t = threadIdx.x;
  const int blk = blockIdx.x;
  const int row0 = blk * 4;
  const int b = row0 >> 11;
  const float* __restrict__ xb = x + (size_t)b * 3 * NPTS;
  for (int e = t; e < 768; e += 256) w1l[e] = w1[e];
  if (t < 128) {
    int r = t >> 5;
    int n = (row0 & (NPTS - 1)) + r;
    int j = idx1[(size_t)(row0 + r) * KNBR + (t & 31)];
    float c0 = xb[n], c1 = xb[NPTS + n], c2 = xb[2 * NPTS + n];
    featl[0][t] = xb[j] - c0;
    featl[1][t] = xb[NPTS + j] - c1;
    featl[2][t] = xb[2 * NPTS + j] - c2;
    featl[3][t] = c0; featl[4][t] = c1; featl[5][t] = c2;
  }
  __syncthreads();
  {
    const int s = t >> 1, hh = t & 1;
    float f0 = featl[0][s], f1 = featl[1][s], f2 = featl[2][s];
    float f3 = featl[3][s], f4 = featl[4][s], f5 = featl[5][s];
    #pragma unroll
    for (int chunk = 0; chunk < 8; ++chunk) {
      UH8 hi8, lo8;
      #pragma unroll
      for (int i = 0; i < 8; ++i) {
        int c = hh * 64 + chunk * 8 + i;
        const float* wr = &w1l[c * 6];
        float y = wr[0] * f0 + wr[1] * f1 + wr[2] * f2 + wr[3] * f3 + wr[4] * f4 + wr[5] * f5;
        float z = y * sc1g[c] + sh1g[c];
        z = z > 0.f ? z : SLOPEV * z;
        _Float16 h = (_Float16)z;
        hi8.h[i] = h;
        lo8.h[i] = (_Float16)(z - (float)h);
      }
      *reinterpret_cast<uint4*>(&z1h[s * 136 + hh * 64 + chunk * 8]) = hi8.u;
      *reinterpret_cast<uint4*>(&z1lo[s * 136 + hh * 64 + chunk * 8]) = lo8.u;
    }
  }
  const int lane = t & 63, w = t >> 6;
  const int c15 = lane & 15, g = lane >> 4;
  const int o4 = 16 * w + c15;
  f16x8 Bh[4], Bl[4];
  #pragma unroll
  for (int ks = 0; ks < 4; ++ks) {
    const float* wr = w2 + o4 * 128 + ks * 32 + g * 8;
    #pragma unroll
    for (int i = 0; i < 8; ++i) {
      float v = wr[i];
      _Float16 h = (_Float16)v;
      Bh[ks][i] = h;
      Bl[ks][i] = (_Float16)(v - (float)h);
    }
  }
  __syncthreads();
  f32x4 acc[8] = {};
  #pragma unroll
  for (int mt = 0; mt < 8; ++mt) {
    #pragma unroll
    for (int ks = 0; ks < 4; ++ks) {
      UH8 ah, al;
      ah.u = *reinterpret_cast<const uint4*>(&z1h[(16 * mt + c15) * 136 + ks * 32 + g * 8]);
      al.u = *reinterpret_cast<const uint4*>(&z1lo[(16 * mt + c15) * 136 + ks * 32 + g * 8]);
      acc[mt] = __builtin_amdgcn_mfma_f32_16x16x32_f16(ah.h, Bh[ks], acc[mt], 0, 0, 0);
      acc[mt] = __builtin_amdgcn_mfma_f32_16x16x32_f16(al.h, Bh[ks], acc[mt], 0, 0, 0);
      acc[mt] = __builtin_amdgcn_mfma_f32_16x16x32_f16(ah.h, Bl[ks], acc[mt], 0, 0, 0);
    }
  }
  float s = 0.f, ss = 0.f;
  float mx[4], mn[4];
  #pragma unroll
  for (int rp = 0; rp < 4; ++rp) { mx[rp] = -3.0e38f; mn[rp] = 3.0e38f; }
  #pragma unroll
  for (int mt = 0; mt < 8; ++mt) {
    const int rp = mt >> 1;
    #pragma unroll
    for (int r = 0; r < 4; ++r) {
      float v = acc[mt][r];
      s += v; ss += v * v;
      mx[rp] = fmaxf(mx[rp], v); mn[rp] = fminf(mn[rp], v);
    }
  }
  s += __shfl_xor(s, 16); ss += __shfl_xor(ss, 16);
  s += __shfl_xor(s, 32); ss += __shfl_xor(ss, 32);
  #pragma unroll
  for (int rp = 0; rp < 4; ++rp) {
    mx[rp] = fmaxf(mx[rp], __shfl_xor(mx[rp], 16));
    mx[rp] = fmaxf(mx[rp], __shfl_xor(mx[rp], 32));
    mn[rp] = fminf(mn[rp], __shfl_xor(mn[rp], 16));
    mn[rp] = fminf(mn[rp], __shfl_xor(mn[rp], 32));
  }
  if (lane < 16) {
    #pragma unroll
    for (int rp = 0; rp < 4; ++rp) {
      h1max[(size_t)(row0 + rp) * 64 + o4] = mx[rp];
      h1min[(size_t)(row0 + rp) * 64 + o4] = mn[rp];
    }
    pS2[(size_t)blk * 64 + o4] = s;
    pSS2[(size_t)blk * 64 + o4] = ss;
  }
}

// ---------------- K5: BN + lrelu epilogue from (max,min); writes out (+h1t,+nsq) ----------------
__global__ __launch_bounds__(256) void k_finbn(
    const float* __restrict__ hmax, const float* __restrict__ hmin,
    const float* __restrict__ scg, const float* __restrict__ shg,
    float* __restrict__ out, const int choff,
    float* __restrict__ h1t, float* __restrict__ nsq) {
  __shared__ float ht[128][65];
  const int t = threadIdx.x;
  const int blk = blockIdx.x;
  const int row0 = blk * 128;
  const int b = row0 >> 11, n0 = row0 & (NPTS - 1);
  const int c = t & 63;
  const float sc = scg[c], sh = shg[c];
  const int rbase = t >> 6;
  for (int it = 0; it < 32; ++it) {
    int rl = it * 4 + rbase;
    size_t gi = (size_t)(row0 + rl) * 64 + c;
    float y = sc > 0.f ? hmax[gi] : hmin[gi];
    float h = lrelu(sc * y + sh);
    if (h1t) h1t[gi] = h;
    ht[rl][c] = h;
  }
  __syncthreads();
  if (nsq && t < 128) {
    float s = 0.f;
    #pragma unroll
    for (int c2 = 0; c2 < 64; ++c2) { float v = ht[t][c2]; s += v * v; }
    nsq[row0 + t] = s;
  }
  const int co = t >> 2, i0 = (t & 3) * 32;
  float* __restrict__ op = out + ((size_t)b * 128 + choff + co) * NPTS + n0 + i0;
  for (int i = 0; i < 32; i += 4) {
    float4 v;
    v.x = ht[i0 + i][co]; v.y = ht[i0 + i + 1][co];
    v.z = ht[i0 + i + 2][co]; v.w = ht[i0 + i + 3][co];
    *reinterpret_cast<float4*>(op + i) = v;
  }
}

// ---------------- K7b: ND = 2*H*H^T - n_i - n_j ----------------
#define BCOL(c) ((c) + (((c) >> 5) << 2))
__global__ __launch_bounds__(256) void k_dist(const float* __restrict__ h1t,
                                              const float* __restrict__ nsq,
                                              float* __restrict__ ndb) {
  __shared__ __align__(16) float Al[32][132];
  __shared__ __align__(16) float Bl[32][140];
  const int t = threadIdx.x;
  const int bt = blockIdx.x >> 8, rem = blockIdx.x & 255;
  const int ti = rem >> 4, tj = rem & 15;
  const float* __restrict__ hb = h1t + (size_t)bt * NPTS * 64;
  const int r0 = ti * 128, c0 = tj * 128;
  const int tx = t & 15, ty = t >> 4;
  float acc[8][8] = {};
  for (int kk = 0; kk < 64; kk += 32) {
    __syncthreads();
    for (int e = t; e < 1024; e += 256) {
      int r = e >> 3, c4 = e & 7;
      float4 va = *reinterpret_cast<const float4*>(hb + (size_t)(r0 + r) * 64 + kk + c4 * 4);
      int cb = c4 * 4;
      Al[cb][r] = va.x; Al[cb + 1][r] = va.y; Al[cb + 2][r] = va.z; Al[cb + 3][r] = va.w;
      float4 vb = *reinterpret_cast<const float4*>(hb + (size_t)(c0 + r) * 64 + kk + c4 * 4);
      int rp = BCOL(r);
      Bl[cb][rp] = vb.x; Bl[cb + 1][rp] = vb.y; Bl[cb + 2][rp] = vb.z; Bl[cb + 3][rp] = vb.w;
    }
    __syncthreads();
    #pragma unroll 8
    for (int k = 0; k < 32; ++k) {
      U4 a0; a0.u = *reinterpret_cast<const uint4*>(&Al[k][ty * 8]);
      U4 a1; a1.u = *reinterpret_cast<const uint4*>(&Al[k][ty * 8 + 4]);
      U4 b0; b0.u = *reinterpret_cast<const uint4*>(&Bl[k][BCOL(tx * 8)]);
      U4 b1; b1.u = *reinterpret_cast<const uint4*>(&Bl[k][BCOL(tx * 8) + 4]);
      #pragma unroll
      for (int rr = 0; rr < 4; ++rr) {
        #pragma unroll
        for (int cc = 0; cc < 4; ++cc) {
          acc[rr][cc] += a0.f[rr] * b0.f[cc];
          acc[rr][cc + 4] += a0.f[rr] * b1.f[cc];
          acc[rr + 4][cc] += a1.f[rr] * b0.f[cc];
          acc[rr + 4][cc + 4] += a1.f[rr] * b1.f[cc];
        }
      }
    }
  }
  float nr[8], nc[8];
  const float* __restrict__ nb2 = nsq + (size_t)bt * NPTS;
  #pragma unroll
  for (int i = 0; i < 8; ++i) {
    nr[i] = nb2[r0 + ty * 8 + i];
    nc[i] = nb2[c0 + tx * 8 + i];
  }
  float* __restrict__ op = ndb + ((size_t)bt * NPTS + r0 + ty * 8) * NPTS + c0 + tx * 8;
  #pragma unroll
  for (int rr = 0; rr < 8; ++rr) {
    float4 o0, o1;
    o0.x = 2.f * acc[rr][0] - nr[rr] - nc[0];
    o0.y = 2.f * acc[rr][1] - nr[rr] - nc[1];
    o0.z = 2.f * acc[rr][2] - nr[rr] - nc[2];
    o0.w = 2.f * acc[rr][3] - nr[rr] - nc[3];
    o1.x = 2.f * acc[rr][4] - nr[rr] - nc[4];
    o1.y = 2.f * acc[rr][5] - nr[rr] - nc[5];
    o1.z = 2.f * acc[rr][6] - nr[rr] - nc[6];
    o1.w = 2.f * acc[rr][7] - nr[rr] - nc[7];
    *reinterpret_cast<float4*>(op + (size_t)rr * NPTS) = o0;
    *reinterpret_cast<float4*>(op + (size_t)rr * NPTS + 4) = o1;
  }
}

// ---------------- K7c: streaming top-32 selection ----------------
__global__ __launch_bounds__(512) void k_sel(const float* __restrict__ ndb,
                                             int* __restrict__ idx2) {
  const int t = threadIdx.x, lane = t & 63, w = t >> 6;
  const int row = blockIdx.x * 8 + w;
  const float* __restrict__ nr = ndb + (size_t)row * NPTS;
  float nd[32];
  #pragma unroll
  for (int s = 0; s < 32; ++s) nd[s] = nr[s * 64 + lane];
  select_top32(nd, lane, idx2 + (size_t)row * KNBR);
}

DI f16x8 packw8(const float* __restrict__ wr) {
  float4 a = *reinterpret_cast<const float4*>(wr);
  float4 bq = *reinterpret_cast<const float4*>(wr + 4);
  f16x8 f;
  f[0] = (_Float16)a.x; f[1] = (_Float16)a.y; f[2] = (_Float16)a.z; f[3] = (_Float16)a.w;
  f[4] = (_Float16)bq.x; f[5] = (_Float16)bq.y; f[6] = (_Float16)bq.z; f[7] = (_Float16)bq.w;
  return f;
}

// ---------------- K8a: P/Q GEMM.  P = H*w3d^T, Q = H*(w3c-w3d)^T, f16 out ----------------
// PQ[row][0..127] = P, PQ[row][128..255] = Q. 256 blocks x 64 rows.
__global__ __launch_bounds__(256) void k_pq(const float* __restrict__ h1t,
                                            const float* __restrict__ w3,
                                            _Float16* __restrict__ PQ) {
  __shared__ __align__(16) _Float16 a16[64 * 72];
  const int t = threadIdx.x;
  const int row0 = blockIdx.x * 64;
  {
    int row = t >> 2, q = t & 3;
    const float* src = h1t + (size_t)(row0 + row) * 64 + q * 16;
    float4 f0 = *reinterpret_cast<const float4*>(src);
    float4 f1 = *reinterpret_cast<const float4*>(src + 4);
    float4 f2 = *reinterpret_cast<const float4*>(src + 8);
    float4 f3 = *reinterpret_cast<const float4*>(src + 12);
    UH8 lo, hi;
    lo.h[0] = (_Float16)f0.x; lo.h[1] = (_Float16)f0.y; lo.h[2] = (_Float16)f0.z; lo.h[3] = (_Float16)f0.w;
    lo.h[4] = (_Float16)f1.x; lo.h[5] = (_Float16)f1.y; lo.h[6] = (_Float16)f1.z; lo.h[7] = (_Float16)f1.w;
    hi.h[0] = (_Float16)f2.x; hi.h[1] = (_Float16)f2.y; hi.h[2] = (_Float16)f2.z; hi.h[3] = (_Float16)f2.w;
    hi.h[4] = (_Float16)f3.x; hi.h[5] = (_Float16)f3.y; hi.h[6] = (_Float16)f3.z; hi.h[7] = (_Float16)f3.w;
    *reinterpret_cast<uint4*>(&a16[row * 72 + q * 16]) = lo.u;
    *reinterpret_cast<uint4*>(&a16[row * 72 + q * 16 + 8]) = hi.u;
  }
  const int lane = t & 63, w = t >> 6, c15 = lane & 15, g = lane >> 4;
  f16x8 Bf[4][2];
  #pragma unroll
  for (int nt = 0; nt < 4; ++nt) {
    const int ch = 64 * w + 16 * nt + c15;  // 0..255
    #pragma unroll
    for (int ks = 0; ks < 2; ++ks) {
      const int k0 = ks * 32 + g * 8;
      if (ch < 128) {
        const float* wr = w3 + ch * 128 + k0;
        #pragma unroll
        for (int i = 0; i < 8; ++i) Bf[nt][ks][i] = (_Float16)wr[i];
      } else {
        const float* wr = w3 + (ch - 128) * 128 + k0;
        #pragma unroll
        for (int i = 0; i < 8; ++i) Bf[nt][ks][i] = (_Float16)(wr[64 + i] - wr[i]);
      }
    }
  }
  __syncthreads();
  f32x4 acc[4][4] = {};
  #pragma unroll
  for (int mt = 0; mt < 4; ++mt) {
    #pragma unroll
    for (int ks = 0; ks < 2; ++ks) {
      UH8 av;
      av.u = *reinterpret_cast<const uint4*>(&a16[(16 * mt + c15) * 72 + ks * 32 + g * 8]);
      #pragma unroll
      for (int nt = 0; nt < 4; ++nt)
        acc[mt][nt] = __builtin_amdgcn_mfma_f32_16x16x32_f16(av.h, Bf[nt][ks], acc[mt][nt], 0, 0, 0);
    }
  }
  #pragma unroll
  for (int mt = 0; mt < 4; ++mt)
    #pragma unroll
    for (int nt = 0; nt < 4; ++nt)
      #pragma unroll
      for (int r = 0; r < 4; ++r)
        PQ[(size_t)(row0 + 16 * mt + 4 * g + r) * 256 + 64 * w + 16 * nt + c15] =
            (_Float16)acc[mt][nt][r];
}

// ---------------- K8b: BN3 stats from y3 = P[j] + Q[i] ----------------
// 1024 blocks x 16 rows (512 pairs). Thread owns one channel, loops pairs.
__global__ __launch_bounds__(256) void k_stats3(const _Float16* __restrict__ PQ,
                                                const int* __restrict__ idx2,
                                                float* __restrict__ gS3,
                                                float* __restrict__ gSS3) {
  __shared__ float Qf[16][128];
  __shared__ int idxl[512];
  __shared__ float redS[2][128], redQ[2][128];
  const int t = threadIdx.x;
  const int row0 = blockIdx.x * 16;
  const int bbase = row0 & ~(NPTS - 1);
  for (int e = t; e < 2048; e += 256) {
    int r = e >> 7, c = e & 127;
    Qf[r][c] = (float)PQ[(size_t)(row0 + r) * 256 + 128 + c];
  }
  for (int e = t; e < 512; e += 256) idxl[e] = idx2[(size_t)row0 * KNBR + e];
  __syncthreads();
  const int c = t & 127, grp = t >> 7;
  float s = 0.f, ss = 0.f;
  #pragma nounroll
  for (int p = grp * 256; p < grp * 256 + 256; ++p) {
    int j = idxl[p] + bbase;
    float v = (float)PQ[(size_t)j * 256 + c] + Qf[p >> 5][c];
    s += v; ss += v * v;
  }
  redS[grp][c] = s; redQ[grp][c] = ss;
  __syncthreads();
  if (t < 128) {
    atomicAdd(&gS3[t], redS[0][t] + redS[1][t]);
    atomicAdd(&gSS3[t], redQ[0][t] + redQ[1][t]);
  }
}

// ---------------- K8c: z3 = lrelu(BN3(P[j]+Q[i])) -> conv4 MFMA + stats4 + k-max/min ----------------
__global__ __launch_bounds__(256) void k_conv4z(
    const _Float16* __restrict__ PQ, const int* __restrict__ idx2,
    const float* __restrict__ w4,
    const float* __restrict__ sc3g, const float* __restrict__ sh3g,
    float* __restrict__ h2max, float* __restrict__ h2min,
    float* __restrict__ gS4, float* __restrict__ gSS4) {
  __shared__ __align__(16) _Float16 z3[128 * 136];
  __shared__ float scl[128], shl[128];
  const int t = threadIdx.x;
  const int row0 = blockIdx.x * 4;
  const int bbase = row0 & ~(NPTS - 1);
  if (t < 128) { scl[t] = sc3g[t]; shl[t] = sh3g[t]; }
  __syncthreads();
  {
    const int s = t >> 1, hh = t & 1;
    const int r = s >> 5, k = s & 31;
    const int j = idx2[(size_t)(row0 + r) * KNBR + k] + bbase;
    const _Float16* pp = PQ + (size_t)j * 256 + hh * 64;
    const _Float16* qq = PQ + (size_t)(row0 + r) * 256 + 128 + hh * 64;
    _Float16* zp = z3 + s * 136 + hh * 64;
    #pragma unroll
    for (int i0 = 0; i0 < 64; i0 += 8) {
      UH8 pv, qv, zv;
      pv.u = *reinterpret_cast<const uint4*>(pp + i0);
      qv.u = *reinterpret_cast<const uint4*>(qq + i0);
      #pragma unroll
      for (int i = 0; i < 8; ++i) {
        int ch = hh * 64 + i0 + i;
        float y = (float)pv.h[i] + (float)qv.h[i];
        float z = y * scl[ch] + shl[ch];
        zv.h[i] = (_Float16)(z > 0.f ? z : SLOPEV * z);
      }
      *reinterpret_cast<uint4*>(zp + i0) = zv.u;
    }
  }
  const int lane = t & 63, w = t >> 6, c15 = lane & 15, g = lane >> 4;
  f16x8 B4[4];
  const int o4 = 16 * w + c15;
  {
    const float* wr = w4 + o4 * 128 + 8 * g;
    #pragma unroll
    for (int ks = 0; ks < 4; ++ks) B4[ks] = packw8(wr + ks * 32);
  }
  __syncthreads();
  f32x4 a4[8] = {};
  #pragma unroll
  for (int mt = 0; mt < 8; ++mt) {
    #pragma unroll
    for (int ks = 0; ks < 4; ++ks) {
      UH8 av;
      av.u = *reinterpret_cast<const uint4*>(&z3[(16 * mt + c15) * 136 + ks * 32 + g * 8]);
      a4[mt] = __builtin_amdgcn_mfma_f32_16x16x32_f16(av.h, B4[ks], a4[mt], 0, 0, 0);
    }
  }
  float s = 0.f, ss = 0.f;
  float mx[4], mn[4];
  #pragma unroll
  for (int rp = 0; rp < 4; ++rp) { mx[rp] = -3.0e38f; mn[rp] = 3.0e38f; }
  #pragma unroll
  for (int mt = 0; mt < 8; ++mt) {
    const int rp = mt >> 1;
    #pragma unroll
    for (int r = 0; r < 4; ++r) {
      float v = a4[mt][r];
      s += v; ss += v * v;
      mx[rp] = fmaxf(mx[rp], v); mn[rp] = fminf(mn[rp], v);
    }
  }
  s += __shfl_xor(s, 16); ss += __shfl_xor(ss, 16);
  s += __shfl_xor(s, 32); ss += __shfl_xor(ss, 32);
  #pragma unroll
  for (int rp = 0; rp < 4; ++rp) {
    mx[rp] = fmaxf(mx[rp], __shfl_xor(mx[rp], 16));
    mx[rp] = fmaxf(mx[rp], __shfl_xor(mx[rp], 32));
    mn[rp] = fminf(mn[rp], __shfl_xor(mn[rp], 16));
    mn[rp] = fminf(mn[rp], __shfl_xor(mn[rp], 32));
  }
  if (lane < 16) {
    #pragma unroll
    for (int rp = 0; rp < 4; ++rp) {
      h2max[(size_t)(row0 + rp) * 64 + o4] = mx[rp];
      h2min[(size_t)(row0 + rp) * 64 + o4] = mn[rp];
    }
    atomicAdd(&gS4[o4], s);
    atomicAdd(&gSS4[o4], ss);
  }
}

// ---------------- host launcher ----------------
extern "C" void kernel_launch(void* const* d_in, const int* in_sizes, int n_in,
                              void* d_out, int out_size, void* d_ws, size_t ws_size,
                              hipStream_t stream) {
  const float* x = (const float*)d_in[0];
  const float* w1 = (const float*)d_in[1];
  const float* g1 = (const float*)d_in[2];
  const float* b1 = (const float*)d_in[3];
  const float* w2 = (const float*)d_in[4];
  const float* g2 = (const float*)d_in[5];
  const float* b2 = (const float*)d_in[6];
  const float* w3 = (const float*)d_in[7];
  const float* g3 = (const float*)d_in[8];
  const float* b3 = (const float*)d_in[9];
  const float* w4 = (const float*)d_in[10];
  const float* g4 = (const float*)d_in[11];
  const float* b4 = (const float*)d_in[12];
  float* out = (float*)d_out;
  char* ws = (char*)d_ws;
  int* idx1 = (int*)(ws + OFF_IDX1);
  int* idx2 = (int*)(ws + OFF_IDX2);
  float* h1t = (float*)(ws + OFF_H1T);
  float* stat = (float*)(ws + OFF_STAT);
  float* partF = (float*)(ws + OFF_PF);
  float* nsq = (float*)(ws + OFF_NSQ);
  float* pS2 = (float*)(ws + OFF_PS2);
  float* pSS2 = (float*)(ws + OFF_PSS2);
  float* big0 = (float*)(ws + OFF_BIG);
  float* big1 = (float*)(ws + OFF_BIG + 4u * 1024u * 1024u);
  float* ndb = (float*)(ws + OFF_BIG);
  _Float16* PQh = (_Float16*)(ws + OFF_PQ);

  hipMemsetAsync(stat, 0, 8192, stream);  // zero BN3/BN4 atomic accumulators
  hipLaunchKernelGGL(k_topk1, dim3(4096), dim3(256), 0, stream, x, idx1);
  hipLaunchKernelGGL(k_featstats, dim3(64), dim3(256), 0, stream, x, idx1, partF);
  hipLaunchKernelGGL(k_bnprep1, dim3(1), dim3(128), 0, stream, partF, w1, g1, b1, stat + SC1, stat + SH1);
  hipLaunchKernelGGL(k_conv12m, dim3(4096), dim3(256), 0, stream, x, idx1, w1, w2,
                     stat + SC1, stat + SH1, big0, big1, pS2, pSS2);
  hipLaunchKernelGGL(k_bnprep2, dim3(64), dim3(256), 0, stream, pS2, pSS2, g2, b2,
                     stat + SC2, stat + SH2);
  hipLaunchKernelGGL(k_finbn, dim3(128), dim3(256), 0, stream, big0, big1,
                     stat + SC2, stat + SH2, out, 0, h1t, nsq);
  hipLaunchKernelGGL(k_dist, dim3(2048), dim3(256), 0, stream, h1t, nsq, ndb);
  hipLaunchKernelGGL(k_sel, dim3(2048), dim3(512), 0, stream, ndb, idx2);
  hipLaunchKernelGGL(k_pq, dim3(256), dim3(256), 0, stream, h1t, w3, PQh);
  hipLaunchKernelGGL(k_stats3, dim3(1024), dim3(256), 0, stream, PQh, idx2, stat + S3o, stat + SS3o);
  hipLaunchKernelGGL(k_bnprep, dim3(1), dim3(128), 0, stream, stat + S3o, stat + SS3o, g3, b3,
                     stat + SC3, stat + SH3, 128);
  hipLaunchKernelGGL(k_conv4z, dim3(4096), dim3(256), 0, stream, PQh, idx2, w4,
                     stat + SC3, stat + SH3, big0, big1, stat + S4o, stat + SS4o);
  hipLaunchKernelGGL(k_bnprep, dim3(1), dim3(128), 0, stream, stat + S4o, stat + SS4o, g4, b4,
                     stat + SC4, stat + SH4, 64);
  hipLaunchKernelGGL(k_finbn, dim3(128), dim3(256), 0, stream, big0, big1,
                     stat + SC4, stat + SH4, out, 64, (float*)nullptr, (float*)nullptr);
  (void)in_sizes; (void)n_in; (void)out_size; (void)ws_size;
}

// Round 11
// 529.590 us; speedup vs baseline: 15.0250x; 1.2671x over previous
//
#include <hip/hip_runtime.h>

#define DI __device__ __forceinline__

typedef _Float16 f16x2 __attribute__((ext_vector_type(2)));
typedef _Float16 f16x8 __attribute__((ext_vector_type(8)));
typedef float f32x4 __attribute__((ext_vector_type(4)));

#define NPTS 2048
#define KNBR 32
#define SALL 524288.0f
#define EPSV 1e-5f
#define SLOPEV 0.2f

// ---------------- workspace layout (bytes), total 144 MiB ----------------
#define OFF_IDX1 0u
#define OFF_IDX2 (2u*1024u*1024u)
#define OFF_H1T  (4u*1024u*1024u)
#define OFF_STAT (8u*1024u*1024u)
#define OFF_PF   (8u*1024u*1024u + 16384u)       // 4096 x 27 floats = 432 KB
#define OFF_NSQ  (9u*1024u*1024u)
#define OFF_PS2  (10u*1024u*1024u)               // 4096 x 64 (reused for BN4)
#define OFF_PSS2 (11u*1024u*1024u)
#define OFF_W2H  (12u*1024u*1024u)               // 8192 f16
#define OFF_W2L  (12u*1024u*1024u + 16384u)
#define OFF_W4H  (12u*1024u*1024u + 32768u)
#define OFF_BIG  (16u*1024u*1024u)
#define OFF_PQ   (16u*1024u*1024u + 8u*1024u*1024u)
// stat float offsets
#define SC1 32
#define SH1 160
#define SC2 416
#define SH2 480
#define S3o 544
#define SS3o 672
#define SC3 800
#define SH3 928
#define SC4 1184
#define SH4 1248

union U4 { uint4 u; float f[4]; };
union UH8 { uint4 u; f16x8 h; };

DI float lrelu(float z) { return z > 0.f ? z : SLOPEV * z; }

DI unsigned ordf(float f) {
  unsigned u = __float_as_uint(f);
  return ((int)u < 0) ? ~u : (u | 0x80000000u);
}

// Exact top-32 SET of 2048 values nd[s] per lane (value j = s*64+lane).
// Deterministic; boundary ties go to lowest j (jax tie rule).
// Early-exit: if cnt(>=cand)==32, those 32 ARE the set.
DI void select_top32(const float (&nd)[32], int lane, int* __restrict__ outp) {
  unsigned uo[32];
  #pragma unroll
  for (int s = 0; s < 32; ++s) uo[s] = ordf(nd[s]);
  unsigned T = 0u;
  #pragma nounroll
  for (int bit = 31; bit >= 0; --bit) {
    unsigned cand = T | (1u << bit);
    int cnt = 0;
    #pragma unroll
    for (int s = 0; s < 32; ++s) cnt += __popcll(__ballot(uo[s] >= cand));
    if (cnt >= 32) {
      T = cand;
      if (cnt == 32) break;   // exact set found
    }
  }
  const unsigned long long lml = (1ull << lane) - 1ull;
  int base = 0;
  #pragma nounroll
  for (int s = 0; s < 32; ++s) {
    unsigned long long m = __ballot(uo[s] > T);
    if ((m >> lane) & 1ull) outp[base + __popcll(m & lml)] = s * 64 + lane;
    base += __popcll(m);
  }
  #pragma nounroll
  for (int s = 0; s < 32 && base < 32; ++s) {
    unsigned long long m = __ballot(uo[s] == T);
    int r = __popcll(m & lml);
    if (((m >> lane) & 1ull) && (base + r) < 32) outp[base + r] = s * 64 + lane;
    base += __popcll(m);
  }
}

// ---------------- K0: weight pre-conversion (w2 split hi/lo, w4 f16) ----------------
__global__ __launch_bounds__(256) void k_wprep(const float* __restrict__ w2,
                                               const float* __restrict__ w4,
                                               _Float16* __restrict__ w2h,
                                               _Float16* __restrict__ w2l,
                                               _Float16* __restrict__ w4h) {
  const int i = blockIdx.x * 256 + threadIdx.x;
  if (i < 8192) {
    float v = w2[i];
    _Float16 h = (_Float16)v;
    w2h[i] = h;
    w2l[i] = (_Float16)(v - (float)h);
  } else if (i < 16384) {
    w4h[i - 8192] = (_Float16)w4[i - 8192];
  }
}

// ---------------- K1: stage-1 top-k (C=3) + fused feat1 moments ----------------
__global__ __launch_bounds__(256) void k_topk1(const float* __restrict__ x,
                                               int* __restrict__ idx1,
                                               float* __restrict__ partF) {
  __shared__ float xl[NPTS * 3];
  __shared__ float sq[NPTS];
  __shared__ int selb[4][32];
  __shared__ float wred[4][27];
  const int t = threadIdx.x;
  const int blk4 = blockIdx.x * 4;
  const int b = blk4 >> 11;
  const float* __restrict__ xb = x + (size_t)b * 3 * NPTS;
  for (int e = t; e < 3 * NPTS; e += 256) {
    int c = e >> 11, n = e & (NPTS - 1);
    xl[n * 3 + c] = xb[e];
  }
  __syncthreads();
  for (int n = t; n < NPTS; n += 256) {
    float a0 = xl[n * 3], a1 = xl[n * 3 + 1], a2 = xl[n * 3 + 2];
    sq[n] = a0 * a0 + a1 * a1 + a2 * a2;
  }
  __syncthreads();
  const int lane = t & 63, w = t >> 6;
  const int row = blk4 + w;
  const int i = row & (NPTS - 1);
  const float xi0 = xl[i * 3], xi1 = xl[i * 3 + 1], xi2 = xl[i * 3 + 2];
  const float si = sq[i];
  float nd[32];
  #pragma unroll
  for (int s = 0; s < 32; ++s) {
    int j = s * 64 + lane;
    float d = xi0 * xl[j * 3] + xi1 * xl[j * 3 + 1] + xi2 * xl[j * 3 + 2];
    nd[s] = (2.0f * d - si) - sq[j];
  }
  select_top32(nd, lane, selb[w]);
  __syncthreads();
  if (lane < 32) idx1[(size_t)row * KNBR + lane] = selb[w][lane];
  // feat1 moments from LDS (lanes 0..31 own one neighbor each)
  float sd0 = 0, sd1 = 0, sd2 = 0, q00 = 0, q01 = 0, q02 = 0, q11 = 0, q12 = 0, q22 = 0;
  if (lane < 32) {
    int j = selb[w][lane];
    float d0 = xl[j * 3] - xi0, d1 = xl[j * 3 + 1] - xi1, d2 = xl[j * 3 + 2] - xi2;
    sd0 = d0; sd1 = d1; sd2 = d2;
    q00 = d0 * d0; q01 = d0 * d1; q02 = d0 * d2;
    q11 = d1 * d1; q12 = d1 * d2; q22 = d2 * d2;
  }
  #pragma unroll
  for (int d = 1; d < 64; d <<= 1) {
    sd0 += __shfl_xor(sd0, d); sd1 += __shfl_xor(sd1, d); sd2 += __shfl_xor(sd2, d);
    q00 += __shfl_xor(q00, d); q01 += __shfl_xor(q01, d); q02 += __shfl_xor(q02, d);
    q11 += __shfl_xor(q11, d); q12 += __shfl_xor(q12, d); q22 += __shfl_xor(q22, d);
  }
  if (lane == 0) {
    float* v = wred[w];
    v[0] = sd0; v[1] = sd1; v[2] = sd2; v[3] = 32.f * xi0; v[4] = 32.f * xi1; v[5] = 32.f * xi2;
    v[6] = q00; v[7] = q01; v[8] = q02; v[9] = sd0 * xi0; v[10] = sd0 * xi1; v[11] = sd0 * xi2;
    v[12] = q11; v[13] = q12; v[14] = sd1 * xi0; v[15] = sd1 * xi1; v[16] = sd1 * xi2;
    v[17] = q22; v[18] = sd2 * xi0; v[19] = sd2 * xi1; v[20] = sd2 * xi2;
    v[21] = 32.f * xi0 * xi0; v[22] = 32.f * xi0 * xi1; v[23] = 32.f * xi0 * xi2;
    v[24] = 32.f * xi1 * xi1; v[25] = 32.f * xi1 * xi2; v[26] = 32.f * xi2 * xi2;
  }
  __syncthreads();
  if (t < 27)
    partF[(size_t)blockIdx.x * 27 + t] =
        (wred[0][t] + wred[1][t]) + (wred[2][t] + wred[3][t]);
}

// ---------------- K3: BN1 params (deterministic reduce of 4096 partials) ----------------
__global__ __launch_bounds__(256) void k_bnprep1(const float* __restrict__ partF,
                                                 const float* __restrict__ w1,
                                                 const float* __restrict__ g1,
                                                 const float* __restrict__ b1,
                                                 float* __restrict__ sc1,
                                                 float* __restrict__ sh1) {
  __shared__ float acc[8][27];
  __shared__ float F[27], M[36], mu[6];
  const int t = threadIdx.x;
  const float inv = 1.0f / SALL;
  if (t < 216) {
    int q = t % 27, seg = t / 27;
    float s = 0.f;
    for (int i2 = 0; i2 < 512; ++i2) s += partF[(size_t)(seg * 512 + i2) * 27 + q];
    acc[seg][q] = s;
  }
  __syncthreads();
  if (t < 27)
    F[t] = ((acc[0][t] + acc[1][t]) + (acc[2][t] + acc[3][t])) +
           ((acc[4][t] + acc[5][t]) + (acc[6][t] + acc[7][t]));
  __syncthreads();
  if (t < 6) mu[t] = F[t] * inv;
  if (t < 36) {
    int a = t / 6, bq = t % 6;
    int aa = a < bq ? a : bq, bb = a < bq ? bq : a;
    int pos = aa * 6 - aa * (aa + 1) / 2 + bb;
    M[t] = F[6 + pos] * inv;
  }
  __syncthreads();
  if (t < 128) {
    const float* w = w1 + t * 6;
    float m = 0.f;
    for (int c = 0; c < 6; ++c) m += w[c] * mu[c];
    float e2 = 0.f;
    for (int a = 0; a < 6; ++a)
      for (int c = 0; c < 6; ++c) e2 += w[a] * w[c] * M[a * 6 + c];
    float var = e2 - m * m;
    float rstd = rsqrtf(var + EPSV);
    float s = g1[t] * rstd;
    sc1[t] = s;
    sh1[t] = b1[t] - m * s;
  }
}

// ---------------- BN prep: deterministic reduce of 4096 block partials (BN2/BN4) ----------------
__global__ __launch_bounds__(256) void k_bnprep2(
    const float* __restrict__ pS, const float* __restrict__ pSS,
    const float* __restrict__ g, const float* __restrict__ bb,
    float* __restrict__ sc, float* __restrict__ sh) {
  __shared__ float wsA[4], wsB[4];
  const int c = blockIdx.x;
  const int t = threadIdx.x;
  float s = 0.f, ss = 0.f;
  #pragma nounroll
  for (int i = 0; i < 16; ++i) {
    int blk = t * 16 + i;
    s += pS[(size_t)blk * 64 + c];
    ss += pSS[(size_t)blk * 64 + c];
  }
  #pragma unroll
  for (int d = 1; d < 64; d <<= 1) { s += __shfl_xor(s, d); ss += __shfl_xor(ss, d); }
  if ((t & 63) == 0) { wsA[t >> 6] = s; wsB[t >> 6] = ss; }
  __syncthreads();
  if (t == 0) {
    float S = (wsA[0] + wsA[1]) + (wsA[2] + wsA[3]);
    float SS = (wsB[0] + wsB[1]) + (wsB[2] + wsB[3]);
    const float inv = 1.0f / SALL;
    float m = S * inv;
    float var = SS * inv - m * m;
    float rstd = rsqrtf(var + EPSV);
    float scale = g[c] * rstd;
    sc[c] = scale;
    sh[c] = bb[c] - m * scale;
  }
}

// ---------------- generic BN prep (atomic sums; BN3 only) ----------------
__global__ void k_bnprep(const float* __restrict__ s, const float* __restrict__ ss,
                         const float* __restrict__ g, const float* __restrict__ bb,
                         float* __restrict__ sc, float* __restrict__ sh, int nch) {
  const int t = threadIdx.x;
  if (t < nch) {
    const float inv = 1.0f / SALL;
    float m = s[t] * inv;
    float var = ss[t] * inv - m * m;
    float rstd = rsqrtf(var + EPSV);
    float scale = g[t] * rstd;
    sc[t] = scale;
    sh[t] = bb[t] - m * scale;
  }
}

// ---------------- K4: gather + conv1(fp32) + BN1 + lrelu + conv2(split-f16 MFMA) ----------------
__global__ __launch_bounds__(256) void k_conv12m(
    const float* __restrict__ x, const int* __restrict__ idx1,
    const float* __restrict__ w1,
    const _Float16* __restrict__ w2h, const _Float16* __restrict__ w2l,
    const float* __restrict__ sc1g, const float* __restrict__ sh1g,
    float* __restrict__ h1max, float* __restrict__ h1min,
    float* __restrict__ pS2, float* __restrict__ pSS2) {
  __shared__ __align__(16) _Float16 z1h[128 * 136];
  __shared__ __align__(16) _Float16 z1lo[128 * 136];
  __shared__ float featl[6][128];
  __shared__ float w1l[768];
  const int t = threadIdx.x;
  const int blk = blockIdx.x;
  const int row0 = blk * 4;
  const int b = row0 >> 11;
  const float* __restrict__ xb = x + (size_t)b * 3 * NPTS;
  for (int e = t; e < 768; e += 256) w1l[e] = w1[e];
  if (t < 128) {
    int r = t >> 5;
    int n = (row0 & (NPTS - 1)) + r;
    int j = idx1[(size_t)(row0 + r) * KNBR + (t & 31)];
    float c0 = xb[n], c1 = xb[NPTS + n], c2 = xb[2 * NPTS + n];
    featl[0][t] = xb[j] - c0;
    featl[1][t] = xb[NPTS + j] - c1;
    featl[2][t] = xb[2 * NPTS + j] - c2;
    featl[3][t] = c0; featl[4][t] = c1; featl[5][t] = c2;
  }
  __syncthreads();
  {
    const int s = t >> 1, hh = t & 1;
    float f0 = featl[0][s], f1 = featl[1][s], f2 = featl[2][s];
    float f3 = featl[3][s], f4 = featl[4][s], f5 = featl[5][s];
    #pragma unroll
    for (int chunk = 0; chunk < 8; ++chunk) {
      UH8 hi8, lo8;
      #pragma unroll
      for (int i = 0; i < 8; ++i) {
        int c = hh * 64 + chunk * 8 + i;
        const float* wr = &w1l[c * 6];
        float y = wr[0] * f0 + wr[1] * f1 + wr[2] * f2 + wr[3] * f3 + wr[4] * f4 + wr[5] * f5;
        float z = y * sc1g[c] + sh1g[c];
        z = z > 0.f ? z : SLOPEV * z;
        _Float16 h = (_Float16)z;
        hi8.h[i] = h;
        lo8.h[i] = (_Float16)(z - (float)h);
      }
      *reinterpret_cast<uint4*>(&z1h[s * 136 + hh * 64 + chunk * 8]) = hi8.u;
      *reinterpret_cast<uint4*>(&z1lo[s * 136 + hh * 64 + chunk * 8]) = lo8.u;
    }
  }
  const int lane = t & 63, w = t >> 6;
  const int c15 = lane & 15, g = lane >> 4;
  const int o4 = 16 * w + c15;
  f16x8 Bh[4], Bl[4];
  #pragma unroll
  for (int ks = 0; ks < 4; ++ks) {
    UH8 a, bq;
    a.u = *reinterpret_cast<const uint4*>(w2h + o4 * 128 + ks * 32 + g * 8);
    bq.u = *reinterpret_cast<const uint4*>(w2l + o4 * 128 + ks * 32 + g * 8);
    Bh[ks] = a.h; Bl[ks] = bq.h;
  }
  __syncthreads();
  f32x4 acc[8] = {};
  #pragma unroll
  for (int mt = 0; mt < 8; ++mt) {
    #pragma unroll
    for (int ks = 0; ks < 4; ++ks) {
      UH8 ah, al;
      ah.u = *reinterpret_cast<const uint4*>(&z1h[(16 * mt + c15) * 136 + ks * 32 + g * 8]);
      al.u = *reinterpret_cast<const uint4*>(&z1lo[(16 * mt + c15) * 136 + ks * 32 + g * 8]);
      acc[mt] = __builtin_amdgcn_mfma_f32_16x16x32_f16(ah.h, Bh[ks], acc[mt], 0, 0, 0);
      acc[mt] = __builtin_amdgcn_mfma_f32_16x16x32_f16(al.h, Bh[ks], acc[mt], 0, 0, 0);
      acc[mt] = __builtin_amdgcn_mfma_f32_16x16x32_f16(ah.h, Bl[ks], acc[mt], 0, 0, 0);
    }
  }
  float s = 0.f, ss = 0.f;
  float mx[4], mn[4];
  #pragma unroll
  for (int rp = 0; rp < 4; ++rp) { mx[rp] = -3.0e38f; mn[rp] = 3.0e38f; }
  #pragma unroll
  for (int mt = 0; mt < 8; ++mt) {
    const int rp = mt >> 1;
    #pragma unroll
    for (int r = 0; r < 4; ++r) {
      float v = acc[mt][r];
      s += v; ss += v * v;
      mx[rp] = fmaxf(mx[rp], v); mn[rp] = fminf(mn[rp], v);
    }
  }
  s += __shfl_xor(s, 16); ss += __shfl_xor(ss, 16);
  s += __shfl_xor(s, 32); ss += __shfl_xor(ss, 32);
  #pragma unroll
  for (int rp = 0; rp < 4; ++rp) {
    mx[rp] = fmaxf(mx[rp], __shfl_xor(mx[rp], 16));
    mx[rp] = fmaxf(mx[rp], __shfl_xor(mx[rp], 32));
    mn[rp] = fminf(mn[rp], __shfl_xor(mn[rp], 16));
    mn[rp] = fminf(mn[rp], __shfl_xor(mn[rp], 32));
  }
  if (lane < 16) {
    #pragma unroll
    for (int rp = 0; rp < 4; ++rp) {
      h1max[(size_t)(row0 + rp) * 64 + o4] = mx[rp];
      h1min[(size_t)(row0 + rp) * 64 + o4] = mn[rp];
    }
    pS2[(size_t)blk * 64 + o4] = s;
    pSS2[(size_t)blk * 64 + o4] = ss;
  }
}

// ---------------- K5: BN + lrelu epilogue from (max,min); writes out (+h1t,+nsq) ----------------
__global__ __launch_bounds__(256) void k_finbn(
    const float* __restrict__ hmax, const float* __restrict__ hmin,
    const float* __restrict__ scg, const float* __restrict__ shg,
    float* __restrict__ out, const int choff,
    float* __restrict__ h1t, float* __restrict__ nsq) {
  __shared__ float ht[128][65];
  const int t = threadIdx.x;
  const int blk = blockIdx.x;
  const int row0 = blk * 128;
  const int b = row0 >> 11, n0 = row0 & (NPTS - 1);
  const int c = t & 63;
  const float sc = scg[c], sh = shg[c];
  const int rbase = t >> 6;
  for (int it = 0; it < 32; ++it) {
    int rl = it * 4 + rbase;
    size_t gi = (size_t)(row0 + rl) * 64 + c;
    float y = sc > 0.f ? hmax[gi] : hmin[gi];
    float h = lrelu(sc * y + sh);
    if (h1t) h1t[gi] = h;
    ht[rl][c] = h;
  }
  __syncthreads();
  if (nsq && t < 128) {
    float s = 0.f;
    #pragma unroll
    for (int c2 = 0; c2 < 64; ++c2) { float v = ht[t][c2]; s += v * v; }
    nsq[row0 + t] = s;
  }
  const int co = t >> 2, i0 = (t & 3) * 32;
  float* __restrict__ op = out + ((size_t)b * 128 + choff + co) * NPTS + n0 + i0;
  for (int i = 0; i < 32; i += 4) {
    float4 v;
    v.x = ht[i0 + i][co]; v.y = ht[i0 + i + 1][co];
    v.z = ht[i0 + i + 2][co]; v.w = ht[i0 + i + 3][co];
    *reinterpret_cast<float4*>(op + i) = v;
  }
}

// ---------------- K7b: ND = 2*H*H^T - n_i - n_j ----------------
#define BCOL(c) ((c) + (((c) >> 5) << 2))
__global__ __launch_bounds__(256) void k_dist(const float* __restrict__ h1t,
                                              const float* __restrict__ nsq,
                                              float* __restrict__ ndb) {
  __shared__ __align__(16) float Al[32][132];
  __shared__ __align__(16) float Bl[32][140];
  const int t = threadIdx.x;
  const int bt = blockIdx.x >> 8, rem = blockIdx.x & 255;
  const int ti = rem >> 4, tj = rem & 15;
  const float* __restrict__ hb = h1t + (size_t)bt * NPTS * 64;
  const int r0 = ti * 128, c0 = tj * 128;
  const int tx = t & 15, ty = t >> 4;
  float acc[8][8] = {};
  for (int kk = 0; kk < 64; kk += 32) {
    __syncthreads();
    for (int e = t; e < 1024; e += 256) {
      int r = e >> 3, c4 = e & 7;
      float4 va = *reinterpret_cast<const float4*>(hb + (size_t)(r0 + r) * 64 + kk + c4 * 4);
      int cb = c4 * 4;
      Al[cb][r] = va.x; Al[cb + 1][r] = va.y; Al[cb + 2][r] = va.z; Al[cb + 3][r] = va.w;
      float4 vb = *reinterpret_cast<const float4*>(hb + (size_t)(c0 + r) * 64 + kk + c4 * 4);
      int rp = BCOL(r);
      Bl[cb][rp] = vb.x; Bl[cb + 1][rp] = vb.y; Bl[cb + 2][rp] = vb.z; Bl[cb + 3][rp] = vb.w;
    }
    __syncthreads();
    #pragma unroll 8
    for (int k = 0; k < 32; ++k) {
      U4 a0; a0.u = *reinterpret_cast<const uint4*>(&Al[k][ty * 8]);
      U4 a1; a1.u = *reinterpret_cast<const uint4*>(&Al[k][ty * 8 + 4]);
      U4 b0; b0.u = *reinterpret_cast<const uint4*>(&Bl[k][BCOL(tx * 8)]);
      U4 b1; b1.u = *reinterpret_cast<const uint4*>(&Bl[k][BCOL(tx * 8) + 4]);
      #pragma unroll
      for (int rr = 0; rr < 4; ++rr) {
        #pragma unroll
        for (int cc = 0; cc < 4; ++cc) {
          acc[rr][cc] += a0.f[rr] * b0.f[cc];
          acc[rr][cc + 4] += a0.f[rr] * b1.f[cc];
          acc[rr + 4][cc] += a1.f[rr] * b0.f[cc];
          acc[rr + 4][cc + 4] += a1.f[rr] * b1.f[cc];
        }
      }
    }
  }
  float nr[8], nc[8];
  const float* __restrict__ nb2 = nsq + (size_t)bt * NPTS;
  #pragma unroll
  for (int i = 0; i < 8; ++i) {
    nr[i] = nb2[r0 + ty * 8 + i];
    nc[i] = nb2[c0 + tx * 8 + i];
  }
  float* __restrict__ op = ndb + ((size_t)bt * NPTS + r0 + ty * 8) * NPTS + c0 + tx * 8;
  #pragma unroll
  for (int rr = 0; rr < 8; ++rr) {
    float4 o0, o1;
    o0.x = 2.f * acc[rr][0] - nr[rr] - nc[0];
    o0.y = 2.f * acc[rr][1] - nr[rr] - nc[1];
    o0.z = 2.f * acc[rr][2] - nr[rr] - nc[2];
    o0.w = 2.f * acc[rr][3] - nr[rr] - nc[3];
    o1.x = 2.f * acc[rr][4] - nr[rr] - nc[4];
    o1.y = 2.f * acc[rr][5] - nr[rr] - nc[5];
    o1.z = 2.f * acc[rr][6] - nr[rr] - nc[6];
    o1.w = 2.f * acc[rr][7] - nr[rr] - nc[7];
    *reinterpret_cast<float4*>(op + (size_t)rr * NPTS) = o0;
    *reinterpret_cast<float4*>(op + (size_t)rr * NPTS + 4) = o1;
  }
}

// ---------------- K7c: streaming top-32 selection ----------------
__global__ __launch_bounds__(512) void k_sel(const float* __restrict__ ndb,
                                             int* __restrict__ idx2) {
  const int t = threadIdx.x, lane = t & 63, w = t >> 6;
  const int row = blockIdx.x * 8 + w;
  const float* __restrict__ nr = ndb + (size_t)row * NPTS;
  float nd[32];
  #pragma unroll
  for (int s = 0; s < 32; ++s) nd[s] = nr[s * 64 + lane];
  select_top32(nd, lane, idx2 + (size_t)row * KNBR);
}

// ---------------- K8a: P/Q GEMM.  P = H*w3d^T, Q = H*(w3c-w3d)^T, f16 out ----------------
__global__ __launch_bounds__(256) void k_pq(const float* __restrict__ h1t,
                                            const float* __restrict__ w3,
                                            _Float16* __restrict__ PQ) {
  __shared__ __align__(16) _Float16 a16[64 * 72];
  const int t = threadIdx.x;
  const int row0 = blockIdx.x * 64;
  {
    int row = t >> 2, q = t & 3;
    const float* src = h1t + (size_t)(row0 + row) * 64 + q * 16;
    float4 f0 = *reinterpret_cast<const float4*>(src);
    float4 f1 = *reinterpret_cast<const float4*>(src + 4);
    float4 f2 = *reinterpret_cast<const float4*>(src + 8);
    float4 f3 = *reinterpret_cast<const float4*>(src + 12);
    UH8 lo, hi;
    lo.h[0] = (_Float16)f0.x; lo.h[1] = (_Float16)f0.y; lo.h[2] = (_Float16)f0.z; lo.h[3] = (_Float16)f0.w;
    lo.h[4] = (_Float16)f1.x; lo.h[5] = (_Float16)f1.y; lo.h[6] = (_Float16)f1.z; lo.h[7] = (_Float16)f1.w;
    hi.h[0] = (_Float16)f2.x; hi.h[1] = (_Float16)f2.y; hi.h[2] = (_Float16)f2.z; hi.h[3] = (_Float16)f2.w;
    hi.h[4] = (_Float16)f3.x; hi.h[5] = (_Float16)f3.y; hi.h[6] = (_Float16)f3.z; hi.h[7] = (_Float16)f3.w;
    *reinterpret_cast<uint4*>(&a16[row * 72 + q * 16]) = lo.u;
    *reinterpret_cast<uint4*>(&a16[row * 72 + q * 16 + 8]) = hi.u;
  }
  const int lane = t & 63, w = t >> 6, c15 = lane & 15, g = lane >> 4;
  f16x8 Bf[4][2];
  #pragma unroll
  for (int nt = 0; nt < 4; ++nt) {
    const int ch = 64 * w + 16 * nt + c15;
    #pragma unroll
    for (int ks = 0; ks < 2; ++ks) {
      const int k0 = ks * 32 + g * 8;
      if (ch < 128) {
        const float* wr = w3 + ch * 128 + k0;
        #pragma unroll
        for (int i = 0; i < 8; ++i) Bf[nt][ks][i] = (_Float16)wr[i];
      } else {
        const float* wr = w3 + (ch - 128) * 128 + k0;
        #pragma unroll
        for (int i = 0; i < 8; ++i) Bf[nt][ks][i] = (_Float16)(wr[64 + i] - wr[i]);
      }
    }
  }
  __syncthreads();
  f32x4 acc[4][4] = {};
  #pragma unroll
  for (int mt = 0; mt < 4; ++mt) {
    #pragma unroll
    for (int ks = 0; ks < 2; ++ks) {
      UH8 av;
      av.u = *reinterpret_cast<const uint4*>(&a16[(16 * mt + c15) * 72 + ks * 32 + g * 8]);
      #pragma unroll
      for (int nt = 0; nt < 4; ++nt)
        acc[mt][nt] = __builtin_amdgcn_mfma_f32_16x16x32_f16(av.h, Bf[nt][ks], acc[mt][nt], 0, 0, 0);
    }
  }
  #pragma unroll
  for (int mt = 0; mt < 4; ++mt)
    #pragma unroll
    for (int nt = 0; nt < 4; ++nt)
      #pragma unroll
      for (int r = 0; r < 4; ++r)
        PQ[(size_t)(row0 + 16 * mt + 4 * g + r) * 256 + 64 * w + 16 * nt + c15] =
            (_Float16)acc[mt][nt][r];
}

// ---------------- K8b: BN3 stats from y3 = P[j] + Q[i] ----------------
__global__ __launch_bounds__(256) void k_stats3(const _Float16* __restrict__ PQ,
                                                const int* __restrict__ idx2,
                                                float* __restrict__ gS3,
                                                float* __restrict__ gSS3) {
  __shared__ float Qf[16][128];
  __shared__ int idxl[512];
  __shared__ float redS[2][128], redQ[2][128];
  const int t = threadIdx.x;
  const int row0 = blockIdx.x * 16;
  const int bbase = row0 & ~(NPTS - 1);
  for (int e = t; e < 2048; e += 256) {
    int r = e >> 7, c = e & 127;
    Qf[r][c] = (float)PQ[(size_t)(row0 + r) * 256 + 128 + c];
  }
  for (int e = t; e < 512; e += 256) idxl[e] = idx2[(size_t)row0 * KNBR + e];
  __syncthreads();
  const int c = t & 127, grp = t >> 7;
  float s = 0.f, ss = 0.f;
  #pragma nounroll
  for (int p = grp * 256; p < grp * 256 + 256; ++p) {
    int j = idxl[p] + bbase;
    float v = (float)PQ[(size_t)j * 256 + c] + Qf[p >> 5][c];
    s += v; ss += v * v;
  }
  redS[grp][c] = s; redQ[grp][c] = ss;
  __syncthreads();
  if (t < 128) {
    atomicAdd(&gS3[t], redS[0][t] + redS[1][t]);
    atomicAdd(&gSS3[t], redQ[0][t] + redQ[1][t]);
  }
}

// ---------------- K8c: z3 = lrelu(BN3(P[j]+Q[i])) -> conv4 MFMA + stats4 + k-max/min ----------------
__global__ __launch_bounds__(256) void k_conv4z(
    const _Float16* __restrict__ PQ, const int* __restrict__ idx2,
    const _Float16* __restrict__ w4h,
    const float* __restrict__ sc3g, const float* __restrict__ sh3g,
    float* __restrict__ h2max, float* __restrict__ h2min,
    float* __restrict__ pS4, float* __restrict__ pSS4) {
  __shared__ __align__(16) _Float16 z3[128 * 136];
  __shared__ float scl[128], shl[128];
  const int t = threadIdx.x;
  const int blk = blockIdx.x;
  const int row0 = blk * 4;
  const int bbase = row0 & ~(NPTS - 1);
  if (t < 128) { scl[t] = sc3g[t]; shl[t] = sh3g[t]; }
  __syncthreads();
  {
    const int s = t >> 1, hh = t & 1;
    const int r = s >> 5, k = s & 31;
    const int j = idx2[(size_t)(row0 + r) * KNBR + k] + bbase;
    const _Float16* pp = PQ + (size_t)j * 256 + hh * 64;
    const _Float16* qq = PQ + (size_t)(row0 + r) * 256 + 128 + hh * 64;
    _Float16* zp = z3 + s * 136 + hh * 64;
    #pragma unroll
    for (int i0 = 0; i0 < 64; i0 += 8) {
      UH8 pv, qv, zv;
      pv.u = *reinterpret_cast<const uint4*>(pp + i0);
      qv.u = *reinterpret_cast<const uint4*>(qq + i0);
      #pragma unroll
      for (int i = 0; i < 8; ++i) {
        int ch = hh * 64 + i0 + i;
        float y = (float)pv.h[i] + (float)qv.h[i];
        float z = y * scl[ch] + shl[ch];
        zv.h[i] = (_Float16)(z > 0.f ? z : SLOPEV * z);
      }
      *reinterpret_cast<uint4*>(zp + i0) = zv.u;
    }
  }
  const int lane = t & 63, w = t >> 6, c15 = lane & 15, g = lane >> 4;
  f16x8 B4[4];
  const int o4 = 16 * w + c15;
  #pragma unroll
  for (int ks = 0; ks < 4; ++ks) {
    UH8 a;
    a.u = *reinterpret_cast<const uint4*>(w4h + o4 * 128 + ks * 32 + g * 8);
    B4[ks] = a.h;
  }
  __syncthreads();
  f32x4 a4[8] = {};
  #pragma unroll
  for (int mt = 0; mt < 8; ++mt) {
    #pragma unroll
    for (int ks = 0; ks < 4; ++ks) {
      UH8 av;
      av.u = *reinterpret_cast<const uint4*>(&z3[(16 * mt + c15) * 136 + ks * 32 + g * 8]);
      a4[mt] = __builtin_amdgcn_mfma_f32_16x16x32_f16(av.h, B4[ks], a4[mt], 0, 0, 0);
    }
  }
  float s = 0.f, ss = 0.f;
  float mx[4], mn[4];
  #pragma unroll
  for (int rp = 0; rp < 4; ++rp) { mx[rp] = -3.0e38f; mn[rp] = 3.0e38f; }
  #pragma unroll
  for (int mt = 0; mt < 8; ++mt) {
    const int rp = mt >> 1;
    #pragma unroll
    for (int r = 0; r < 4; ++r) {
      float v = a4[mt][r];
      s += v; ss += v * v;
      mx[rp] = fmaxf(mx[rp], v); mn[rp] = fminf(mn[rp], v);
    }
  }
  s += __shfl_xor(s, 16); ss += __shfl_xor(ss, 16);
  s += __shfl_xor(s, 32); ss += __shfl_xor(ss, 32);
  #pragma unroll
  for (int rp = 0; rp < 4; ++rp) {
    mx[rp] = fmaxf(mx[rp], __shfl_xor(mx[rp], 16));
    mx[rp] = fmaxf(mx[rp], __shfl_xor(mx[rp], 32));
    mn[rp] = fminf(mn[rp], __shfl_xor(mn[rp], 16));
    mn[rp] = fminf(mn[rp], __shfl_xor(mn[rp], 32));
  }
  if (lane < 16) {
    #pragma unroll
    for (int rp = 0; rp < 4; ++rp) {
      h2max[(size_t)(row0 + rp) * 64 + o4] = mx[rp];
      h2min[(size_t)(row0 + rp) * 64 + o4] = mn[rp];
    }
    pS4[(size_t)blk * 64 + o4] = s;
    pSS4[(size_t)blk * 64 + o4] = ss;
  }
}

// ---------------- host launcher ----------------
extern "C" void kernel_launch(void* const* d_in, const int* in_sizes, int n_in,
                              void* d_out, int out_size, void* d_ws, size_t ws_size,
                              hipStream_t stream) {
  const float* x = (const float*)d_in[0];
  const float* w1 = (const float*)d_in[1];
  const float* g1 = (const float*)d_in[2];
  const float* b1 = (const float*)d_in[3];
  const float* w2 = (const float*)d_in[4];
  const float* g2 = (const float*)d_in[5];
  const float* b2 = (const float*)d_in[6];
  const float* w3 = (const float*)d_in[7];
  const float* g3 = (const float*)d_in[8];
  const float* b3 = (const float*)d_in[9];
  const float* w4 = (const float*)d_in[10];
  const float* g4 = (const float*)d_in[11];
  const float* b4 = (const float*)d_in[12];
  float* out = (float*)d_out;
  char* ws = (char*)d_ws;
  int* idx1 = (int*)(ws + OFF_IDX1);
  int* idx2 = (int*)(ws + OFF_IDX2);
  float* h1t = (float*)(ws + OFF_H1T);
  float* stat = (float*)(ws + OFF_STAT);
  float* partF = (float*)(ws + OFF_PF);
  float* nsq = (float*)(ws + OFF_NSQ);
  float* pS2 = (float*)(ws + OFF_PS2);
  float* pSS2 = (float*)(ws + OFF_PSS2);
  _Float16* w2h = (_Float16*)(ws + OFF_W2H);
  _Float16* w2l = (_Float16*)(ws + OFF_W2L);
  _Float16* w4h = (_Float16*)(ws + OFF_W4H);
  float* big0 = (float*)(ws + OFF_BIG);
  float* big1 = (float*)(ws + OFF_BIG + 4u * 1024u * 1024u);
  float* ndb = (float*)(ws + OFF_BIG);
  _Float16* PQh = (_Float16*)(ws + OFF_PQ);

  hipMemsetAsync(stat, 0, 8192, stream);  // zero BN3 atomic accumulators
  hipLaunchKernelGGL(k_wprep, dim3(64), dim3(256), 0, stream, w2, w4, w2h, w2l, w4h);
  hipLaunchKernelGGL(k_topk1, dim3(4096), dim3(256), 0, stream, x, idx1, partF);
  hipLaunchKernelGGL(k_bnprep1, dim3(1), dim3(256), 0, stream, partF, w1, g1, b1, stat + SC1, stat + SH1);
  hipLaunchKernelGGL(k_conv12m, dim3(4096), dim3(256), 0, stream, x, idx1, w1, w2h, w2l,
                     stat + SC1, stat + SH1, big0, big1, pS2, pSS2);
  hipLaunchKernelGGL(k_bnprep2, dim3(64), dim3(256), 0, stream, pS2, pSS2, g2, b2,
                     stat + SC2, stat + SH2);
  hipLaunchKernelGGL(k_finbn, dim3(128), dim3(256), 0, stream, big0, big1,
                     stat + SC2, stat + SH2, out, 0, h1t, nsq);
  hipLaunchKernelGGL(k_dist, dim3(2048), dim3(256), 0, stream, h1t, nsq, ndb);
  hipLaunchKernelGGL(k_sel, dim3(2048), dim3(512), 0, stream, ndb, idx2);
  hipLaunchKernelGGL(k_pq, dim3(256), dim3(256), 0, stream, h1t, w3, PQh);
  hipLaunchKernelGGL(k_stats3, dim3(1024), dim3(256), 0, stream, PQh, idx2, stat + S3o, stat + SS3o);
  hipLaunchKernelGGL(k_bnprep, dim3(1), dim3(128), 0, stream, stat + S3o, stat + SS3o, g3, b3,
                     stat + SC3, stat + SH3, 128);
  hipLaunchKernelGGL(k_conv4z, dim3(4096), dim3(256), 0, stream, PQh, idx2, w4h,
                     stat + SC3, stat + SH3, big0, big1, pS2, pSS2);
  hipLaunchKernelGGL(k_bnprep2, dim3(64), dim3(256), 0, stream, pS2, pSS2, g4, b4,
                     stat + SC4, stat + SH4);
  hipLaunchKernelGGL(k_finbn, dim3(128), dim3(256), 0, stream, big0, big1,
                     stat + SC4, stat + SH4, out, 64, (float*)nullptr, (float*)nullptr);
  (void)in_sizes; (void)n_in; (void)out_size; (void)ws_size;
}